// Round 1
// baseline (746.387 us; speedup 1.0000x reference)
//
#include <hip/hip_runtime.h>
#include <cstddef>
#include <cstdint>

#define N_NODES 10000
#define N_EDGES 160000

// ---- constants ----
#define RS8    0.35355339059327373f   // 1/sqrt(8)
#define RS32   0.17677669529663687f   // 1/sqrt(32)
#define RS96   0.10206207261596575f   // 1/sqrt(96)
#define RS128  0.08838834764831845f   // 1/sqrt(128)
#define RS3    0.5773502691896258f    // 1/sqrt(3)
#define SQ3_   1.7320508075688772f
#define SQ5_   2.23606797749979f
#define A_     0.18257418583505536f   // 1/sqrt(30)
#define B_     0.31622776601683794f   // 1/sqrt(10)
#define SILU_C_ 1.6765208f
#define CS_    0.3826834323650898f    // sin(pi/8)
#define CX_    0.9238795325112867f    // cos(pi/8)
#define QDEG   0.25f                  // 1/sqrt(16)

typedef __attribute__((ext_vector_type(8))) short bf16x8;
typedef __attribute__((ext_vector_type(4))) float f32x4;
typedef __attribute__((ext_vector_type(2))) unsigned u32x2;
typedef __attribute__((ext_vector_type(4))) unsigned u32x4;

__device__ inline float bf2f(unsigned v) {
  union { unsigned u; float f; } c; c.u = v << 16; return c.f;
}
__device__ inline float bfhi(unsigned v) {   // float from HIGH 16 bits
  union { unsigned u; float f; } c; c.u = v & 0xffff0000u; return c.f;
}
__device__ inline unsigned short f2bf(float f) {
  union { float f; unsigned u; } c; c.f = f;
  unsigned r = c.u + 0x7fff + ((c.u >> 16) & 1);
  return (unsigned short)(r >> 16);
}
__device__ inline unsigned pack2bf(float a, float b) {
  return (unsigned)f2bf(a) | ((unsigned)f2bf(b) << 16);
}

// zero counts + build fc1p (fc1 64x320 f32 -> bf16 MFMA B-fragment order)
__global__ void k_init(int* __restrict__ counts, const float* __restrict__ fc1,
                       unsigned short* __restrict__ fc1p) {
  int i = blockIdx.x * blockDim.x + threadIdx.x;
  if (i < N_NODES) counts[i] = 0;
  if (i < 20480) {
    int j = i & 7, q = (i >> 3) & 3, n = (i >> 5) & 15, kq = (i >> 9) & 1, t = i >> 10;
    int k = kq * 32 + q * 8 + j;
    fc1p[i] = f2bf(fc1[k * 320 + t * 16 + n]);
  }
}

__global__ void k_hist(const int* __restrict__ edst, int* __restrict__ counts) {
  int e = blockIdx.x * blockDim.x + threadIdx.x;
  if (e < N_EDGES) atomicAdd(&counts[edst[e]], 1);
}

// exclusive scan of counts -> offs/cur; degree histogram + descending-degree
// exclusive scan -> dcur (single block).
__global__ __launch_bounds__(256) void k_scan(const int* __restrict__ counts,
                                              int* __restrict__ offs,
                                              int* __restrict__ cur,
                                              int* __restrict__ dcur) {
  __shared__ int ps[256];
  __shared__ int dbin[256];
  int t = threadIdx.x;
  dbin[t] = 0;
  int base = t * 40;
  int sum = 0;
  for (int i = 0; i < 40; ++i) {
    int idx = base + i;
    if (idx < N_NODES) sum += counts[idx];
  }
  ps[t] = sum;
  __syncthreads();
  for (int off = 1; off < 256; off <<= 1) {
    int v = (t >= off) ? ps[t - off] : 0;
    __syncthreads();
    ps[t] += v;
    __syncthreads();
  }
  int run = (t == 0) ? 0 : ps[t - 1];
  for (int i = 0; i < 40; ++i) {
    int idx = base + i;
    if (idx < N_NODES) {
      int c = counts[idx];
      offs[idx] = run; cur[idx] = run;
      run += c;
      atomicAdd(&dbin[c < 255 ? c : 255], 1);
    }
  }
  __syncthreads();
  int rb = 255 - t;
  int v = dbin[rb];
  __syncthreads();
  ps[t] = v;
  __syncthreads();
  for (int off = 1; off < 256; off <<= 1) {
    int u = (t >= off) ? ps[t - off] : 0;
    __syncthreads();
    ps[t] += u;
    __syncthreads();
  }
  dcur[rb] = ps[t] - v;
}

// Permute kernel: per edge compute sorted position p and SCATTER-WRITE two
// permuted per-edge streams:
//   ed2a (stride 12 f): [0..8]=SH, [9]=src, [10,11]=pad   (node_agg input)
//   ed2b (stride  8 f): ele row                            (w_gemm input)
// Inputs staged coalesced in LDS. Also the node scatter (descending-degree
// rank -> order/obeg/ocnt).
__global__ __launch_bounds__(256) void k_perm(
    const int* __restrict__ edst, int* __restrict__ cur,
    const int* __restrict__ counts, const int* __restrict__ offs,
    int* __restrict__ dcur, int* __restrict__ order,
    int* __restrict__ obeg, int* __restrict__ ocnt,
    const float* __restrict__ ele, const float* __restrict__ eattr,
    const int* __restrict__ esrc, float* __restrict__ ed2a,
    float* __restrict__ ed2b) {
  __shared__ __align__(16) float sh_ea[256 * 9];
  __shared__ __align__(16) float sh_el[256 * 8];
  int t = threadIdx.x;
  int eb = blockIdx.x * 256;
  int e = eb + t;
  for (int i = t; i < 2304; i += 256) sh_ea[i] = eattr[(size_t)eb * 9 + i];
  {
    const float4* src = (const float4*)(ele + (size_t)eb * 8);
    float4* dst = (float4*)sh_el;
    dst[t] = src[t]; dst[t + 256] = src[t + 256];
  }
  __syncthreads();
  int d = edst[e];
  int p = atomicAdd(&cur[d], 1);
  const float* ea = sh_ea + t * 9;
  const float* el = sh_el + t * 8;
  float4 r0 = {ea[0], ea[1], ea[2], ea[3]};
  float4 r1 = {ea[4], ea[5], ea[6], ea[7]};
  float4 r2 = {ea[8], __int_as_float(esrc[e]), 0.f, 0.f};
  float4* da = (float4*)(ed2a + (size_t)p * 12);
  da[0] = r0; da[1] = r1; da[2] = r2;
  float4 r3 = {el[0], el[1], el[2], el[3]};
  float4 r4 = {el[4], el[5], el[6], el[7]};
  float4* db = (float4*)(ed2b + (size_t)p * 8);
  db[0] = r3; db[1] = r4;
  if (e < N_NODES) {
    int c = counts[e];
    int b = c < 255 ? c : 255;
    int q = atomicAdd(&dcur[b], 1);
    order[q] = e; obeg[q] = offs[e]; ocnt[q] = c;
  }
}

__device__ inline f32x4 wtile(const unsigned short* __restrict__ fc1p,
                              bf16x8 a0, bf16x8 a1, int mrow, int quad, int t) {
  f32x4 acc = {0.f, 0.f, 0.f, 0.f};
  bf16x8 b0 = *(const bf16x8*)(fc1p + ((size_t)((t * 2 + 0) * 16 + mrow) * 4 + quad) * 8);
  bf16x8 b1 = *(const bf16x8*)(fc1p + ((size_t)((t * 2 + 1) * 16 + mrow) * 4 + quad) * 8);
  acc = __builtin_amdgcn_mfma_f32_16x16x32_bf16(b0, a0, acc, 0, 0, 0);
  acc = __builtin_amdgcn_mfma_f32_16x16x32_bf16(b1, a1, acc, 0, 0, 0);
  return acc;
}

struct WgemmShared {
  __align__(16) float ele[64][8];
  __align__(16) unsigned short h[64 * 72];   // 72-stride pad
};

// STREAMING MFMA radial GEMM: 64 edges/block, reads ele slices from the
// already-permuted ed2b (sequential), writes packed wbuf (640 B/edge,
// NON-TEMPORAL stores — write-once, read much later): [0,256) AB
// interleaved; [256,384) C; [384,640) DEFG interleaved.
__device__ void w_gemm_body(WgemmShared& sh, int blk,
    const float* __restrict__ ed2b, const float* __restrict__ fc0,
    const unsigned short* __restrict__ fc1p, unsigned short* __restrict__ wout) {
  int t = threadIdx.x;
  int eb = blk * 64;
  if (t < 128) {
    int e = t >> 1, hh = t & 1;
    ((float4*)&sh.ele[e][0])[hh] =
        *(const float4*)(ed2b + (size_t)(eb + e) * 8 + hh * 4);
  }
  __syncthreads();
  #pragma unroll
  for (int ii = 0; ii < 16; ++ii) {
    int idx = t + ii * 256;
    int e = idx >> 6, k = idx & 63;
    float acc = 0.f;
    #pragma unroll
    for (int m = 0; m < 8; ++m) acc += sh.ele[e][m] * fc0[m * 64 + k];
    acc *= RS8;
    float hv = SILU_C_ * acc / (1.f + __expf(-acc));
    sh.h[e * 72 + k] = f2bf(hv);
  }
  __syncthreads();

  int wv = t >> 6, lane = t & 63;
  int m0 = wv * 16;
  int mrow = lane & 15, quad = lane >> 4;
  bf16x8 a0 = *(const bf16x8*)(sh.h + (m0 + mrow) * 72 + quad * 8);
  bf16x8 a1 = *(const bf16x8*)(sh.h + (m0 + mrow) * 72 + 32 + quad * 8);
  char* wbase = (char*)wout + (size_t)(eb + m0 + mrow) * 640;
  const float K = 0.125f;
  #pragma unroll
  for (int tt = 0; tt < 4; ++tt) {
    f32x4 Av = wtile(fc1p, a0, a1, mrow, quad, tt);
    f32x4 Bv = wtile(fc1p, a0, a1, mrow, quad, tt + 4);
    u32x4 st;
    st.x = pack2bf(Av[0] * K, Bv[0] * K);
    st.y = pack2bf(Av[1] * K, Bv[1] * K);
    st.z = pack2bf(Av[2] * K, Bv[2] * K);
    st.w = pack2bf(Av[3] * K, Bv[3] * K);
    __builtin_nontemporal_store(st, (u32x4*)(wbase + 64 * tt + 16 * quad));
  }
  #pragma unroll
  for (int tt = 8; tt < 12; ++tt) {
    f32x4 Cv = wtile(fc1p, a0, a1, mrow, quad, tt);
    u32x2 st;
    st.x = pack2bf(Cv[0] * K, Cv[1] * K);
    st.y = pack2bf(Cv[2] * K, Cv[3] * K);
    __builtin_nontemporal_store(st, (u32x2*)(wbase + 256 + 32 * (tt - 8) + 8 * quad));
  }
  #pragma unroll
  for (int tt = 12; tt < 14; ++tt) {
    f32x4 Dv = wtile(fc1p, a0, a1, mrow, quad, tt);
    f32x4 Ev = wtile(fc1p, a0, a1, mrow, quad, tt + 2);
    f32x4 Fv = wtile(fc1p, a0, a1, mrow, quad, tt + 4);
    f32x4 Gv = wtile(fc1p, a0, a1, mrow, quad, tt + 6);
    char* db = wbase + 384 + 128 * (tt - 12) + 32 * quad;
    u32x4 s0, s1;
    s0.x = pack2bf(Dv[0] * K, Ev[0] * K); s0.y = pack2bf(Fv[0] * K, Gv[0] * K);
    s0.z = pack2bf(Dv[1] * K, Ev[1] * K); s0.w = pack2bf(Fv[1] * K, Gv[1] * K);
    s1.x = pack2bf(Dv[2] * K, Ev[2] * K); s1.y = pack2bf(Fv[2] * K, Gv[2] * K);
    s1.z = pack2bf(Dv[3] * K, Ev[3] * K); s1.w = pack2bf(Fv[3] * K, Gv[3] * K);
    __builtin_nontemporal_store(s0, (u32x4*)(db));
    __builtin_nontemporal_store(s1, (u32x4*)(db + 16));
  }
}

// y PADDED (stride 192 f): [0,64) scalar, vector channel u' as float4
// {x0,x1,x2,0} at 64+4u'. (s is computed in node_agg's epilogue now.)
__device__ void node_pre_body(int blk,
    const float* __restrict__ xin, const float* __restrict__ attr,
    const float* __restrict__ l1_w0, const float* __restrict__ l1_w1,
    float* __restrict__ y) {
  int idx = blk * 256 + threadIdx.x;
  int n = idx / 160, c = idx - n * 160;
  const float* xr = xin + (size_t)n * 160;
  float a = attr[n];
  if (c < 64) {
    float y_ = 0.f;
    #pragma unroll 8
    for (int u = 0; u < 64; ++u) y_ += xr[u] * l1_w0[u * 64 + c];
    y[(size_t)n * 192 + c] = y_ * a * 0.125f;
  } else {
    int t = c - 64; int v = t / 3, i = t - v * 3;
    float y_ = 0.f;
    #pragma unroll 8
    for (int u = 0; u < 32; ++u) y_ += xr[64 + u * 3 + i] * l1_w1[u * 32 + v];
    y[(size_t)n * 192 + 64 + v * 4 + i] = y_ * a * RS32;
    if (i == 2) y[(size_t)n * 192 + 64 + v * 4 + 3] = 0.f;
  }
}

// fused mid-stage: blocks [0,2500) = w_gemm, [2500,8750) = node_pre
__global__ __launch_bounds__(256) void k_mid(
    const float* __restrict__ ed2b, const float* __restrict__ fc0,
    const unsigned short* __restrict__ fc1p, unsigned short* __restrict__ wout,
    const float* __restrict__ xin, const float* __restrict__ attr,
    const float* __restrict__ l1_w0, const float* __restrict__ l1_w1,
    float* __restrict__ y) {
  __shared__ WgemmShared sh;
  if (blockIdx.x < 2500) {
    w_gemm_body(sh, blockIdx.x, ed2b, fc0, fc1p, wout);
  } else {
    node_pre_body(blockIdx.x - 2500, xin, attr, l1_w0, l1_w1, y);
  }
}

// node_agg: 2500 blocks x 4 waves, ONE NODE PER WAVE in degree-desc order.
// NEW (this round): the node's ed2a rows (SH + srcn, 48 B/edge, contiguous)
// are STAGED INTO THE WAVE'S LDS SCRATCH (reusing the epilogue R region, in
// chunks of 64 edges) with 3 coalesced nt float4 loads. This removes the
// ed2->srcn->y dependent global chain from the loop. The V pipeline is
// deepened 2->3 slots so each COMPUTE runs ~2 computes after its loads were
// issued. wbuf loads are non-temporal (read-once stream) to keep L2 for y.
#define WREG 960
__global__ __launch_bounds__(256, 4) void node_agg(
    const float* __restrict__ y, const float* __restrict__ xin,
    const float* __restrict__ attr, const float* __restrict__ ed2a,
    const unsigned short* __restrict__ wbuf,
    const int* __restrict__ order, const int* __restrict__ obeg,
    const int* __restrict__ ocnt,
    const float* __restrict__ sc_w0, const float* __restrict__ sc_w1,
    const float* __restrict__ w0, const float* __restrict__ w1,
    const float* __restrict__ w2, float* __restrict__ out) {
  __shared__ __align__(16) float smem[4 * WREG];
  int tid = threadIdx.x, wid = tid >> 6, lane = tid & 63, l31 = lane & 31;
  float* R = smem + wid * WREG;
  int gw = blockIdx.x * 4 + wid;
  // fixed per-lane byte offsets (loop-invariant)
  int voY  = 4 * lane;           // y scalar block
  int voX  = 256 + 16 * l31;     // y vector float4 {x0,x1,x2,0}
  int voAB = 4 * lane;           // wbuf AB
  int voC  = 256 + 2 * lane;     // wbuf C
  int voDG = 384 + 8 * l31;      // wbuf DEFG

// PEV: read edge idx's SH+srcn from LDS (fast), then issue the 5 global
// loads (y gather via srcn, wbuf via linear stride). Guard is wave-uniform.
#define PEV(S, idx)                                                            \
  if ((idx) < m) {                                                             \
    const f32x4* lp4 = (const f32x4*)(R + (idx) * 12);                         \
    PE0##S = lp4[0]; PE1##S = lp4[1]; PE2##S = lp4[2];                         \
    int srcn = __float_as_int(PE2##S.y);                                       \
    const char* yb = (const char*)y + (size_t)srcn * 768;                      \
    Y##S = *(const float*)(yb + voY);                                          \
    X##S = *(const f32x4*)(yb + voX);                                          \
    const char* wb = (const char*)wbuf + (size_t)(beg + ch + (idx)) * 640;     \
    AB##S = __builtin_nontemporal_load((const unsigned*)(wb + voAB));          \
    Cw##S = __builtin_nontemporal_load((const unsigned short*)(wb + voC));     \
    DG##S = __builtin_nontemporal_load((const u32x2*)(wb + voDG));             \
  }
#define COMPUTE(S)                                                             \
  {                                                                            \
    float e0 = PE0##S.x, ey = PE0##S.y, ez = PE0##S.z, ex = PE0##S.w;          \
    float q0 = PE1##S.x, q1 = PE1##S.y, q2 = PE1##S.z, q3 = PE1##S.w;          \
    float q4 = PE2##S.x;                                                       \
    float Yv = Y##S, x0 = X##S.x, x1 = X##S.y, x2 = X##S.z;                    \
    float vA = bf2f(AB##S), vB = bfhi(AB##S), vC = bf2f(Cw##S);                \
    float vD = bf2f(DG##S.x), vE = bfhi(DG##S.x);                              \
    float vF = bf2f(DG##S.y), vG = bfhi(DG##S.y);                              \
    aK0 += Yv * e0 * vA;                                                       \
    float tB = Yv * vB; aK2x += tB * ey; aK2y += tB * ez; aK2z += tB * ex;     \
    float tC = Yv * vC;                                                        \
    aK5a += tC * q0; aK5b += tC * q1; aK5c += tC * q2;                         \
    aK5d += tC * q3; aK5e += tC * q4;                                          \
    float t1 = x0 * ey + x1 * ez + x2 * ex; aK1 += (RS3 * vE) * t1;            \
    float s3 = e0 * vD; aK3x += x0 * s3; aK3y += x1 * s3; aK3z += x2 * s3;     \
    float s4 = SQ3_ * vG;                                                      \
    aK4x += s4 * (B_ * (x2 * q0 + x1 * q1 - x0 * q4) - A_ * x0 * q2);          \
    aK4y += s4 * (B_ * (x0 * q1 + x2 * q3) + 2.f * A_ * x1 * q2);              \
    aK4z += s4 * (B_ * (x0 * q0 + x1 * q3 + x2 * q4) - A_ * x2 * q2);          \
    float s6 = SQ5_ * vF;                                                      \
    aK6a += s6 * (-B_ * (x0 * ex + x2 * ey));                                  \
    aK6b += s6 * (-B_ * (x0 * ez + x1 * ey));                                  \
    aK6c += s6 * ( A_ * (x0 * ey + x2 * ex - 2.f * x1 * ez));                  \
    aK6d += s6 * (-B_ * (x1 * ex + x2 * ez));                                  \
    aK6e += s6 * ( B_ * (x0 * ey - x2 * ex));                                  \
  }
#define LWAIT __asm__ volatile("s_waitcnt lgkmcnt(0)" ::: "memory")

  int n = order[gw], beg = obeg[gw], cnt = ocnt[gw];

  float aK0 = 0.f, aK2x = 0.f, aK2y = 0.f, aK2z = 0.f;
  float aK5a = 0.f, aK5b = 0.f, aK5c = 0.f, aK5d = 0.f, aK5e = 0.f;
  float aK1 = 0.f, aK3x = 0.f, aK3y = 0.f, aK3z = 0.f;
  float aK4x = 0.f, aK4y = 0.f, aK4z = 0.f;
  float aK6a = 0.f, aK6b = 0.f, aK6c = 0.f, aK6d = 0.f, aK6e = 0.f;

  f32x4 PE0a, PE1a, PE2a, PE0b, PE1b, PE2b, PE0c, PE1c, PE2c;
  float Ya, Yb, Yc; f32x4 Xa, Xb, Xc;
  unsigned ABa, ABb, ABc; unsigned short Cwa, Cwb, Cwc;
  u32x2 DGa, DGb, DGc;

  for (int ch = 0; ch < cnt; ch += 64) {
    int m = cnt - ch; if (m > 64) m = 64;
    // stage chunk's ed2a rows (48 B each, contiguous) into wave-private LDS:
    // 3*m float4s, coalesced, non-temporal (read-once stream).
    {
      const f32x4* sp = (const f32x4*)(ed2a + (size_t)(beg + ch) * 12);
      f32x4* Lp = (f32x4*)R;
      int t3 = 3 * m;
      if (lane < t3)       Lp[lane]       = __builtin_nontemporal_load(sp + lane);
      if (lane + 64 < t3)  Lp[lane + 64]  = __builtin_nontemporal_load(sp + lane + 64);
      if (lane + 128 < t3) Lp[lane + 128] = __builtin_nontemporal_load(sp + lane + 128);
    }
    PEV(a, 0)
    PEV(b, 1)
    PEV(c, 2)
    int i = 0;
    while (i < m) {
      COMPUTE(a)
      PEV(a, i + 3)
      ++i; if (i >= m) break;
      COMPUTE(b)
      PEV(b, i + 3)
      ++i; if (i >= m) break;
      COMPUTE(c)
      PEV(c, i + 3)
      ++i;
    }
  }

  // epilogue: accs -> wave-private m (LDS) -> lin2 + fused lin1-s + combine
  R[lane]            = aK0  * QDEG;
  R[96 + 3 * lane]   = aK2x * QDEG;
  R[97 + 3 * lane]   = aK2y * QDEG;
  R[98 + 3 * lane]   = aK2z * QDEG;
  R[480 + 5 * lane]  = aK5a * QDEG;
  R[481 + 5 * lane]  = aK5b * QDEG;
  R[482 + 5 * lane]  = aK5c * QDEG;
  R[483 + 5 * lane]  = aK5d * QDEG;
  R[484 + 5 * lane]  = aK5e * QDEG;
  if (lane < 32) {
    R[64 + lane]       = aK1  * QDEG;
    R[288 + 3 * lane]  = aK3x * QDEG;
    R[289 + 3 * lane]  = aK3y * QDEG;
    R[290 + 3 * lane]  = aK3z * QDEG;
    R[384 + 3 * lane]  = aK4x * QDEG;
    R[385 + 3 * lane]  = aK4y * QDEG;
    R[386 + 3 * lane]  = aK4z * QDEG;
    R[800 + 5 * lane]  = aK6a * QDEG;
    R[801 + 5 * lane]  = aK6b * QDEG;
    R[802 + 5 * lane]  = aK6c * QDEG;
    R[803 + 5 * lane]  = aK6d * QDEG;
    R[804 + 5 * lane]  = aK6e * QDEG;
  }
  LWAIT;
  float a = attr[n];
  const float* xr = xin + (size_t)n * 160;
  float* orow = out + (size_t)n * 320;
  #pragma unroll
  for (int jo = 0; jo < 5; ++jo) {
    int oc = lane + 64 * jo;
    float res;
    if (oc < 64) {
      float o = 0.f, sv = 0.f;
      #pragma unroll 8
      for (int u = 0; u < 96; ++u) o += R[u] * w0[u * 64 + oc];
      #pragma unroll 8
      for (int u = 0; u < 64; ++u) sv += xr[u] * sc_w0[u * 64 + oc];
      res = CS_ * (sv * a * 0.125f) + CX_ * (o * a * RS96);
    } else if (oc < 160) {
      int t2 = oc - 64, v = t2 / 3, ii = t2 - v * 3;
      float o = 0.f, sv = 0.f;
      #pragma unroll 8
      for (int u = 0; u < 128; ++u) o += R[96 + u * 3 + ii] * w1[u * 32 + v];
      #pragma unroll 8
      for (int u = 0; u < 32; ++u) sv += xr[64 + u * 3 + ii] * sc_w1[u * 32 + v];
      res = CS_ * (sv * a * RS32) + CX_ * (o * a * RS128);
    } else {
      int t2 = oc - 160, v = t2 / 5, kk = t2 - v * 5;
      float o = 0.f;
      #pragma unroll 8
      for (int u = 0; u < 96; ++u) o += R[480 + u * 5 + kk] * w2[u * 32 + v];
      res = o * a * RS96;
    }
    orow[oc] = res;
  }
#undef PEV
#undef COMPUTE
#undef LWAIT
}

extern "C" void kernel_launch(void* const* d_in, const int* in_sizes, int n_in,
                              void* d_out, int out_size, void* d_ws, size_t ws_size,
                              hipStream_t stream) {
  const float* node_input = (const float*)d_in[0];
  const float* node_attr  = (const float*)d_in[1];
  const int*   edge_src   = (const int*)d_in[2];
  const int*   edge_dst   = (const int*)d_in[3];
  const float* edge_attr  = (const float*)d_in[4];
  const float* ele        = (const float*)d_in[5];
  const float* sc_w0      = (const float*)d_in[6];
  const float* sc_w1      = (const float*)d_in[7];
  const float* l1_w0      = (const float*)d_in[8];
  const float* l1_w1      = (const float*)d_in[9];
  const float* fc_w0      = (const float*)d_in[10];
  const float* fc_w1      = (const float*)d_in[11];
  const float* l2_w0      = (const float*)d_in[12];
  const float* l2_w1      = (const float*)d_in[13];
  const float* l2_w2      = (const float*)d_in[14];
  float* out = (float*)d_out;

  char* base = (char*)d_ws;
  float* y              = (float*)(base);                       // 7.68 MB (stride 192)
  unsigned short* wbuf  = (unsigned short*)(base + 7680000);    // 102.4 MB packed
  float* ed2a           = (float*)(base + 110080000);           // 7.68 MB (stride 12)
  float* ed2b           = (float*)(base + 117760000);           // 5.12 MB (stride 8)
  int* counts           = (int*)(base + 122880000);
  int* offs             = (int*)(base + 122920000);
  int* cur              = (int*)(base + 122960000);
  int* order            = (int*)(base + 123000000);
  int* obeg             = (int*)(base + 123040000);
  int* ocnt             = (int*)(base + 123080000);
  int* dcur             = (int*)(base + 123120000);             // 1 KB
  unsigned short* fc1p  = (unsigned short*)(base + 123121024);  // 40 KB

  hipLaunchKernelGGL(k_init, dim3(80), dim3(256), 0, stream, counts, fc_w1, fc1p);
  hipLaunchKernelGGL(k_hist, dim3((N_EDGES + 255) / 256), dim3(256), 0, stream,
                     edge_dst, counts);
  hipLaunchKernelGGL(k_scan, dim3(1), dim3(256), 0, stream, counts, offs, cur, dcur);
  hipLaunchKernelGGL(k_perm, dim3(N_EDGES / 256), dim3(256), 0, stream,
                     edge_dst, cur, counts, offs, dcur, order, obeg, ocnt,
                     ele, edge_attr, edge_src, ed2a, ed2b);
  hipLaunchKernelGGL(k_mid, dim3(2500 + 6250), dim3(256), 0, stream,
                     ed2b, fc_w0, fc1p, wbuf,
                     node_input, node_attr, l1_w0, l1_w1, y);
  hipLaunchKernelGGL(node_agg, dim3(2500), dim3(256), 0, stream,
                     y, node_input, node_attr, ed2a, wbuf,
                     order, obeg, ocnt, sc_w0, sc_w1, l2_w0, l2_w1, l2_w2, out);
}

// Round 2
// 285.158 us; speedup vs baseline: 2.6174x; 2.6174x over previous
//
#include <hip/hip_runtime.h>
#include <cstddef>
#include <cstdint>

#define N_NODES 10000
#define N_EDGES 160000

// ---- constants ----
#define RS8    0.35355339059327373f   // 1/sqrt(8)
#define RS32   0.17677669529663687f   // 1/sqrt(32)
#define RS96   0.10206207261596575f   // 1/sqrt(96)
#define RS128  0.08838834764831845f   // 1/sqrt(128)
#define RS3    0.5773502691896258f    // 1/sqrt(3)
#define SQ3_   1.7320508075688772f
#define SQ5_   2.23606797749979f
#define A_     0.18257418583505536f   // 1/sqrt(30)
#define B_     0.31622776601683794f   // 1/sqrt(10)
#define SILU_C_ 1.6765208f
#define CS_    0.3826834323650898f    // sin(pi/8)
#define CX_    0.9238795325112867f    // cos(pi/8)
#define QDEG   0.25f                  // 1/sqrt(16)

typedef __attribute__((ext_vector_type(8))) short bf16x8;
typedef __attribute__((ext_vector_type(4))) float f32x4;
typedef __attribute__((ext_vector_type(2))) unsigned u32x2;
typedef __attribute__((ext_vector_type(4))) unsigned u32x4;

__device__ inline float bf2f(unsigned v) {
  union { unsigned u; float f; } c; c.u = v << 16; return c.f;
}
__device__ inline float bfhi(unsigned v) {   // float from HIGH 16 bits
  union { unsigned u; float f; } c; c.u = v & 0xffff0000u; return c.f;
}
__device__ inline unsigned short f2bf(float f) {
  union { float f; unsigned u; } c; c.f = f;
  unsigned r = c.u + 0x7fff + ((c.u >> 16) & 1);
  return (unsigned short)(r >> 16);
}
__device__ inline unsigned pack2bf(float a, float b) {
  return (unsigned)f2bf(a) | ((unsigned)f2bf(b) << 16);
}

// zero counts + build fc1p (fc1 64x320 f32 -> bf16 MFMA B-fragment order)
__global__ void k_init(int* __restrict__ counts, const float* __restrict__ fc1,
                       unsigned short* __restrict__ fc1p) {
  int i = blockIdx.x * blockDim.x + threadIdx.x;
  if (i < N_NODES) counts[i] = 0;
  if (i < 20480) {
    int j = i & 7, q = (i >> 3) & 3, n = (i >> 5) & 15, kq = (i >> 9) & 1, t = i >> 10;
    int k = kq * 32 + q * 8 + j;
    fc1p[i] = f2bf(fc1[k * 320 + t * 16 + n]);
  }
}

__global__ void k_hist(const int* __restrict__ edst, int* __restrict__ counts) {
  int e = blockIdx.x * blockDim.x + threadIdx.x;
  if (e < N_EDGES) atomicAdd(&counts[edst[e]], 1);
}

// exclusive scan of counts -> offs/cur; degree histogram + descending-degree
// exclusive scan -> dcur (single block).
__global__ __launch_bounds__(256) void k_scan(const int* __restrict__ counts,
                                              int* __restrict__ offs,
                                              int* __restrict__ cur,
                                              int* __restrict__ dcur) {
  __shared__ int ps[256];
  __shared__ int dbin[256];
  int t = threadIdx.x;
  dbin[t] = 0;
  int base = t * 40;
  int sum = 0;
  for (int i = 0; i < 40; ++i) {
    int idx = base + i;
    if (idx < N_NODES) sum += counts[idx];
  }
  ps[t] = sum;
  __syncthreads();
  for (int off = 1; off < 256; off <<= 1) {
    int v = (t >= off) ? ps[t - off] : 0;
    __syncthreads();
    ps[t] += v;
    __syncthreads();
  }
  int run = (t == 0) ? 0 : ps[t - 1];
  for (int i = 0; i < 40; ++i) {
    int idx = base + i;
    if (idx < N_NODES) {
      int c = counts[idx];
      offs[idx] = run; cur[idx] = run;
      run += c;
      atomicAdd(&dbin[c < 255 ? c : 255], 1);
    }
  }
  __syncthreads();
  int rb = 255 - t;
  int v = dbin[rb];
  __syncthreads();
  ps[t] = v;
  __syncthreads();
  for (int off = 1; off < 256; off <<= 1) {
    int u = (t >= off) ? ps[t - off] : 0;
    __syncthreads();
    ps[t] += u;
    __syncthreads();
  }
  dcur[rb] = ps[t] - v;
}

// Permute kernel: per edge compute sorted position p and SCATTER-WRITE two
// permuted per-edge streams:
//   ed2a (stride 12 f): [0..8]=SH, [9]=src, [10,11]=pad   (node_agg input)
//   ed2b (stride  8 f): ele row                            (w_gemm input)
// Inputs staged coalesced in LDS. Also the node scatter (descending-degree
// rank -> order/obeg/ocnt).
__global__ __launch_bounds__(256) void k_perm(
    const int* __restrict__ edst, int* __restrict__ cur,
    const int* __restrict__ counts, const int* __restrict__ offs,
    int* __restrict__ dcur, int* __restrict__ order,
    int* __restrict__ obeg, int* __restrict__ ocnt,
    const float* __restrict__ ele, const float* __restrict__ eattr,
    const int* __restrict__ esrc, float* __restrict__ ed2a,
    float* __restrict__ ed2b) {
  __shared__ __align__(16) float sh_ea[256 * 9];
  __shared__ __align__(16) float sh_el[256 * 8];
  int t = threadIdx.x;
  int eb = blockIdx.x * 256;
  int e = eb + t;
  for (int i = t; i < 2304; i += 256) sh_ea[i] = eattr[(size_t)eb * 9 + i];
  {
    const float4* src = (const float4*)(ele + (size_t)eb * 8);
    float4* dst = (float4*)sh_el;
    dst[t] = src[t]; dst[t + 256] = src[t + 256];
  }
  __syncthreads();
  int d = edst[e];
  int p = atomicAdd(&cur[d], 1);
  const float* ea = sh_ea + t * 9;
  const float* el = sh_el + t * 8;
  float4 r0 = {ea[0], ea[1], ea[2], ea[3]};
  float4 r1 = {ea[4], ea[5], ea[6], ea[7]};
  float4 r2 = {ea[8], __int_as_float(esrc[e]), 0.f, 0.f};
  float4* da = (float4*)(ed2a + (size_t)p * 12);
  da[0] = r0; da[1] = r1; da[2] = r2;
  float4 r3 = {el[0], el[1], el[2], el[3]};
  float4 r4 = {el[4], el[5], el[6], el[7]};
  float4* db = (float4*)(ed2b + (size_t)p * 8);
  db[0] = r3; db[1] = r4;
  if (e < N_NODES) {
    int c = counts[e];
    int b = c < 255 ? c : 255;
    int q = atomicAdd(&dcur[b], 1);
    order[q] = e; obeg[q] = offs[e]; ocnt[q] = c;
  }
}

__device__ inline f32x4 wtile(const unsigned short* __restrict__ fc1p,
                              bf16x8 a0, bf16x8 a1, int mrow, int quad, int t) {
  f32x4 acc = {0.f, 0.f, 0.f, 0.f};
  bf16x8 b0 = *(const bf16x8*)(fc1p + ((size_t)((t * 2 + 0) * 16 + mrow) * 4 + quad) * 8);
  bf16x8 b1 = *(const bf16x8*)(fc1p + ((size_t)((t * 2 + 1) * 16 + mrow) * 4 + quad) * 8);
  acc = __builtin_amdgcn_mfma_f32_16x16x32_bf16(b0, a0, acc, 0, 0, 0);
  acc = __builtin_amdgcn_mfma_f32_16x16x32_bf16(b1, a1, acc, 0, 0, 0);
  return acc;
}

struct WgemmShared {
  __align__(16) float ele[64][8];
  __align__(16) unsigned short h[64 * 72];   // 72-stride pad
};

// STREAMING MFMA radial GEMM: 64 edges/block, reads ele slices from the
// already-permuted ed2b (sequential), writes packed wbuf (640 B/edge,
// NON-TEMPORAL stores — write-once, read much later): [0,256) AB
// interleaved; [256,384) C; [384,640) DEFG interleaved.
__device__ void w_gemm_body(WgemmShared& sh, int blk,
    const float* __restrict__ ed2b, const float* __restrict__ fc0,
    const unsigned short* __restrict__ fc1p, unsigned short* __restrict__ wout) {
  int t = threadIdx.x;
  int eb = blk * 64;
  if (t < 128) {
    int e = t >> 1, hh = t & 1;
    ((float4*)&sh.ele[e][0])[hh] =
        *(const float4*)(ed2b + (size_t)(eb + e) * 8 + hh * 4);
  }
  __syncthreads();
  #pragma unroll
  for (int ii = 0; ii < 16; ++ii) {
    int idx = t + ii * 256;
    int e = idx >> 6, k = idx & 63;
    float acc = 0.f;
    #pragma unroll
    for (int m = 0; m < 8; ++m) acc += sh.ele[e][m] * fc0[m * 64 + k];
    acc *= RS8;
    float hv = SILU_C_ * acc / (1.f + __expf(-acc));
    sh.h[e * 72 + k] = f2bf(hv);
  }
  __syncthreads();

  int wv = t >> 6, lane = t & 63;
  int m0 = wv * 16;
  int mrow = lane & 15, quad = lane >> 4;
  bf16x8 a0 = *(const bf16x8*)(sh.h + (m0 + mrow) * 72 + quad * 8);
  bf16x8 a1 = *(const bf16x8*)(sh.h + (m0 + mrow) * 72 + 32 + quad * 8);
  char* wbase = (char*)wout + (size_t)(eb + m0 + mrow) * 640;
  const float K = 0.125f;
  #pragma unroll
  for (int tt = 0; tt < 4; ++tt) {
    f32x4 Av = wtile(fc1p, a0, a1, mrow, quad, tt);
    f32x4 Bv = wtile(fc1p, a0, a1, mrow, quad, tt + 4);
    u32x4 st;
    st.x = pack2bf(Av[0] * K, Bv[0] * K);
    st.y = pack2bf(Av[1] * K, Bv[1] * K);
    st.z = pack2bf(Av[2] * K, Bv[2] * K);
    st.w = pack2bf(Av[3] * K, Bv[3] * K);
    __builtin_nontemporal_store(st, (u32x4*)(wbase + 64 * tt + 16 * quad));
  }
  #pragma unroll
  for (int tt = 8; tt < 12; ++tt) {
    f32x4 Cv = wtile(fc1p, a0, a1, mrow, quad, tt);
    u32x2 st;
    st.x = pack2bf(Cv[0] * K, Cv[1] * K);
    st.y = pack2bf(Cv[2] * K, Cv[3] * K);
    __builtin_nontemporal_store(st, (u32x2*)(wbase + 256 + 32 * (tt - 8) + 8 * quad));
  }
  #pragma unroll
  for (int tt = 12; tt < 14; ++tt) {
    f32x4 Dv = wtile(fc1p, a0, a1, mrow, quad, tt);
    f32x4 Ev = wtile(fc1p, a0, a1, mrow, quad, tt + 2);
    f32x4 Fv = wtile(fc1p, a0, a1, mrow, quad, tt + 4);
    f32x4 Gv = wtile(fc1p, a0, a1, mrow, quad, tt + 6);
    char* db = wbase + 384 + 128 * (tt - 12) + 32 * quad;
    u32x4 s0, s1;
    s0.x = pack2bf(Dv[0] * K, Ev[0] * K); s0.y = pack2bf(Fv[0] * K, Gv[0] * K);
    s0.z = pack2bf(Dv[1] * K, Ev[1] * K); s0.w = pack2bf(Fv[1] * K, Gv[1] * K);
    s1.x = pack2bf(Dv[2] * K, Ev[2] * K); s1.y = pack2bf(Fv[2] * K, Gv[2] * K);
    s1.z = pack2bf(Dv[3] * K, Ev[3] * K); s1.w = pack2bf(Fv[3] * K, Gv[3] * K);
    __builtin_nontemporal_store(s0, (u32x4*)(db));
    __builtin_nontemporal_store(s1, (u32x4*)(db + 16));
  }
}

// y PADDED (stride 192 f): [0,64) scalar, vector channel u' as float4
// {x0,x1,x2,0} at 64+4u'. (s is computed in node_agg's epilogue now.)
__device__ void node_pre_body(int blk,
    const float* __restrict__ xin, const float* __restrict__ attr,
    const float* __restrict__ l1_w0, const float* __restrict__ l1_w1,
    float* __restrict__ y) {
  int idx = blk * 256 + threadIdx.x;
  int n = idx / 160, c = idx - n * 160;
  const float* xr = xin + (size_t)n * 160;
  float a = attr[n];
  if (c < 64) {
    float y_ = 0.f;
    #pragma unroll 8
    for (int u = 0; u < 64; ++u) y_ += xr[u] * l1_w0[u * 64 + c];
    y[(size_t)n * 192 + c] = y_ * a * 0.125f;
  } else {
    int t = c - 64; int v = t / 3, i = t - v * 3;
    float y_ = 0.f;
    #pragma unroll 8
    for (int u = 0; u < 32; ++u) y_ += xr[64 + u * 3 + i] * l1_w1[u * 32 + v];
    y[(size_t)n * 192 + 64 + v * 4 + i] = y_ * a * RS32;
    if (i == 2) y[(size_t)n * 192 + 64 + v * 4 + 3] = 0.f;
  }
}

// fused mid-stage: blocks [0,2500) = w_gemm, [2500,8750) = node_pre
__global__ __launch_bounds__(256) void k_mid(
    const float* __restrict__ ed2b, const float* __restrict__ fc0,
    const unsigned short* __restrict__ fc1p, unsigned short* __restrict__ wout,
    const float* __restrict__ xin, const float* __restrict__ attr,
    const float* __restrict__ l1_w0, const float* __restrict__ l1_w1,
    float* __restrict__ y) {
  __shared__ WgemmShared sh;
  if (blockIdx.x < 2500) {
    w_gemm_body(sh, blockIdx.x, ed2b, fc0, fc1p, wout);
  } else {
    node_pre_body(blockIdx.x - 2500, xin, attr, l1_w0, l1_w1, y);
  }
}

// node_agg: 2500 blocks x 4 waves, ONE NODE PER WAVE in degree-desc order.
// Round-0 proven 2-slot pipeline shape (64 VGPR, no spill) with two
// register-neutral scheduling fixes:
//  (1) srcn prefetched 2 half-iterations ahead into 1-reg slots SNa/SNb —
//      removes the E->srcn->V full-latency stall at every V issue.
//  (2) wbuf loads (linear address, srcn-independent) moved from the V
//      bundle (distance 1) to the E position (distance 2) — 2x latency
//      cover on the 102 MB HBM stream, same registers.
#define WREG 960
__global__ __launch_bounds__(256) void node_agg(
    const float* __restrict__ y, const float* __restrict__ xin,
    const float* __restrict__ attr, const float* __restrict__ ed2a,
    const unsigned short* __restrict__ wbuf,
    const int* __restrict__ order, const int* __restrict__ obeg,
    const int* __restrict__ ocnt,
    const float* __restrict__ sc_w0, const float* __restrict__ sc_w1,
    const float* __restrict__ w0, const float* __restrict__ w1,
    const float* __restrict__ w2, float* __restrict__ out) {
  __shared__ __align__(16) float smem[4 * WREG];
  int tid = threadIdx.x, wid = tid >> 6, lane = tid & 63, l31 = lane & 31;
  float* R = smem + wid * WREG;
  int gw = blockIdx.x * 4 + wid;
  // fixed per-lane byte offsets (loop-invariant)
  int voY  = 4 * lane;           // y scalar block
  int voX  = 256 + 16 * l31;     // y vector float4 {x0,x1,x2,0}
  int voAB = 4 * lane;           // wbuf AB
  int voC  = 256 + 2 * lane;     // wbuf C
  int voDG = 384 + 8 * l31;      // wbuf DEFG

#define E_LOAD(S, idx)                                                         \
  if ((idx) < cnt) {                                                           \
    const float4* ep = (const float4*)(ed2a + (size_t)(beg + (idx)) * 12);     \
    PE0##S = ep[0]; PE1##S = ep[1]; PE2##S = ep[2];                            \
  }
#define W_LOAD(S, idx)                                                         \
  if ((idx) < cnt) {                                                           \
    const char* wb = (const char*)wbuf + (size_t)(beg + (idx)) * 640;          \
    AB##S = *(const unsigned*)(wb + voAB);                                     \
    Cw##S = *(const unsigned short*)(wb + voC);                                \
    DG##S = *(const uint2*)(wb + voDG);                                        \
  }
#define S_LOAD(S, idx)                                                         \
  if ((idx) < cnt) {                                                           \
    SN##S = __float_as_int(ed2a[(size_t)(beg + (idx)) * 12 + 9]);              \
  }
#define V_LOAD(S, idx)                                                         \
  if ((idx) < cnt) {                                                           \
    const char* yb = (const char*)y + (size_t)SN##S * 768;                     \
    Y##S = *(const float*)(yb + voY);                                          \
    X##S = *(const f32x4*)(yb + voX);                                          \
  }
#define COMPUTE(S)                                                             \
  {                                                                            \
    float e0 = PE0##S.x, ey = PE0##S.y, ez = PE0##S.z, ex = PE0##S.w;          \
    float q0 = PE1##S.x, q1 = PE1##S.y, q2 = PE1##S.z, q3 = PE1##S.w;          \
    float q4 = PE2##S.x;                                                       \
    float Yv = Y##S, x0 = X##S.x, x1 = X##S.y, x2 = X##S.z;                    \
    float vA = bf2f(AB##S), vB = bfhi(AB##S), vC = bf2f(Cw##S);                \
    float vD = bf2f(DG##S.x), vE = bfhi(DG##S.x);                              \
    float vF = bf2f(DG##S.y), vG = bfhi(DG##S.y);                              \
    aK0 += Yv * e0 * vA;                                                       \
    float tB = Yv * vB; aK2x += tB * ey; aK2y += tB * ez; aK2z += tB * ex;     \
    float tC = Yv * vC;                                                        \
    aK5a += tC * q0; aK5b += tC * q1; aK5c += tC * q2;                         \
    aK5d += tC * q3; aK5e += tC * q4;                                          \
    float t1 = x0 * ey + x1 * ez + x2 * ex; aK1 += (RS3 * vE) * t1;            \
    float s3 = e0 * vD; aK3x += x0 * s3; aK3y += x1 * s3; aK3z += x2 * s3;     \
    float s4 = SQ3_ * vG;                                                      \
    aK4x += s4 * (B_ * (x2 * q0 + x1 * q1 - x0 * q4) - A_ * x0 * q2);          \
    aK4y += s4 * (B_ * (x0 * q1 + x2 * q3) + 2.f * A_ * x1 * q2);              \
    aK4z += s4 * (B_ * (x0 * q0 + x1 * q3 + x2 * q4) - A_ * x2 * q2);          \
    float s6 = SQ5_ * vF;                                                      \
    aK6a += s6 * (-B_ * (x0 * ex + x2 * ey));                                  \
    aK6b += s6 * (-B_ * (x0 * ez + x1 * ey));                                  \
    aK6c += s6 * ( A_ * (x0 * ey + x2 * ex - 2.f * x1 * ez));                  \
    aK6d += s6 * (-B_ * (x1 * ex + x2 * ez));                                  \
    aK6e += s6 * ( B_ * (x0 * ey - x2 * ex));                                  \
  }
#define LWAIT __asm__ volatile("s_waitcnt lgkmcnt(0)" ::: "memory")

  int n = order[gw], beg = obeg[gw], cnt = ocnt[gw];

  float aK0 = 0.f, aK2x = 0.f, aK2y = 0.f, aK2z = 0.f;
  float aK5a = 0.f, aK5b = 0.f, aK5c = 0.f, aK5d = 0.f, aK5e = 0.f;
  float aK1 = 0.f, aK3x = 0.f, aK3y = 0.f, aK3z = 0.f;
  float aK4x = 0.f, aK4y = 0.f, aK4z = 0.f;
  float aK6a = 0.f, aK6b = 0.f, aK6c = 0.f, aK6d = 0.f, aK6e = 0.f;

  float4 PE0a, PE1a, PE2a, PE0b, PE1b, PE2b;
  float Ya, Yb; f32x4 Xa, Xb;
  unsigned ABa, ABb; unsigned short Cwa, Cwb;
  uint2 DGa, DGb;
  int SNa, SNb;

  E_LOAD(a, 0)
  E_LOAD(b, 1)
  W_LOAD(a, 0)
  W_LOAD(b, 1)
  S_LOAD(b, 1)
  S_LOAD(a, 2)
  // first V for slot a (edge 0): srcn straight from PE2a (one-time stall)
  if (0 < cnt) {
    int srcn0 = __float_as_int(PE2a.y);
    const char* yb = (const char*)y + (size_t)srcn0 * 768;
    Ya = *(const float*)(yb + voY);
    Xa = *(const f32x4*)(yb + voX);
  }

  int i = 0;
  while (i < cnt) {
    V_LOAD(b, i + 1)      // uses SNb (srcn[i+1], prefetched 2 halves ago)
    S_LOAD(b, i + 3)      // refill SNb for edge i+3
    COMPUTE(a)            // edge i
    E_LOAD(a, i + 2)
    W_LOAD(a, i + 2)
    ++i; if (i >= cnt) break;
    V_LOAD(a, i + 1)      // uses SNa
    S_LOAD(a, i + 3)
    COMPUTE(b)            // edge i
    E_LOAD(b, i + 2)
    W_LOAD(b, i + 2)
    ++i;
  }

  // epilogue: accs -> wave-private m (LDS) -> lin2 + fused lin1-s + combine
  R[lane]            = aK0  * QDEG;
  R[96 + 3 * lane]   = aK2x * QDEG;
  R[97 + 3 * lane]   = aK2y * QDEG;
  R[98 + 3 * lane]   = aK2z * QDEG;
  R[480 + 5 * lane]  = aK5a * QDEG;
  R[481 + 5 * lane]  = aK5b * QDEG;
  R[482 + 5 * lane]  = aK5c * QDEG;
  R[483 + 5 * lane]  = aK5d * QDEG;
  R[484 + 5 * lane]  = aK5e * QDEG;
  if (lane < 32) {
    R[64 + lane]       = aK1  * QDEG;
    R[288 + 3 * lane]  = aK3x * QDEG;
    R[289 + 3 * lane]  = aK3y * QDEG;
    R[290 + 3 * lane]  = aK3z * QDEG;
    R[384 + 3 * lane]  = aK4x * QDEG;
    R[385 + 3 * lane]  = aK4y * QDEG;
    R[386 + 3 * lane]  = aK4z * QDEG;
    R[800 + 5 * lane]  = aK6a * QDEG;
    R[801 + 5 * lane]  = aK6b * QDEG;
    R[802 + 5 * lane]  = aK6c * QDEG;
    R[803 + 5 * lane]  = aK6d * QDEG;
    R[804 + 5 * lane]  = aK6e * QDEG;
  }
  LWAIT;
  float a = attr[n];
  const float* xr = xin + (size_t)n * 160;
  float* orow = out + (size_t)n * 320;
  #pragma unroll
  for (int jo = 0; jo < 5; ++jo) {
    int oc = lane + 64 * jo;
    float res;
    if (oc < 64) {
      float o = 0.f, sv = 0.f;
      #pragma unroll 8
      for (int u = 0; u < 96; ++u) o += R[u] * w0[u * 64 + oc];
      #pragma unroll 8
      for (int u = 0; u < 64; ++u) sv += xr[u] * sc_w0[u * 64 + oc];
      res = CS_ * (sv * a * 0.125f) + CX_ * (o * a * RS96);
    } else if (oc < 160) {
      int t2 = oc - 64, v = t2 / 3, ii = t2 - v * 3;
      float o = 0.f, sv = 0.f;
      #pragma unroll 8
      for (int u = 0; u < 128; ++u) o += R[96 + u * 3 + ii] * w1[u * 32 + v];
      #pragma unroll 8
      for (int u = 0; u < 32; ++u) sv += xr[64 + u * 3 + ii] * sc_w1[u * 32 + v];
      res = CS_ * (sv * a * RS32) + CX_ * (o * a * RS128);
    } else {
      int t2 = oc - 160, v = t2 / 5, kk = t2 - v * 5;
      float o = 0.f;
      #pragma unroll 8
      for (int u = 0; u < 96; ++u) o += R[480 + u * 5 + kk] * w2[u * 32 + v];
      res = o * a * RS96;
    }
    orow[oc] = res;
  }
#undef E_LOAD
#undef W_LOAD
#undef S_LOAD
#undef V_LOAD
#undef COMPUTE
#undef LWAIT
}

extern "C" void kernel_launch(void* const* d_in, const int* in_sizes, int n_in,
                              void* d_out, int out_size, void* d_ws, size_t ws_size,
                              hipStream_t stream) {
  const float* node_input = (const float*)d_in[0];
  const float* node_attr  = (const float*)d_in[1];
  const int*   edge_src   = (const int*)d_in[2];
  const int*   edge_dst   = (const int*)d_in[3];
  const float* edge_attr  = (const float*)d_in[4];
  const float* ele        = (const float*)d_in[5];
  const float* sc_w0      = (const float*)d_in[6];
  const float* sc_w1      = (const float*)d_in[7];
  const float* l1_w0      = (const float*)d_in[8];
  const float* l1_w1      = (const float*)d_in[9];
  const float* fc_w0      = (const float*)d_in[10];
  const float* fc_w1      = (const float*)d_in[11];
  const float* l2_w0      = (const float*)d_in[12];
  const float* l2_w1      = (const float*)d_in[13];
  const float* l2_w2      = (const float*)d_in[14];
  float* out = (float*)d_out;

  char* base = (char*)d_ws;
  float* y              = (float*)(base);                       // 7.68 MB (stride 192)
  unsigned short* wbuf  = (unsigned short*)(base + 7680000);    // 102.4 MB packed
  float* ed2a           = (float*)(base + 110080000);           // 7.68 MB (stride 12)
  float* ed2b           = (float*)(base + 117760000);           // 5.12 MB (stride 8)
  int* counts           = (int*)(base + 122880000);
  int* offs             = (int*)(base + 122920000);
  int* cur              = (int*)(base + 122960000);
  int* order            = (int*)(base + 123000000);
  int* obeg             = (int*)(base + 123040000);
  int* ocnt             = (int*)(base + 123080000);
  int* dcur             = (int*)(base + 123120000);             // 1 KB
  unsigned short* fc1p  = (unsigned short*)(base + 123121024);  // 40 KB

  hipLaunchKernelGGL(k_init, dim3(80), dim3(256), 0, stream, counts, fc_w1, fc1p);
  hipLaunchKernelGGL(k_hist, dim3((N_EDGES + 255) / 256), dim3(256), 0, stream,
                     edge_dst, counts);
  hipLaunchKernelGGL(k_scan, dim3(1), dim3(256), 0, stream, counts, offs, cur, dcur);
  hipLaunchKernelGGL(k_perm, dim3(N_EDGES / 256), dim3(256), 0, stream,
                     edge_dst, cur, counts, offs, dcur, order, obeg, ocnt,
                     ele, edge_attr, edge_src, ed2a, ed2b);
  hipLaunchKernelGGL(k_mid, dim3(2500 + 6250), dim3(256), 0, stream,
                     ed2b, fc_w0, fc1p, wbuf,
                     node_input, node_attr, l1_w0, l1_w1, y);
  hipLaunchKernelGGL(node_agg, dim3(2500), dim3(256), 0, stream,
                     y, node_input, node_attr, ed2a, wbuf,
                     order, obeg, ocnt, sc_w0, sc_w1, l2_w0, l2_w1, l2_w2, out);
}

// Round 4
// 276.114 us; speedup vs baseline: 2.7032x; 1.0328x over previous
//
#include <hip/hip_runtime.h>
#include <cstddef>
#include <cstdint>

#define N_NODES 10000
#define N_EDGES 160000

// ---- constants ----
#define RS8    0.35355339059327373f   // 1/sqrt(8)
#define RS32   0.17677669529663687f   // 1/sqrt(32)
#define RS96   0.10206207261596575f   // 1/sqrt(96)
#define RS128  0.08838834764831845f   // 1/sqrt(128)
#define RS3    0.5773502691896258f    // 1/sqrt(3)
#define SQ3_   1.7320508075688772f
#define SQ5_   2.23606797749979f
#define A_     0.18257418583505536f   // 1/sqrt(30)
#define B_     0.31622776601683794f   // 1/sqrt(10)
#define SILU_C_ 1.6765208f
#define CS_    0.3826834323650898f    // sin(pi/8)
#define CX_    0.9238795325112867f    // cos(pi/8)
#define QDEG   0.25f                  // 1/sqrt(16)

typedef __attribute__((ext_vector_type(8))) short bf16x8;
typedef __attribute__((ext_vector_type(4))) float f32x4;

__device__ inline float bf2f(unsigned v) {
  union { unsigned u; float f; } c; c.u = v << 16; return c.f;
}
__device__ inline float bfhi(unsigned v) {   // float from HIGH 16 bits
  union { unsigned u; float f; } c; c.u = v & 0xffff0000u; return c.f;
}
__device__ inline unsigned short f2bf(float f) {
  union { float f; unsigned u; } c; c.f = f;
  unsigned r = c.u + 0x7fff + ((c.u >> 16) & 1);
  return (unsigned short)(r >> 16);
}
__device__ inline unsigned pack2bf(float a, float b) {
  return (unsigned)f2bf(a) | ((unsigned)f2bf(b) << 16);
}

// zero counts + build fc1p (fc1 64x320 f32 -> bf16 MFMA B-fragment order)
__global__ void k_init(int* __restrict__ counts, const float* __restrict__ fc1,
                       unsigned short* __restrict__ fc1p) {
  int i = blockIdx.x * blockDim.x + threadIdx.x;
  if (i < N_NODES) counts[i] = 0;
  if (i < 20480) {
    int j = i & 7, q = (i >> 3) & 3, n = (i >> 5) & 15, kq = (i >> 9) & 1, t = i >> 10;
    int k = kq * 32 + q * 8 + j;
    fc1p[i] = f2bf(fc1[k * 320 + t * 16 + n]);
  }
}

__global__ void k_hist(const int* __restrict__ edst, int* __restrict__ counts) {
  int e = blockIdx.x * blockDim.x + threadIdx.x;
  if (e < N_EDGES) atomicAdd(&counts[edst[e]], 1);
}

// exclusive scan of counts -> offs/cur; degree histogram + descending-degree
// exclusive scan -> dcur (single block).
__global__ __launch_bounds__(256) void k_scan(const int* __restrict__ counts,
                                              int* __restrict__ offs,
                                              int* __restrict__ cur,
                                              int* __restrict__ dcur) {
  __shared__ int ps[256];
  __shared__ int dbin[256];
  int t = threadIdx.x;
  dbin[t] = 0;
  int base = t * 40;
  int sum = 0;
  for (int i = 0; i < 40; ++i) {
    int idx = base + i;
    if (idx < N_NODES) sum += counts[idx];
  }
  ps[t] = sum;
  __syncthreads();
  for (int off = 1; off < 256; off <<= 1) {
    int v = (t >= off) ? ps[t - off] : 0;
    __syncthreads();
    ps[t] += v;
    __syncthreads();
  }
  int run = (t == 0) ? 0 : ps[t - 1];
  for (int i = 0; i < 40; ++i) {
    int idx = base + i;
    if (idx < N_NODES) {
      int c = counts[idx];
      offs[idx] = run; cur[idx] = run;
      run += c;
      atomicAdd(&dbin[c < 255 ? c : 255], 1);
    }
  }
  __syncthreads();
  int rb = 255 - t;
  int v = dbin[rb];
  __syncthreads();
  ps[t] = v;
  __syncthreads();
  for (int off = 1; off < 256; off <<= 1) {
    int u = (t >= off) ? ps[t - off] : 0;
    __syncthreads();
    ps[t] += u;
    __syncthreads();
  }
  dcur[rb] = ps[t] - v;
}

// Permute kernel: per edge compute sorted position p and SCATTER-WRITE the
// permuted per-edge stream ed2 (stride 20 f): [0..8]=SH, [9]=src,
// [10,11]=pad, [12..19]=ele row. Inputs staged coalesced in LDS. Also the
// node scatter (descending-degree rank -> order/obeg/ocnt).
__global__ __launch_bounds__(256) void k_perm(
    const int* __restrict__ edst, int* __restrict__ cur,
    const int* __restrict__ counts, const int* __restrict__ offs,
    int* __restrict__ dcur, int* __restrict__ order,
    int* __restrict__ obeg, int* __restrict__ ocnt,
    const float* __restrict__ ele, const float* __restrict__ eattr,
    const int* __restrict__ esrc, float* __restrict__ ed2) {
  __shared__ __align__(16) float sh_ea[256 * 9];
  __shared__ __align__(16) float sh_el[256 * 8];
  int t = threadIdx.x;
  int eb = blockIdx.x * 256;
  int e = eb + t;
  for (int i = t; i < 2304; i += 256) sh_ea[i] = eattr[(size_t)eb * 9 + i];
  {
    const float4* src = (const float4*)(ele + (size_t)eb * 8);
    float4* dst = (float4*)sh_el;
    dst[t] = src[t]; dst[t + 256] = src[t + 256];
  }
  __syncthreads();
  int d = edst[e];
  int p = atomicAdd(&cur[d], 1);
  const float* ea = sh_ea + t * 9;
  const float* el = sh_el + t * 8;
  float4 r0 = {ea[0], ea[1], ea[2], ea[3]};
  float4 r1 = {ea[4], ea[5], ea[6], ea[7]};
  float4 r2 = {ea[8], __int_as_float(esrc[e]), 0.f, 0.f};
  float4 r3 = {el[0], el[1], el[2], el[3]};
  float4 r4 = {el[4], el[5], el[6], el[7]};
  float4* dst = (float4*)(ed2 + (size_t)p * 20);
  dst[0] = r0; dst[1] = r1; dst[2] = r2; dst[3] = r3; dst[4] = r4;
  if (e < N_NODES) {
    int c = counts[e];
    int b = c < 255 ? c : 255;
    int q = atomicAdd(&dcur[b], 1);
    order[q] = e; obeg[q] = offs[e]; ocnt[q] = c;
  }
}

__device__ inline f32x4 wtile(const unsigned short* __restrict__ fc1p,
                              bf16x8 a0, bf16x8 a1, int mrow, int quad, int t) {
  f32x4 acc = {0.f, 0.f, 0.f, 0.f};
  bf16x8 b0 = *(const bf16x8*)(fc1p + ((size_t)((t * 2 + 0) * 16 + mrow) * 4 + quad) * 8);
  bf16x8 b1 = *(const bf16x8*)(fc1p + ((size_t)((t * 2 + 1) * 16 + mrow) * 4 + quad) * 8);
  acc = __builtin_amdgcn_mfma_f32_16x16x32_bf16(b0, a0, acc, 0, 0, 0);
  acc = __builtin_amdgcn_mfma_f32_16x16x32_bf16(b1, a1, acc, 0, 0, 0);
  return acc;
}

struct WgemmShared {
  __align__(16) float ele[64][8];
  __align__(16) unsigned short h[64 * 72];   // 72-stride pad
};

// STREAMING MFMA radial GEMM: 64 edges/block, reads ele slices from the
// already-permuted ed2 (sequential), writes packed wbuf (640 B/edge):
// [0,256) AB interleaved; [256,384) C; [384,640) DEFG interleaved.
__device__ void w_gemm_body(WgemmShared& sh, int blk,
    const float* __restrict__ ed2, const float* __restrict__ fc0,
    const unsigned short* __restrict__ fc1p, unsigned short* __restrict__ wout) {
  int t = threadIdx.x;
  int eb = blk * 64;
  if (t < 128) {
    int e = t >> 1, hh = t & 1;
    ((float4*)&sh.ele[e][0])[hh] =
        *(const float4*)(ed2 + (size_t)(eb + e) * 20 + 12 + hh * 4);
  }
  __syncthreads();
  #pragma unroll
  for (int ii = 0; ii < 16; ++ii) {
    int idx = t + ii * 256;
    int e = idx >> 6, k = idx & 63;
    float acc = 0.f;
    #pragma unroll
    for (int m = 0; m < 8; ++m) acc += sh.ele[e][m] * fc0[m * 64 + k];
    acc *= RS8;
    float hv = SILU_C_ * acc / (1.f + __expf(-acc));
    sh.h[e * 72 + k] = f2bf(hv);
  }
  __syncthreads();

  int wv = t >> 6, lane = t & 63;
  int m0 = wv * 16;
  int mrow = lane & 15, quad = lane >> 4;
  bf16x8 a0 = *(const bf16x8*)(sh.h + (m0 + mrow) * 72 + quad * 8);
  bf16x8 a1 = *(const bf16x8*)(sh.h + (m0 + mrow) * 72 + 32 + quad * 8);
  char* wbase = (char*)wout + (size_t)(eb + m0 + mrow) * 640;
  const float K = 0.125f;
  #pragma unroll
  for (int tt = 0; tt < 4; ++tt) {
    f32x4 Av = wtile(fc1p, a0, a1, mrow, quad, tt);
    f32x4 Bv = wtile(fc1p, a0, a1, mrow, quad, tt + 4);
    uint4 st;
    st.x = pack2bf(Av[0] * K, Bv[0] * K);
    st.y = pack2bf(Av[1] * K, Bv[1] * K);
    st.z = pack2bf(Av[2] * K, Bv[2] * K);
    st.w = pack2bf(Av[3] * K, Bv[3] * K);
    *(uint4*)(wbase + 64 * tt + 16 * quad) = st;
  }
  #pragma unroll
  for (int tt = 8; tt < 12; ++tt) {
    f32x4 Cv = wtile(fc1p, a0, a1, mrow, quad, tt);
    uint2 st;
    st.x = pack2bf(Cv[0] * K, Cv[1] * K);
    st.y = pack2bf(Cv[2] * K, Cv[3] * K);
    *(uint2*)(wbase + 256 + 32 * (tt - 8) + 8 * quad) = st;
  }
  #pragma unroll
  for (int tt = 12; tt < 14; ++tt) {
    f32x4 Dv = wtile(fc1p, a0, a1, mrow, quad, tt);
    f32x4 Ev = wtile(fc1p, a0, a1, mrow, quad, tt + 2);
    f32x4 Fv = wtile(fc1p, a0, a1, mrow, quad, tt + 4);
    f32x4 Gv = wtile(fc1p, a0, a1, mrow, quad, tt + 6);
    char* db = wbase + 384 + 128 * (tt - 12) + 32 * quad;
    uint4 s0, s1;
    s0.x = pack2bf(Dv[0] * K, Ev[0] * K); s0.y = pack2bf(Fv[0] * K, Gv[0] * K);
    s0.z = pack2bf(Dv[1] * K, Ev[1] * K); s0.w = pack2bf(Fv[1] * K, Gv[1] * K);
    s1.x = pack2bf(Dv[2] * K, Ev[2] * K); s1.y = pack2bf(Fv[2] * K, Gv[2] * K);
    s1.z = pack2bf(Dv[3] * K, Ev[3] * K); s1.w = pack2bf(Fv[3] * K, Gv[3] * K);
    *(uint4*)(db) = s0;
    *(uint4*)(db + 16) = s1;
  }
}

// y PADDED (stride 192 f): [0,64) scalar, vector channel u' as float4
// {x0,x1,x2,0} at 64+4u'. (s is computed in k_out now.)
__device__ void node_pre_body(int blk,
    const float* __restrict__ xin, const float* __restrict__ attr,
    const float* __restrict__ l1_w0, const float* __restrict__ l1_w1,
    float* __restrict__ y) {
  int idx = blk * 256 + threadIdx.x;
  int n = idx / 160, c = idx - n * 160;
  const float* xr = xin + (size_t)n * 160;
  float a = attr[n];
  if (c < 64) {
    float y_ = 0.f;
    #pragma unroll 8
    for (int u = 0; u < 64; ++u) y_ += xr[u] * l1_w0[u * 64 + c];
    y[(size_t)n * 192 + c] = y_ * a * 0.125f;
  } else {
    int t = c - 64; int v = t / 3, i = t - v * 3;
    float y_ = 0.f;
    #pragma unroll 8
    for (int u = 0; u < 32; ++u) y_ += xr[64 + u * 3 + i] * l1_w1[u * 32 + v];
    y[(size_t)n * 192 + 64 + v * 4 + i] = y_ * a * RS32;
    if (i == 2) y[(size_t)n * 192 + 64 + v * 4 + 3] = 0.f;
  }
}

// fused mid-stage: blocks [0,2500) = w_gemm, [2500,8750) = node_pre
__global__ __launch_bounds__(256) void k_mid(
    const float* __restrict__ ed2, const float* __restrict__ fc0,
    const unsigned short* __restrict__ fc1p, unsigned short* __restrict__ wout,
    const float* __restrict__ xin, const float* __restrict__ attr,
    const float* __restrict__ l1_w0, const float* __restrict__ l1_w1,
    float* __restrict__ y) {
  __shared__ WgemmShared sh;
  if (blockIdx.x < 2500) {
    w_gemm_body(sh, blockIdx.x, ed2, fc0, fc1p, wout);
  } else {
    node_pre_body(blockIdx.x - 2500, xin, attr, l1_w0, l1_w1, y);
  }
}

// node_agg: EXACT round-0 proven loop (2-slot pipeline, 64 VGPR). The
// epilogue (lin2 + sc GEMMs, which re-read ~200 KB of weights per wave =
// ~2 GB of L2 traffic kernel-wide) is REMOVED: accumulators are stored
// directly to the per-node agg buffer (bf16, QDEG-scaled). No LDS at all.
__global__ __launch_bounds__(256) void node_agg(
    const float* __restrict__ y, const float* __restrict__ ed2,
    const unsigned short* __restrict__ wbuf,
    const int* __restrict__ order, const int* __restrict__ obeg,
    const int* __restrict__ ocnt, unsigned short* __restrict__ aggb) {
  int tid = threadIdx.x, wid = tid >> 6, lane = tid & 63, l31 = lane & 31;
  int gw = blockIdx.x * 4 + wid;
  // fixed per-lane byte offsets (loop-invariant)
  int voY  = 4 * lane;           // y scalar block
  int voX  = 256 + 16 * l31;     // y vector float4 {x0,x1,x2,0}
  int voAB = 4 * lane;           // wbuf AB
  int voC  = 256 + 2 * lane;     // wbuf C
  int voDG = 384 + 8 * l31;      // wbuf DEFG

#define E_LOAD(S, idx)                                                         \
  if ((idx) < cnt) {                                                           \
    const float4* ep = (const float4*)(ed2 + (size_t)(beg + (idx)) * 20);      \
    PE0##S = ep[0]; PE1##S = ep[1]; PE2##S = ep[2];                            \
  }
#define V_LOAD(S, idx)                                                         \
  if ((idx) < cnt) {                                                           \
    int srcn = __float_as_int(PE2##S.y);                                       \
    const char* yb = (const char*)y + (size_t)srcn * 768;                      \
    Y##S = *(const float*)(yb + voY);                                          \
    X##S = *(const f32x4*)(yb + voX);                                          \
    const char* wb = (const char*)wbuf + (size_t)(beg + (idx)) * 640;          \
    AB##S = *(const unsigned*)(wb + voAB);                                     \
    Cw##S = *(const unsigned short*)(wb + voC);                                \
    DG##S = *(const uint2*)(wb + voDG);                                        \
  }
#define COMPUTE(S)                                                             \
  {                                                                            \
    float e0 = PE0##S.x, ey = PE0##S.y, ez = PE0##S.z, ex = PE0##S.w;          \
    float q0 = PE1##S.x, q1 = PE1##S.y, q2 = PE1##S.z, q3 = PE1##S.w;          \
    float q4 = PE2##S.x;                                                       \
    float Yv = Y##S, x0 = X##S.x, x1 = X##S.y, x2 = X##S.z;                    \
    float vA = bf2f(AB##S), vB = bfhi(AB##S), vC = bf2f(Cw##S);                \
    float vD = bf2f(DG##S.x), vE = bfhi(DG##S.x);                              \
    float vF = bf2f(DG##S.y), vG = bfhi(DG##S.y);                              \
    aK0 += Yv * e0 * vA;                                                       \
    float tB = Yv * vB; aK2x += tB * ey; aK2y += tB * ez; aK2z += tB * ex;     \
    float tC = Yv * vC;                                                        \
    aK5a += tC * q0; aK5b += tC * q1; aK5c += tC * q2;                         \
    aK5d += tC * q3; aK5e += tC * q4;                                          \
    float t1 = x0 * ey + x1 * ez + x2 * ex; aK1 += (RS3 * vE) * t1;            \
    float s3 = e0 * vD; aK3x += x0 * s3; aK3y += x1 * s3; aK3z += x2 * s3;     \
    float s4 = SQ3_ * vG;                                                      \
    aK4x += s4 * (B_ * (x2 * q0 + x1 * q1 - x0 * q4) - A_ * x0 * q2);          \
    aK4y += s4 * (B_ * (x0 * q1 + x2 * q3) + 2.f * A_ * x1 * q2);              \
    aK4z += s4 * (B_ * (x0 * q0 + x1 * q3 + x2 * q4) - A_ * x2 * q2);          \
    float s6 = SQ5_ * vF;                                                      \
    aK6a += s6 * (-B_ * (x0 * ex + x2 * ey));                                  \
    aK6b += s6 * (-B_ * (x0 * ez + x1 * ey));                                  \
    aK6c += s6 * ( A_ * (x0 * ey + x2 * ex - 2.f * x1 * ez));                  \
    aK6d += s6 * (-B_ * (x1 * ex + x2 * ez));                                  \
    aK6e += s6 * ( B_ * (x0 * ey - x2 * ex));                                  \
  }

  int n = order[gw], beg = obeg[gw], cnt = ocnt[gw];

  float aK0 = 0.f, aK2x = 0.f, aK2y = 0.f, aK2z = 0.f;
  float aK5a = 0.f, aK5b = 0.f, aK5c = 0.f, aK5d = 0.f, aK5e = 0.f;
  float aK1 = 0.f, aK3x = 0.f, aK3y = 0.f, aK3z = 0.f;
  float aK4x = 0.f, aK4y = 0.f, aK4z = 0.f;
  float aK6a = 0.f, aK6b = 0.f, aK6c = 0.f, aK6d = 0.f, aK6e = 0.f;

  float4 PE0a, PE1a, PE2a, PE0b, PE1b, PE2b;
  float Ya, Yb; f32x4 Xa, Xb;
  unsigned ABa, ABb; unsigned short Cwa, Cwb;
  uint2 DGa, DGb;

  E_LOAD(a, 0)
  E_LOAD(b, 1)
  V_LOAD(a, 0)

  int i = 0;
  while (i < cnt) {
    V_LOAD(b, i + 1)
    COMPUTE(a)
    E_LOAD(a, i + 2)
    ++i; if (i >= cnt) break;
    V_LOAD(a, i + 1)
    COMPUTE(b)
    E_LOAD(b, i + 2)
    ++i;
  }

  // store accumulators (QDEG-scaled, bf16) to the node's agg row [960]
  unsigned short* ag = aggb + (size_t)n * 960;
  ag[lane]           = f2bf(aK0  * QDEG);
  ag[96 + 3 * lane]  = f2bf(aK2x * QDEG);
  ag[97 + 3 * lane]  = f2bf(aK2y * QDEG);
  ag[98 + 3 * lane]  = f2bf(aK2z * QDEG);
  ag[480 + 5 * lane] = f2bf(aK5a * QDEG);
  ag[481 + 5 * lane] = f2bf(aK5b * QDEG);
  ag[482 + 5 * lane] = f2bf(aK5c * QDEG);
  ag[483 + 5 * lane] = f2bf(aK5d * QDEG);
  ag[484 + 5 * lane] = f2bf(aK5e * QDEG);
  if (lane < 32) {
    ag[64 + lane]      = f2bf(aK1  * QDEG);
    ag[288 + 3 * lane] = f2bf(aK3x * QDEG);
    ag[289 + 3 * lane] = f2bf(aK3y * QDEG);
    ag[290 + 3 * lane] = f2bf(aK3z * QDEG);
    ag[384 + 3 * lane] = f2bf(aK4x * QDEG);
    ag[385 + 3 * lane] = f2bf(aK4y * QDEG);
    ag[386 + 3 * lane] = f2bf(aK4z * QDEG);
    ag[800 + 5 * lane] = f2bf(aK6a * QDEG);
    ag[801 + 5 * lane] = f2bf(aK6b * QDEG);
    ag[802 + 5 * lane] = f2bf(aK6c * QDEG);
    ag[803 + 5 * lane] = f2bf(aK6d * QDEG);
    ag[804 + 5 * lane] = f2bf(aK6e * QDEG);
  }
#undef E_LOAD
#undef V_LOAD
#undef COMPUTE
}

// k_out: lin2 + fused lin1-s + combine, 16 nodes per block, weights staged
// ONCE PER BLOCK in LDS as bf16 (w0/sc_w0/w1/w2; sc_w1 is tiny -> global).
// Weight L2 traffic drops from ~2 GB (per-wave re-reads) to ~43 MB.
#define SW_W0  0
#define SW_SC0 6144
#define SW_W1  10240
#define SW_W2  14336
__global__ __launch_bounds__(256) void k_out(
    const unsigned short* __restrict__ aggb, const float* __restrict__ xin,
    const float* __restrict__ attr, const float* __restrict__ sc_w1,
    const float* __restrict__ sc_w0, const float* __restrict__ w0,
    const float* __restrict__ w1, const float* __restrict__ w2,
    float* __restrict__ out) {
  __shared__ unsigned short SW[17408];         // 34816 B
  __shared__ __align__(16) float Rf[4][960];   // 15360 B
  int t = threadIdx.x, wid = t >> 6, lane = t & 63;
  for (int i = t; i < 6144; i += 256) SW[SW_W0 + i]  = f2bf(w0[i]);
  for (int i = t; i < 4096; i += 256) SW[SW_SC0 + i] = f2bf(sc_w0[i]);
  for (int i = t; i < 4096; i += 256) SW[SW_W1 + i]  = f2bf(w1[i]);
  for (int i = t; i < 3072; i += 256) SW[SW_W2 + i]  = f2bf(w2[i]);
  __syncthreads();
  float* R = Rf[wid];
  for (int j = 0; j < 4; ++j) {
    int n = blockIdx.x * 16 + wid * 4 + j;
    const unsigned* arow = (const unsigned*)(aggb + (size_t)n * 960);
    for (int k = lane; k < 480; k += 64) {
      unsigned v = arow[k];
      R[2 * k]     = bf2f(v);
      R[2 * k + 1] = bfhi(v);
    }
    __asm__ volatile("s_waitcnt lgkmcnt(0)" ::: "memory");
    float a = attr[n];
    const float* xr = xin + (size_t)n * 160;
    float* orow = out + (size_t)n * 320;
    #pragma unroll
    for (int jo = 0; jo < 5; ++jo) {
      int oc = lane + 64 * jo;
      float res;
      if (oc < 64) {
        float o = 0.f, sv = 0.f;
        #pragma unroll 8
        for (int u = 0; u < 96; ++u) o += R[u] * bf2f(SW[SW_W0 + u * 64 + oc]);
        #pragma unroll 8
        for (int u = 0; u < 64; ++u) sv += xr[u] * bf2f(SW[SW_SC0 + u * 64 + oc]);
        res = CS_ * (sv * a * 0.125f) + CX_ * (o * a * RS96);
      } else if (oc < 160) {
        int t2 = oc - 64, v = t2 / 3, ii = t2 - v * 3;
        float o = 0.f, sv = 0.f;
        #pragma unroll 8
        for (int u = 0; u < 128; ++u) o += R[96 + u * 3 + ii] * bf2f(SW[SW_W1 + u * 32 + v]);
        #pragma unroll 8
        for (int u = 0; u < 32; ++u) sv += xr[64 + u * 3 + ii] * sc_w1[u * 32 + v];
        res = CS_ * (sv * a * RS32) + CX_ * (o * a * RS128);
      } else {
        int t2 = oc - 160, v = t2 / 5, kk = t2 - v * 5;
        float o = 0.f;
        #pragma unroll 8
        for (int u = 0; u < 96; ++u) o += R[480 + u * 5 + kk] * bf2f(SW[SW_W2 + u * 32 + v]);
        res = o * a * RS96;
      }
      orow[oc] = res;
    }
    __asm__ volatile("s_waitcnt lgkmcnt(0)" ::: "memory");
  }
}

extern "C" void kernel_launch(void* const* d_in, const int* in_sizes, int n_in,
                              void* d_out, int out_size, void* d_ws, size_t ws_size,
                              hipStream_t stream) {
  const float* node_input = (const float*)d_in[0];
  const float* node_attr  = (const float*)d_in[1];
  const int*   edge_src   = (const int*)d_in[2];
  const int*   edge_dst   = (const int*)d_in[3];
  const float* edge_attr  = (const float*)d_in[4];
  const float* ele        = (const float*)d_in[5];
  const float* sc_w0      = (const float*)d_in[6];
  const float* sc_w1      = (const float*)d_in[7];
  const float* l1_w0      = (const float*)d_in[8];
  const float* l1_w1      = (const float*)d_in[9];
  const float* fc_w0      = (const float*)d_in[10];
  const float* fc_w1      = (const float*)d_in[11];
  const float* l2_w0      = (const float*)d_in[12];
  const float* l2_w1      = (const float*)d_in[13];
  const float* l2_w2      = (const float*)d_in[14];
  float* out = (float*)d_out;

  char* base = (char*)d_ws;
  float* y              = (float*)(base);                       // 7.68 MB (stride 192)
  unsigned short* wbuf  = (unsigned short*)(base + 7680000);    // 102.4 MB packed
  float* ed2            = (float*)(base + 110080000);           // 12.8 MB (stride 20)
  int* counts           = (int*)(base + 122880000);
  int* offs             = (int*)(base + 122920000);
  int* cur              = (int*)(base + 122960000);
  int* order            = (int*)(base + 123000000);
  int* obeg             = (int*)(base + 123040000);
  int* ocnt             = (int*)(base + 123080000);
  int* dcur             = (int*)(base + 123120000);             // 1 KB
  unsigned short* fc1p  = (unsigned short*)(base + 123121024);  // 40 KB
  unsigned short* aggb  = (unsigned short*)(base + 123162624);  // 19.2 MB

  hipLaunchKernelGGL(k_init, dim3(80), dim3(256), 0, stream, counts, fc_w1, fc1p);
  hipLaunchKernelGGL(k_hist, dim3((N_EDGES + 255) / 256), dim3(256), 0, stream,
                     edge_dst, counts);
  hipLaunchKernelGGL(k_scan, dim3(1), dim3(256), 0, stream, counts, offs, cur, dcur);
  hipLaunchKernelGGL(k_perm, dim3(N_EDGES / 256), dim3(256), 0, stream,
                     edge_dst, cur, counts, offs, dcur, order, obeg, ocnt,
                     ele, edge_attr, edge_src, ed2);
  hipLaunchKernelGGL(k_mid, dim3(2500 + 6250), dim3(256), 0, stream,
                     ed2, fc_w0, fc1p, wbuf,
                     node_input, node_attr, l1_w0, l1_w1, y);
  hipLaunchKernelGGL(node_agg, dim3(2500), dim3(256), 0, stream,
                     y, ed2, wbuf, order, obeg, ocnt, aggb);
  hipLaunchKernelGGL(k_out, dim3(625), dim3(256), 0, stream,
                     aggb, node_input, node_attr, sc_w1,
                     sc_w0, l2_w0, l2_w1, l2_w2, out);
}

// Round 5
// 222.369 us; speedup vs baseline: 3.3565x; 1.2417x over previous
//
#include <hip/hip_runtime.h>
#include <cstddef>
#include <cstdint>

#define N_NODES 10000
#define N_EDGES 160000

// ---- constants ----
#define RS8    0.35355339059327373f   // 1/sqrt(8)
#define RS32   0.17677669529663687f   // 1/sqrt(32)
#define RS96   0.10206207261596575f   // 1/sqrt(96)
#define RS128  0.08838834764831845f   // 1/sqrt(128)
#define RS3    0.5773502691896258f    // 1/sqrt(3)
#define SQ3_   1.7320508075688772f
#define SQ5_   2.23606797749979f
#define A_     0.18257418583505536f   // 1/sqrt(30)
#define B_     0.31622776601683794f   // 1/sqrt(10)
#define SILU_C_ 1.6765208f
#define CS_    0.3826834323650898f    // sin(pi/8)
#define CX_    0.9238795325112867f    // cos(pi/8)
#define QDEG   0.25f                  // 1/sqrt(16)

typedef __attribute__((ext_vector_type(8))) short bf16x8;
typedef __attribute__((ext_vector_type(4))) float f32x4;

__device__ inline float bf2f(unsigned v) {
  union { unsigned u; float f; } c; c.u = v << 16; return c.f;
}
__device__ inline float bfhi(unsigned v) {   // float from HIGH 16 bits
  union { unsigned u; float f; } c; c.u = v & 0xffff0000u; return c.f;
}
__device__ inline unsigned short f2bf(float f) {
  union { float f; unsigned u; } c; c.f = f;
  unsigned r = c.u + 0x7fff + ((c.u >> 16) & 1);
  return (unsigned short)(r >> 16);
}
__device__ inline unsigned pack2bf(float a, float b) {
  return (unsigned)f2bf(a) | ((unsigned)f2bf(b) << 16);
}

// zero counts + build fc1p (fc1 64x320 f32 -> bf16 MFMA B-fragment order)
__global__ void k_init(int* __restrict__ counts, const float* __restrict__ fc1,
                       unsigned short* __restrict__ fc1p) {
  int i = blockIdx.x * blockDim.x + threadIdx.x;
  if (i < N_NODES) counts[i] = 0;
  if (i < 20480) {
    int j = i & 7, q = (i >> 3) & 3, n = (i >> 5) & 15, kq = (i >> 9) & 1, t = i >> 10;
    int k = kq * 32 + q * 8 + j;
    fc1p[i] = f2bf(fc1[k * 320 + t * 16 + n]);
  }
}

__global__ void k_hist(const int* __restrict__ edst, int* __restrict__ counts) {
  int e = blockIdx.x * blockDim.x + threadIdx.x;
  if (e < N_EDGES) atomicAdd(&counts[edst[e]], 1);
}

// k_wprep: build dense-packed bf16 epilogue weight Wp[1120][320] in MFMA
// first-operand fragment order (mirrors fc1p): linear index
// i = j + 8*(lane) + 512*(ks + 35*nt), lane=(ch + 16*quad);
// value = W[k = ks*32 + quad*8 + j][oc = nt*16 + ch], with the block-sparse
// epilogue structure and CS/CX/RS scale factors folded in.
__global__ __launch_bounds__(256) void k_wprep(
    const float* __restrict__ sc_w0, const float* __restrict__ sc_w1,
    const float* __restrict__ w0, const float* __restrict__ w1,
    const float* __restrict__ w2, unsigned short* __restrict__ Wp) {
  int i = blockIdx.x * 256 + threadIdx.x;
  if (i >= 358400) return;
  int j = i & 7;
  int lane = (i >> 3) & 63;
  int ch = lane & 15, quad = lane >> 4;
  int r = i >> 9;                    // [0,700)
  int nt = r / 35, ks = r - nt * 35;
  int k = ks * 32 + quad * 8 + j;
  int oc = nt * 16 + ch;
  float v = 0.f;
  if (k < 96) {                                   // m0 -> oc [0,64)
    if (oc < 64) v = (CX_ * RS96) * w0[k * 64 + oc];
  } else if (k < 480) {                           // m1 -> oc [64,160)
    int tt = k - 96, u = tt / 3, ii = tt - u * 3;
    if (oc >= 64 && oc < 160) {
      int d = oc - 64, vv = d / 3, jj = d - vv * 3;
      if (jj == ii) v = (CX_ * RS128) * w1[u * 32 + vv];
    }
  } else if (k < 960) {                           // m2 -> oc [160,320)
    int tt = k - 480, u = tt / 5, kk = tt - u * 5;
    if (oc >= 160) {
      int d = oc - 160, vv = d / 5, jj = d - vv * 5;
      if (jj == kk) v = RS96 * w2[u * 32 + vv];
    }
  } else if (k < 1024) {                          // x0 sc -> oc [0,64)
    int u = k - 960;
    if (oc < 64) v = (CS_ * 0.125f) * sc_w0[u * 64 + oc];
  } else {                                        // x1 sc -> oc [64,160)
    int tt = k - 1024, u = tt / 3, ii = tt - u * 3;
    if (oc >= 64 && oc < 160) {
      int d = oc - 64, vv = d / 3, jj = d - vv * 3;
      if (jj == ii) v = (CS_ * RS32) * sc_w1[u * 32 + vv];
    }
  }
  Wp[i] = f2bf(v);
}

// exclusive scan of counts -> offs/cur; degree histogram + descending-degree
// exclusive scan -> dcur (single block).
__global__ __launch_bounds__(256) void k_scan(const int* __restrict__ counts,
                                              int* __restrict__ offs,
                                              int* __restrict__ cur,
                                              int* __restrict__ dcur) {
  __shared__ int ps[256];
  __shared__ int dbin[256];
  int t = threadIdx.x;
  dbin[t] = 0;
  int base = t * 40;
  int sum = 0;
  for (int i = 0; i < 40; ++i) {
    int idx = base + i;
    if (idx < N_NODES) sum += counts[idx];
  }
  ps[t] = sum;
  __syncthreads();
  for (int off = 1; off < 256; off <<= 1) {
    int v = (t >= off) ? ps[t - off] : 0;
    __syncthreads();
    ps[t] += v;
    __syncthreads();
  }
  int run = (t == 0) ? 0 : ps[t - 1];
  for (int i = 0; i < 40; ++i) {
    int idx = base + i;
    if (idx < N_NODES) {
      int c = counts[idx];
      offs[idx] = run; cur[idx] = run;
      run += c;
      atomicAdd(&dbin[c < 255 ? c : 255], 1);
    }
  }
  __syncthreads();
  int rb = 255 - t;
  int v = dbin[rb];
  __syncthreads();
  ps[t] = v;
  __syncthreads();
  for (int off = 1; off < 256; off <<= 1) {
    int u = (t >= off) ? ps[t - off] : 0;
    __syncthreads();
    ps[t] += u;
    __syncthreads();
  }
  dcur[rb] = ps[t] - v;
}

// Permute kernel: per edge compute sorted position p and SCATTER-WRITE the
// permuted per-edge stream ed2 (stride 20 f): [0..8]=SH, [9]=src,
// [10,11]=pad, [12..19]=ele row. Inputs staged coalesced in LDS. Also the
// node scatter (descending-degree rank -> order/obeg/ocnt).
__global__ __launch_bounds__(256) void k_perm(
    const int* __restrict__ edst, int* __restrict__ cur,
    const int* __restrict__ counts, const int* __restrict__ offs,
    int* __restrict__ dcur, int* __restrict__ order,
    int* __restrict__ obeg, int* __restrict__ ocnt,
    const float* __restrict__ ele, const float* __restrict__ eattr,
    const int* __restrict__ esrc, float* __restrict__ ed2) {
  __shared__ __align__(16) float sh_ea[256 * 9];
  __shared__ __align__(16) float sh_el[256 * 8];
  int t = threadIdx.x;
  int eb = blockIdx.x * 256;
  int e = eb + t;
  for (int i = t; i < 2304; i += 256) sh_ea[i] = eattr[(size_t)eb * 9 + i];
  {
    const float4* src = (const float4*)(ele + (size_t)eb * 8);
    float4* dst = (float4*)sh_el;
    dst[t] = src[t]; dst[t + 256] = src[t + 256];
  }
  __syncthreads();
  int d = edst[e];
  int p = atomicAdd(&cur[d], 1);
  const float* ea = sh_ea + t * 9;
  const float* el = sh_el + t * 8;
  float4 r0 = {ea[0], ea[1], ea[2], ea[3]};
  float4 r1 = {ea[4], ea[5], ea[6], ea[7]};
  float4 r2 = {ea[8], __int_as_float(esrc[e]), 0.f, 0.f};
  float4 r3 = {el[0], el[1], el[2], el[3]};
  float4 r4 = {el[4], el[5], el[6], el[7]};
  float4* dst = (float4*)(ed2 + (size_t)p * 20);
  dst[0] = r0; dst[1] = r1; dst[2] = r2; dst[3] = r3; dst[4] = r4;
  if (e < N_NODES) {
    int c = counts[e];
    int b = c < 255 ? c : 255;
    int q = atomicAdd(&dcur[b], 1);
    order[q] = e; obeg[q] = offs[e]; ocnt[q] = c;
  }
}

__device__ inline f32x4 wtile(const unsigned short* __restrict__ fc1p,
                              bf16x8 a0, bf16x8 a1, int mrow, int quad, int t) {
  f32x4 acc = {0.f, 0.f, 0.f, 0.f};
  bf16x8 b0 = *(const bf16x8*)(fc1p + ((size_t)((t * 2 + 0) * 16 + mrow) * 4 + quad) * 8);
  bf16x8 b1 = *(const bf16x8*)(fc1p + ((size_t)((t * 2 + 1) * 16 + mrow) * 4 + quad) * 8);
  acc = __builtin_amdgcn_mfma_f32_16x16x32_bf16(b0, a0, acc, 0, 0, 0);
  acc = __builtin_amdgcn_mfma_f32_16x16x32_bf16(b1, a1, acc, 0, 0, 0);
  return acc;
}

struct WgemmShared {
  __align__(16) float ele[64][8];
  __align__(16) unsigned short h[64 * 72];   // 72-stride pad
};

// STREAMING MFMA radial GEMM: 64 edges/block, reads ele slices from the
// already-permuted ed2 (sequential), writes packed wbuf (640 B/edge):
// [0,256) AB interleaved; [256,384) C; [384,640) DEFG interleaved.
__device__ void w_gemm_body(WgemmShared& sh, int blk,
    const float* __restrict__ ed2, const float* __restrict__ fc0,
    const unsigned short* __restrict__ fc1p, unsigned short* __restrict__ wout) {
  int t = threadIdx.x;
  int eb = blk * 64;
  if (t < 128) {
    int e = t >> 1, hh = t & 1;
    ((float4*)&sh.ele[e][0])[hh] =
        *(const float4*)(ed2 + (size_t)(eb + e) * 20 + 12 + hh * 4);
  }
  __syncthreads();
  #pragma unroll
  for (int ii = 0; ii < 16; ++ii) {
    int idx = t + ii * 256;
    int e = idx >> 6, k = idx & 63;
    float acc = 0.f;
    #pragma unroll
    for (int m = 0; m < 8; ++m) acc += sh.ele[e][m] * fc0[m * 64 + k];
    acc *= RS8;
    float hv = SILU_C_ * acc / (1.f + __expf(-acc));
    sh.h[e * 72 + k] = f2bf(hv);
  }
  __syncthreads();

  int wv = t >> 6, lane = t & 63;
  int m0 = wv * 16;
  int mrow = lane & 15, quad = lane >> 4;
  bf16x8 a0 = *(const bf16x8*)(sh.h + (m0 + mrow) * 72 + quad * 8);
  bf16x8 a1 = *(const bf16x8*)(sh.h + (m0 + mrow) * 72 + 32 + quad * 8);
  char* wbase = (char*)wout + (size_t)(eb + m0 + mrow) * 640;
  const float K = 0.125f;
  #pragma unroll
  for (int tt = 0; tt < 4; ++tt) {
    f32x4 Av = wtile(fc1p, a0, a1, mrow, quad, tt);
    f32x4 Bv = wtile(fc1p, a0, a1, mrow, quad, tt + 4);
    uint4 st;
    st.x = pack2bf(Av[0] * K, Bv[0] * K);
    st.y = pack2bf(Av[1] * K, Bv[1] * K);
    st.z = pack2bf(Av[2] * K, Bv[2] * K);
    st.w = pack2bf(Av[3] * K, Bv[3] * K);
    *(uint4*)(wbase + 64 * tt + 16 * quad) = st;
  }
  #pragma unroll
  for (int tt = 8; tt < 12; ++tt) {
    f32x4 Cv = wtile(fc1p, a0, a1, mrow, quad, tt);
    uint2 st;
    st.x = pack2bf(Cv[0] * K, Cv[1] * K);
    st.y = pack2bf(Cv[2] * K, Cv[3] * K);
    *(uint2*)(wbase + 256 + 32 * (tt - 8) + 8 * quad) = st;
  }
  #pragma unroll
  for (int tt = 12; tt < 14; ++tt) {
    f32x4 Dv = wtile(fc1p, a0, a1, mrow, quad, tt);
    f32x4 Ev = wtile(fc1p, a0, a1, mrow, quad, tt + 2);
    f32x4 Fv = wtile(fc1p, a0, a1, mrow, quad, tt + 4);
    f32x4 Gv = wtile(fc1p, a0, a1, mrow, quad, tt + 6);
    char* db = wbase + 384 + 128 * (tt - 12) + 32 * quad;
    uint4 s0, s1;
    s0.x = pack2bf(Dv[0] * K, Ev[0] * K); s0.y = pack2bf(Fv[0] * K, Gv[0] * K);
    s0.z = pack2bf(Dv[1] * K, Ev[1] * K); s0.w = pack2bf(Fv[1] * K, Gv[1] * K);
    s1.x = pack2bf(Dv[2] * K, Ev[2] * K); s1.y = pack2bf(Fv[2] * K, Gv[2] * K);
    s1.z = pack2bf(Dv[3] * K, Ev[3] * K); s1.w = pack2bf(Fv[3] * K, Gv[3] * K);
    *(uint4*)(db) = s0;
    *(uint4*)(db + 16) = s1;
  }
}

// y PADDED (stride 192 f): [0,64) scalar, vector channel u' as float4
// {x0,x1,x2,0} at 64+4u'.
__device__ void node_pre_body(int blk,
    const float* __restrict__ xin, const float* __restrict__ attr,
    const float* __restrict__ l1_w0, const float* __restrict__ l1_w1,
    float* __restrict__ y) {
  int idx = blk * 256 + threadIdx.x;
  int n = idx / 160, c = idx - n * 160;
  const float* xr = xin + (size_t)n * 160;
  float a = attr[n];
  if (c < 64) {
    float y_ = 0.f;
    #pragma unroll 8
    for (int u = 0; u < 64; ++u) y_ += xr[u] * l1_w0[u * 64 + c];
    y[(size_t)n * 192 + c] = y_ * a * 0.125f;
  } else {
    int t = c - 64; int v = t / 3, i = t - v * 3;
    float y_ = 0.f;
    #pragma unroll 8
    for (int u = 0; u < 32; ++u) y_ += xr[64 + u * 3 + i] * l1_w1[u * 32 + v];
    y[(size_t)n * 192 + 64 + v * 4 + i] = y_ * a * RS32;
    if (i == 2) y[(size_t)n * 192 + 64 + v * 4 + 3] = 0.f;
  }
}

// fused mid-stage: blocks [0,2500) = w_gemm, [2500,8750) = node_pre
__global__ __launch_bounds__(256) void k_mid(
    const float* __restrict__ ed2, const float* __restrict__ fc0,
    const unsigned short* __restrict__ fc1p, unsigned short* __restrict__ wout,
    const float* __restrict__ xin, const float* __restrict__ attr,
    const float* __restrict__ l1_w0, const float* __restrict__ l1_w1,
    float* __restrict__ y) {
  __shared__ WgemmShared sh;
  if (blockIdx.x < 2500) {
    w_gemm_body(sh, blockIdx.x, ed2, fc0, fc1p, wout);
  } else {
    node_pre_body(blockIdx.x - 2500, xin, attr, l1_w0, l1_w1, y);
  }
}

// node_agg: round-0 proven loop (2-slot pipeline, 64 VGPR); accumulators
// stored directly to the per-node agg buffer (bf16, QDEG-scaled). No LDS.
__global__ __launch_bounds__(256) void node_agg(
    const float* __restrict__ y, const float* __restrict__ ed2,
    const unsigned short* __restrict__ wbuf,
    const int* __restrict__ order, const int* __restrict__ obeg,
    const int* __restrict__ ocnt, unsigned short* __restrict__ aggb) {
  int tid = threadIdx.x, wid = tid >> 6, lane = tid & 63, l31 = lane & 31;
  int gw = blockIdx.x * 4 + wid;
  // fixed per-lane byte offsets (loop-invariant)
  int voY  = 4 * lane;           // y scalar block
  int voX  = 256 + 16 * l31;     // y vector float4 {x0,x1,x2,0}
  int voAB = 4 * lane;           // wbuf AB
  int voC  = 256 + 2 * lane;     // wbuf C
  int voDG = 384 + 8 * l31;      // wbuf DEFG

#define E_LOAD(S, idx)                                                         \
  if ((idx) < cnt) {                                                           \
    const float4* ep = (const float4*)(ed2 + (size_t)(beg + (idx)) * 20);      \
    PE0##S = ep[0]; PE1##S = ep[1]; PE2##S = ep[2];                            \
  }
#define V_LOAD(S, idx)                                                         \
  if ((idx) < cnt) {                                                           \
    int srcn = __float_as_int(PE2##S.y);                                       \
    const char* yb = (const char*)y + (size_t)srcn * 768;                      \
    Y##S = *(const float*)(yb + voY);                                          \
    X##S = *(const f32x4*)(yb + voX);                                          \
    const char* wb = (const char*)wbuf + (size_t)(beg + (idx)) * 640;          \
    AB##S = *(const unsigned*)(wb + voAB);                                     \
    Cw##S = *(const unsigned short*)(wb + voC);                                \
    DG##S = *(const uint2*)(wb + voDG);                                        \
  }
#define COMPUTE(S)                                                             \
  {                                                                            \
    float e0 = PE0##S.x, ey = PE0##S.y, ez = PE0##S.z, ex = PE0##S.w;          \
    float q0 = PE1##S.x, q1 = PE1##S.y, q2 = PE1##S.z, q3 = PE1##S.w;          \
    float q4 = PE2##S.x;                                                       \
    float Yv = Y##S, x0 = X##S.x, x1 = X##S.y, x2 = X##S.z;                    \
    float vA = bf2f(AB##S), vB = bfhi(AB##S), vC = bf2f(Cw##S);                \
    float vD = bf2f(DG##S.x), vE = bfhi(DG##S.x);                              \
    float vF = bf2f(DG##S.y), vG = bfhi(DG##S.y);                              \
    aK0 += Yv * e0 * vA;                                                       \
    float tB = Yv * vB; aK2x += tB * ey; aK2y += tB * ez; aK2z += tB * ex;     \
    float tC = Yv * vC;                                                        \
    aK5a += tC * q0; aK5b += tC * q1; aK5c += tC * q2;                         \
    aK5d += tC * q3; aK5e += tC * q4;                                          \
    float t1 = x0 * ey + x1 * ez + x2 * ex; aK1 += (RS3 * vE) * t1;            \
    float s3 = e0 * vD; aK3x += x0 * s3; aK3y += x1 * s3; aK3z += x2 * s3;     \
    float s4 = SQ3_ * vG;                                                      \
    aK4x += s4 * (B_ * (x2 * q0 + x1 * q1 - x0 * q4) - A_ * x0 * q2);          \
    aK4y += s4 * (B_ * (x0 * q1 + x2 * q3) + 2.f * A_ * x1 * q2);              \
    aK4z += s4 * (B_ * (x0 * q0 + x1 * q3 + x2 * q4) - A_ * x2 * q2);          \
    float s6 = SQ5_ * vF;                                                      \
    aK6a += s6 * (-B_ * (x0 * ex + x2 * ey));                                  \
    aK6b += s6 * (-B_ * (x0 * ez + x1 * ey));                                  \
    aK6c += s6 * ( A_ * (x0 * ey + x2 * ex - 2.f * x1 * ez));                  \
    aK6d += s6 * (-B_ * (x1 * ex + x2 * ez));                                  \
    aK6e += s6 * ( B_ * (x0 * ey - x2 * ex));                                  \
  }

  int n = order[gw], beg = obeg[gw], cnt = ocnt[gw];

  float aK0 = 0.f, aK2x = 0.f, aK2y = 0.f, aK2z = 0.f;
  float aK5a = 0.f, aK5b = 0.f, aK5c = 0.f, aK5d = 0.f, aK5e = 0.f;
  float aK1 = 0.f, aK3x = 0.f, aK3y = 0.f, aK3z = 0.f;
  float aK4x = 0.f, aK4y = 0.f, aK4z = 0.f;
  float aK6a = 0.f, aK6b = 0.f, aK6c = 0.f, aK6d = 0.f, aK6e = 0.f;

  float4 PE0a, PE1a, PE2a, PE0b, PE1b, PE2b;
  float Ya, Yb; f32x4 Xa, Xb;
  unsigned ABa, ABb; unsigned short Cwa, Cwb;
  uint2 DGa, DGb;

  E_LOAD(a, 0)
  E_LOAD(b, 1)
  V_LOAD(a, 0)

  int i = 0;
  while (i < cnt) {
    V_LOAD(b, i + 1)
    COMPUTE(a)
    E_LOAD(a, i + 2)
    ++i; if (i >= cnt) break;
    V_LOAD(a, i + 1)
    COMPUTE(b)
    E_LOAD(b, i + 2)
    ++i;
  }

  // store accumulators (QDEG-scaled, bf16) to the node's agg row [960]
  unsigned short* ag = aggb + (size_t)n * 960;
  ag[lane]           = f2bf(aK0  * QDEG);
  ag[96 + 3 * lane]  = f2bf(aK2x * QDEG);
  ag[97 + 3 * lane]  = f2bf(aK2y * QDEG);
  ag[98 + 3 * lane]  = f2bf(aK2z * QDEG);
  ag[480 + 5 * lane] = f2bf(aK5a * QDEG);
  ag[481 + 5 * lane] = f2bf(aK5b * QDEG);
  ag[482 + 5 * lane] = f2bf(aK5c * QDEG);
  ag[483 + 5 * lane] = f2bf(aK5d * QDEG);
  ag[484 + 5 * lane] = f2bf(aK5e * QDEG);
  if (lane < 32) {
    ag[64 + lane]      = f2bf(aK1  * QDEG);
    ag[288 + 3 * lane] = f2bf(aK3x * QDEG);
    ag[289 + 3 * lane] = f2bf(aK3y * QDEG);
    ag[290 + 3 * lane] = f2bf(aK3z * QDEG);
    ag[384 + 3 * lane] = f2bf(aK4x * QDEG);
    ag[385 + 3 * lane] = f2bf(aK4y * QDEG);
    ag[386 + 3 * lane] = f2bf(aK4z * QDEG);
    ag[800 + 5 * lane] = f2bf(aK6a * QDEG);
    ag[801 + 5 * lane] = f2bf(aK6b * QDEG);
    ag[802 + 5 * lane] = f2bf(aK6c * QDEG);
    ag[803 + 5 * lane] = f2bf(aK6d * QDEG);
    ag[804 + 5 * lane] = f2bf(aK6e * QDEG);
  }
#undef E_LOAD
#undef V_LOAD
#undef COMPUTE
}

// k_out (MFMA): out[n,0:320] = attr[n] * (A[n,0:1120] @ W) where
// A = [aggb row (bf16) || bf16(xin row)], W = Wp (dense-packed, scales
// folded). 16 nodes/block, A staged in LDS (stride 1128 bf16 -> 2-way-free
// banks), 4 waves x 5 N-tiles, 35 K-steps. Fragment convention mirrors the
// verified w_gemm/fc1p packing: D[channel=(l>>4)*4+reg, node=l&15].
#define ASTR 1128
__global__ __launch_bounds__(256) void k_out(
    const unsigned short* __restrict__ aggb, const float* __restrict__ xin,
    const float* __restrict__ attr, const unsigned short* __restrict__ Wp,
    float* __restrict__ out) {
  __shared__ __align__(16) unsigned short Ash[16 * ASTR];
  int t = threadIdx.x;
  int nbase = blockIdx.x * 16;
  // stage aggb rows (960 bf16 = 480 u32 each)
  for (int idx = t; idx < 16 * 480; idx += 256) {
    int row = idx / 480, c = idx - row * 480;
    *(unsigned*)(Ash + row * ASTR + 2 * c) =
        *(const unsigned*)(aggb + (size_t)(nbase + row) * 960 + 2 * c);
  }
  // stage xin rows (160 f32 each) -> bf16 at A[960..1120)
  for (int idx = t; idx < 16 * 80; idx += 256) {
    int row = idx / 80, c = idx - row * 80;
    const float* xp = xin + (size_t)(nbase + row) * 160 + 2 * c;
    *(unsigned*)(Ash + row * ASTR + 960 + 2 * c) = pack2bf(xp[0], xp[1]);
  }
  __syncthreads();

  int wid = t >> 6, lane = t & 63;
  int ch = lane & 15, quad = lane >> 4;
  f32x4 acc0 = {0.f,0.f,0.f,0.f}, acc1 = {0.f,0.f,0.f,0.f};
  f32x4 acc2 = {0.f,0.f,0.f,0.f}, acc3 = {0.f,0.f,0.f,0.f};
  f32x4 acc4 = {0.f,0.f,0.f,0.f};
  const unsigned short* arow = Ash + ch * ASTR + quad * 8;
  // per-wave W bases for its 5 N-tiles (nt = wid*5 + q)
  const unsigned short* wq0 = Wp + ((size_t)(wid * 5 + 0) * 35 * 64 + lane) * 8;
  const unsigned short* wq1 = Wp + ((size_t)(wid * 5 + 1) * 35 * 64 + lane) * 8;
  const unsigned short* wq2 = Wp + ((size_t)(wid * 5 + 2) * 35 * 64 + lane) * 8;
  const unsigned short* wq3 = Wp + ((size_t)(wid * 5 + 3) * 35 * 64 + lane) * 8;
  const unsigned short* wq4 = Wp + ((size_t)(wid * 5 + 4) * 35 * 64 + lane) * 8;
  for (int ks = 0; ks < 35; ++ks) {
    bf16x8 af = *(const bf16x8*)(arow + ks * 32);
    bf16x8 w0f = *(const bf16x8*)(wq0 + ks * 512);
    bf16x8 w1f = *(const bf16x8*)(wq1 + ks * 512);
    bf16x8 w2f = *(const bf16x8*)(wq2 + ks * 512);
    bf16x8 w3f = *(const bf16x8*)(wq3 + ks * 512);
    bf16x8 w4f = *(const bf16x8*)(wq4 + ks * 512);
    acc0 = __builtin_amdgcn_mfma_f32_16x16x32_bf16(w0f, af, acc0, 0, 0, 0);
    acc1 = __builtin_amdgcn_mfma_f32_16x16x32_bf16(w1f, af, acc1, 0, 0, 0);
    acc2 = __builtin_amdgcn_mfma_f32_16x16x32_bf16(w2f, af, acc2, 0, 0, 0);
    acc3 = __builtin_amdgcn_mfma_f32_16x16x32_bf16(w3f, af, acc3, 0, 0, 0);
    acc4 = __builtin_amdgcn_mfma_f32_16x16x32_bf16(w4f, af, acc4, 0, 0, 0);
  }
  float a = attr[nbase + ch];
  float* orow = out + (size_t)(nbase + ch) * 320 + quad * 4;
  {
    float4 st = {acc0[0]*a, acc0[1]*a, acc0[2]*a, acc0[3]*a};
    *(float4*)(orow + (wid * 5 + 0) * 16) = st;
  }
  {
    float4 st = {acc1[0]*a, acc1[1]*a, acc1[2]*a, acc1[3]*a};
    *(float4*)(orow + (wid * 5 + 1) * 16) = st;
  }
  {
    float4 st = {acc2[0]*a, acc2[1]*a, acc2[2]*a, acc2[3]*a};
    *(float4*)(orow + (wid * 5 + 2) * 16) = st;
  }
  {
    float4 st = {acc3[0]*a, acc3[1]*a, acc3[2]*a, acc3[3]*a};
    *(float4*)(orow + (wid * 5 + 3) * 16) = st;
  }
  {
    float4 st = {acc4[0]*a, acc4[1]*a, acc4[2]*a, acc4[3]*a};
    *(float4*)(orow + (wid * 5 + 4) * 16) = st;
  }
}

extern "C" void kernel_launch(void* const* d_in, const int* in_sizes, int n_in,
                              void* d_out, int out_size, void* d_ws, size_t ws_size,
                              hipStream_t stream) {
  const float* node_input = (const float*)d_in[0];
  const float* node_attr  = (const float*)d_in[1];
  const int*   edge_src   = (const int*)d_in[2];
  const int*   edge_dst   = (const int*)d_in[3];
  const float* edge_attr  = (const float*)d_in[4];
  const float* ele        = (const float*)d_in[5];
  const float* sc_w0      = (const float*)d_in[6];
  const float* sc_w1      = (const float*)d_in[7];
  const float* l1_w0      = (const float*)d_in[8];
  const float* l1_w1      = (const float*)d_in[9];
  const float* fc_w0      = (const float*)d_in[10];
  const float* fc_w1      = (const float*)d_in[11];
  const float* l2_w0      = (const float*)d_in[12];
  const float* l2_w1      = (const float*)d_in[13];
  const float* l2_w2      = (const float*)d_in[14];
  float* out = (float*)d_out;

  char* base = (char*)d_ws;
  float* y              = (float*)(base);                       // 7.68 MB (stride 192)
  unsigned short* wbuf  = (unsigned short*)(base + 7680000);    // 102.4 MB packed
  float* ed2            = (float*)(base + 110080000);           // 12.8 MB (stride 20)
  int* counts           = (int*)(base + 122880000);
  int* offs             = (int*)(base + 122920000);
  int* cur              = (int*)(base + 122960000);
  int* order            = (int*)(base + 123000000);
  int* obeg             = (int*)(base + 123040000);
  int* ocnt             = (int*)(base + 123080000);
  int* dcur             = (int*)(base + 123120000);             // 1 KB
  unsigned short* fc1p  = (unsigned short*)(base + 123121024);  // 40 KB
  unsigned short* aggb  = (unsigned short*)(base + 123162624);  // 19.2 MB
  unsigned short* Wp    = (unsigned short*)(base + 142362624);  // 716.8 KB

  hipLaunchKernelGGL(k_init, dim3(80), dim3(256), 0, stream, counts, fc_w1, fc1p);
  hipLaunchKernelGGL(k_wprep, dim3(1400), dim3(256), 0, stream,
                     sc_w0, sc_w1, l2_w0, l2_w1, l2_w2, Wp);
  hipLaunchKernelGGL(k_hist, dim3((N_EDGES + 255) / 256), dim3(256), 0, stream,
                     edge_dst, counts);
  hipLaunchKernelGGL(k_scan, dim3(1), dim3(256), 0, stream, counts, offs, cur, dcur);
  hipLaunchKernelGGL(k_perm, dim3(N_EDGES / 256), dim3(256), 0, stream,
                     edge_dst, cur, counts, offs, dcur, order, obeg, ocnt,
                     ele, edge_attr, edge_src, ed2);
  hipLaunchKernelGGL(k_mid, dim3(2500 + 6250), dim3(256), 0, stream,
                     ed2, fc_w0, fc1p, wbuf,
                     node_input, node_attr, l1_w0, l1_w1, y);
  hipLaunchKernelGGL(node_agg, dim3(2500), dim3(256), 0, stream,
                     y, ed2, wbuf, order, obeg, ocnt, aggb);
  hipLaunchKernelGGL(k_out, dim3(625), dim3(256), 0, stream,
                     aggb, node_input, node_attr, Wp, out);
}

// Round 6
// 205.063 us; speedup vs baseline: 3.6398x; 1.0844x over previous
//
#include <hip/hip_runtime.h>
#include <cstddef>
#include <cstdint>

#define N_NODES 10000
#define N_EDGES 160000

// ---- constants ----
#define RS8    0.35355339059327373f   // 1/sqrt(8)
#define RS32   0.17677669529663687f   // 1/sqrt(32)
#define RS96   0.10206207261596575f   // 1/sqrt(96)
#define RS128  0.08838834764831845f   // 1/sqrt(128)
#define RS3    0.5773502691896258f    // 1/sqrt(3)
#define SQ3_   1.7320508075688772f
#define SQ5_   2.23606797749979f
#define A_     0.18257418583505536f   // 1/sqrt(30)
#define B_     0.31622776601683794f   // 1/sqrt(10)
#define SILU_C_ 1.6765208f
#define CS_    0.3826834323650898f    // sin(pi/8)
#define CX_    0.9238795325112867f    // cos(pi/8)
#define QDEG   0.25f                  // 1/sqrt(16)

typedef __attribute__((ext_vector_type(8))) short bf16x8;
typedef __attribute__((ext_vector_type(4))) float f32x4;

__device__ inline float bf2f(unsigned v) {
  union { unsigned u; float f; } c; c.u = v << 16; return c.f;
}
__device__ inline float bfhi(unsigned v) {   // float from HIGH 16 bits
  union { unsigned u; float f; } c; c.u = v & 0xffff0000u; return c.f;
}
__device__ inline unsigned short f2bf(float f) {
  union { float f; unsigned u; } c; c.f = f;
  unsigned r = c.u + 0x7fff + ((c.u >> 16) & 1);
  return (unsigned short)(r >> 16);
}
__device__ inline unsigned pack2bf(float a, float b) {
  return (unsigned)f2bf(a) | ((unsigned)f2bf(b) << 16);
}

// zero counts + build fc1p (fc1 64x320 f32 -> bf16 MFMA B-fragment order)
__global__ void k_init(int* __restrict__ counts, const float* __restrict__ fc1,
                       unsigned short* __restrict__ fc1p) {
  int i = blockIdx.x * blockDim.x + threadIdx.x;
  if (i < N_NODES) counts[i] = 0;
  if (i < 20480) {
    int j = i & 7, q = (i >> 3) & 3, n = (i >> 5) & 15, kq = (i >> 9) & 1, t = i >> 10;
    int k = kq * 32 + q * 8 + j;
    fc1p[i] = f2bf(fc1[k * 320 + t * 16 + n]);
  }
}

__global__ void k_hist(const int* __restrict__ edst, int* __restrict__ counts) {
  int e = blockIdx.x * blockDim.x + threadIdx.x;
  if (e < N_EDGES) atomicAdd(&counts[edst[e]], 1);
}

// k_wprep: build (a) dense-packed bf16 epilogue weight Wp[1120][320] and
// (b) node_pre weight Wyp[160][192], both in the VERIFIED MFMA
// first-operand fragment order: linear index i = j + 8*lane + 512*(ks+KS*nt),
// lane = ch + 16*quad; value = W[k = ks*32 + quad*8 + j][oc = nt*16 + ch],
// block-sparse structure + scale factors folded in.
__global__ __launch_bounds__(256) void k_wprep(
    const float* __restrict__ sc_w0, const float* __restrict__ sc_w1,
    const float* __restrict__ w0, const float* __restrict__ w1,
    const float* __restrict__ w2, const float* __restrict__ l1_w0,
    const float* __restrict__ l1_w1, unsigned short* __restrict__ Wp,
    unsigned short* __restrict__ Wyp) {
  int i = blockIdx.x * 256 + threadIdx.x;
  if (i < 358400) {
    int j = i & 7;
    int lane = (i >> 3) & 63;
    int ch = lane & 15, quad = lane >> 4;
    int r = i >> 9;                    // [0,700)
    int nt = r / 35, ks = r - nt * 35;
    int k = ks * 32 + quad * 8 + j;
    int oc = nt * 16 + ch;
    float v = 0.f;
    if (k < 96) {                                   // m0 -> oc [0,64)
      if (oc < 64) v = (CX_ * RS96) * w0[k * 64 + oc];
    } else if (k < 480) {                           // m1 -> oc [64,160)
      int tt = k - 96, u = tt / 3, ii = tt - u * 3;
      if (oc >= 64 && oc < 160) {
        int d = oc - 64, vv = d / 3, jj = d - vv * 3;
        if (jj == ii) v = (CX_ * RS128) * w1[u * 32 + vv];
      }
    } else if (k < 960) {                           // m2 -> oc [160,320)
      int tt = k - 480, u = tt / 5, kk = tt - u * 5;
      if (oc >= 160) {
        int d = oc - 160, vv = d / 5, jj = d - vv * 5;
        if (jj == kk) v = RS96 * w2[u * 32 + vv];
      }
    } else if (k < 1024) {                          // x0 sc -> oc [0,64)
      int u = k - 960;
      if (oc < 64) v = (CS_ * 0.125f) * sc_w0[u * 64 + oc];
    } else {                                        // x1 sc -> oc [64,160)
      int tt = k - 1024, u = tt / 3, ii = tt - u * 3;
      if (oc >= 64 && oc < 160) {
        int d = oc - 64, vv = d / 3, jj = d - vv * 3;
        if (jj == ii) v = (CS_ * RS32) * sc_w1[u * 32 + vv];
      }
    }
    Wp[i] = f2bf(v);
  } else if (i < 358400 + 30720) {
    // Wyp: y[n, 0:192] = attr * (x[n,0:160] @ Wy). KS=5, NT=12.
    // oc layout matches padded y: [0,64) scalar; 64+v*4+comp (comp<3);
    // pad column 64+v*4+3 = 0.
    int ii2 = i - 358400;
    int j = ii2 & 7;
    int lane = (ii2 >> 3) & 63;
    int ch = lane & 15, quad = lane >> 4;
    int r = ii2 >> 9;                  // [0,60)
    int nt = r / 5, ks = r - nt * 5;
    int k = ks * 32 + quad * 8 + j;    // [0,160)
    int oc = nt * 16 + ch;             // [0,192)
    float v = 0.f;
    if (k < 64) {
      if (oc < 64) v = 0.125f * l1_w0[k * 64 + oc];
    } else {
      int tt = k - 64, u = tt / 3, ci = tt - u * 3;   // u<32, ci<3
      if (oc >= 64) {
        int d = oc - 64, vv = d >> 2, jj = d & 3;
        if (jj == ci) v = RS32 * l1_w1[u * 32 + vv];  // jj==3 never matches
      }
    }
    Wyp[ii2] = f2bf(v);
  }
}

// exclusive scan of counts -> offs/cur; degree histogram + descending-degree
// exclusive scan -> dcur (single block).
__global__ __launch_bounds__(256) void k_scan(const int* __restrict__ counts,
                                              int* __restrict__ offs,
                                              int* __restrict__ cur,
                                              int* __restrict__ dcur) {
  __shared__ int ps[256];
  __shared__ int dbin[256];
  int t = threadIdx.x;
  dbin[t] = 0;
  int base = t * 40;
  int sum = 0;
  for (int i = 0; i < 40; ++i) {
    int idx = base + i;
    if (idx < N_NODES) sum += counts[idx];
  }
  ps[t] = sum;
  __syncthreads();
  for (int off = 1; off < 256; off <<= 1) {
    int v = (t >= off) ? ps[t - off] : 0;
    __syncthreads();
    ps[t] += v;
    __syncthreads();
  }
  int run = (t == 0) ? 0 : ps[t - 1];
  for (int i = 0; i < 40; ++i) {
    int idx = base + i;
    if (idx < N_NODES) {
      int c = counts[idx];
      offs[idx] = run; cur[idx] = run;
      run += c;
      atomicAdd(&dbin[c < 255 ? c : 255], 1);
    }
  }
  __syncthreads();
  int rb = 255 - t;
  int v = dbin[rb];
  __syncthreads();
  ps[t] = v;
  __syncthreads();
  for (int off = 1; off < 256; off <<= 1) {
    int u = (t >= off) ? ps[t - off] : 0;
    __syncthreads();
    ps[t] += u;
    __syncthreads();
  }
  dcur[rb] = ps[t] - v;
}

// Permute kernel: per edge compute sorted position p and SCATTER-WRITE the
// permuted per-edge stream ed2 (stride 20 f): [0..8]=SH, [9]=src,
// [10,11]=pad, [12..19]=ele row. Inputs staged coalesced in LDS. Also the
// node scatter (descending-degree rank -> order/obeg/ocnt).
__global__ __launch_bounds__(256) void k_perm(
    const int* __restrict__ edst, int* __restrict__ cur,
    const int* __restrict__ counts, const int* __restrict__ offs,
    int* __restrict__ dcur, int* __restrict__ order,
    int* __restrict__ obeg, int* __restrict__ ocnt,
    const float* __restrict__ ele, const float* __restrict__ eattr,
    const int* __restrict__ esrc, float* __restrict__ ed2) {
  __shared__ __align__(16) float sh_ea[256 * 9];
  __shared__ __align__(16) float sh_el[256 * 8];
  int t = threadIdx.x;
  int eb = blockIdx.x * 256;
  int e = eb + t;
  for (int i = t; i < 2304; i += 256) sh_ea[i] = eattr[(size_t)eb * 9 + i];
  {
    const float4* src = (const float4*)(ele + (size_t)eb * 8);
    float4* dst = (float4*)sh_el;
    dst[t] = src[t]; dst[t + 256] = src[t + 256];
  }
  __syncthreads();
  int d = edst[e];
  int p = atomicAdd(&cur[d], 1);
  const float* ea = sh_ea + t * 9;
  const float* el = sh_el + t * 8;
  float4 r0 = {ea[0], ea[1], ea[2], ea[3]};
  float4 r1 = {ea[4], ea[5], ea[6], ea[7]};
  float4 r2 = {ea[8], __int_as_float(esrc[e]), 0.f, 0.f};
  float4 r3 = {el[0], el[1], el[2], el[3]};
  float4 r4 = {el[4], el[5], el[6], el[7]};
  float4* dst = (float4*)(ed2 + (size_t)p * 20);
  dst[0] = r0; dst[1] = r1; dst[2] = r2; dst[3] = r3; dst[4] = r4;
  if (e < N_NODES) {
    int c = counts[e];
    int b = c < 255 ? c : 255;
    int q = atomicAdd(&dcur[b], 1);
    order[q] = e; obeg[q] = offs[e]; ocnt[q] = c;
  }
}

__device__ inline f32x4 wtile(const unsigned short* __restrict__ fc1p,
                              bf16x8 a0, bf16x8 a1, int mrow, int quad, int t) {
  f32x4 acc = {0.f, 0.f, 0.f, 0.f};
  bf16x8 b0 = *(const bf16x8*)(fc1p + ((size_t)((t * 2 + 0) * 16 + mrow) * 4 + quad) * 8);
  bf16x8 b1 = *(const bf16x8*)(fc1p + ((size_t)((t * 2 + 1) * 16 + mrow) * 4 + quad) * 8);
  acc = __builtin_amdgcn_mfma_f32_16x16x32_bf16(b0, a0, acc, 0, 0, 0);
  acc = __builtin_amdgcn_mfma_f32_16x16x32_bf16(b1, a1, acc, 0, 0, 0);
  return acc;
}

struct WgemmShared {
  __align__(16) float ele[64][8];
  __align__(16) unsigned short h[64 * 72];   // 72-stride pad
};

// STREAMING MFMA radial GEMM: 64 edges/block, reads ele slices from the
// already-permuted ed2 (sequential), writes packed wbuf (640 B/edge):
// [0,256) AB interleaved; [256,384) C; [384,640) DEFG interleaved.
__device__ void w_gemm_body(WgemmShared& sh, int blk,
    const float* __restrict__ ed2, const float* __restrict__ fc0,
    const unsigned short* __restrict__ fc1p, unsigned short* __restrict__ wout) {
  int t = threadIdx.x;
  int eb = blk * 64;
  if (t < 128) {
    int e = t >> 1, hh = t & 1;
    ((float4*)&sh.ele[e][0])[hh] =
        *(const float4*)(ed2 + (size_t)(eb + e) * 20 + 12 + hh * 4);
  }
  __syncthreads();
  #pragma unroll
  for (int ii = 0; ii < 16; ++ii) {
    int idx = t + ii * 256;
    int e = idx >> 6, k = idx & 63;
    float acc = 0.f;
    #pragma unroll
    for (int m = 0; m < 8; ++m) acc += sh.ele[e][m] * fc0[m * 64 + k];
    acc *= RS8;
    float hv = SILU_C_ * acc / (1.f + __expf(-acc));
    sh.h[e * 72 + k] = f2bf(hv);
  }
  __syncthreads();

  int wv = t >> 6, lane = t & 63;
  int m0 = wv * 16;
  int mrow = lane & 15, quad = lane >> 4;
  bf16x8 a0 = *(const bf16x8*)(sh.h + (m0 + mrow) * 72 + quad * 8);
  bf16x8 a1 = *(const bf16x8*)(sh.h + (m0 + mrow) * 72 + 32 + quad * 8);
  char* wbase = (char*)wout + (size_t)(eb + m0 + mrow) * 640;
  const float K = 0.125f;
  #pragma unroll
  for (int tt = 0; tt < 4; ++tt) {
    f32x4 Av = wtile(fc1p, a0, a1, mrow, quad, tt);
    f32x4 Bv = wtile(fc1p, a0, a1, mrow, quad, tt + 4);
    uint4 st;
    st.x = pack2bf(Av[0] * K, Bv[0] * K);
    st.y = pack2bf(Av[1] * K, Bv[1] * K);
    st.z = pack2bf(Av[2] * K, Bv[2] * K);
    st.w = pack2bf(Av[3] * K, Bv[3] * K);
    *(uint4*)(wbase + 64 * tt + 16 * quad) = st;
  }
  #pragma unroll
  for (int tt = 8; tt < 12; ++tt) {
    f32x4 Cv = wtile(fc1p, a0, a1, mrow, quad, tt);
    uint2 st;
    st.x = pack2bf(Cv[0] * K, Cv[1] * K);
    st.y = pack2bf(Cv[2] * K, Cv[3] * K);
    *(uint2*)(wbase + 256 + 32 * (tt - 8) + 8 * quad) = st;
  }
  #pragma unroll
  for (int tt = 12; tt < 14; ++tt) {
    f32x4 Dv = wtile(fc1p, a0, a1, mrow, quad, tt);
    f32x4 Ev = wtile(fc1p, a0, a1, mrow, quad, tt + 2);
    f32x4 Fv = wtile(fc1p, a0, a1, mrow, quad, tt + 4);
    f32x4 Gv = wtile(fc1p, a0, a1, mrow, quad, tt + 6);
    char* db = wbase + 384 + 128 * (tt - 12) + 32 * quad;
    uint4 s0, s1;
    s0.x = pack2bf(Dv[0] * K, Ev[0] * K); s0.y = pack2bf(Fv[0] * K, Gv[0] * K);
    s0.z = pack2bf(Dv[1] * K, Ev[1] * K); s0.w = pack2bf(Fv[1] * K, Gv[1] * K);
    s1.x = pack2bf(Dv[2] * K, Ev[2] * K); s1.y = pack2bf(Fv[2] * K, Gv[2] * K);
    s1.z = pack2bf(Dv[3] * K, Ev[3] * K); s1.w = pack2bf(Fv[3] * K, Gv[3] * K);
    *(uint4*)(db) = s0;
    *(uint4*)(db + 16) = s1;
  }
}

// k_mid: now w_gemm only (node_pre replaced by MFMA k_npre)
__global__ __launch_bounds__(256) void k_mid(
    const float* __restrict__ ed2, const float* __restrict__ fc0,
    const unsigned short* __restrict__ fc1p, unsigned short* __restrict__ wout) {
  __shared__ WgemmShared sh;
  w_gemm_body(sh, blockIdx.x, ed2, fc0, fc1p, wout);
}

// k_npre (MFMA): y[n, 0:192] = attr[n] * (bf16(xin[n,0:160]) @ Wyp).
// 16 nodes/block, 625 blocks, 4 waves x 3 N-tiles, 5 K-steps. Identical
// staging/fragment/store convention to the verified k_out. Zero pad column
// comes out of Wy's zero column automatically.
#define YSTR 168
__global__ __launch_bounds__(256) void k_npre(
    const float* __restrict__ xin, const float* __restrict__ attr,
    const unsigned short* __restrict__ Wyp, float* __restrict__ y) {
  __shared__ __align__(16) unsigned short Ash[16 * YSTR];
  int t = threadIdx.x;
  int nbase = blockIdx.x * 16;
  for (int idx = t; idx < 16 * 80; idx += 256) {
    int row = idx / 80, c = idx - row * 80;
    const float* xp = xin + (size_t)(nbase + row) * 160 + 2 * c;
    *(unsigned*)(Ash + row * YSTR + 2 * c) = pack2bf(xp[0], xp[1]);
  }
  __syncthreads();
  int wid = t >> 6, lane = t & 63;
  int ch = lane & 15, quad = lane >> 4;
  const unsigned short* arow = Ash + ch * YSTR + quad * 8;
  f32x4 acc0 = {0.f,0.f,0.f,0.f}, acc1 = {0.f,0.f,0.f,0.f}, acc2 = {0.f,0.f,0.f,0.f};
  const unsigned short* wq0 = Wyp + ((size_t)(wid * 3 + 0) * 5 * 64 + lane) * 8;
  const unsigned short* wq1 = Wyp + ((size_t)(wid * 3 + 1) * 5 * 64 + lane) * 8;
  const unsigned short* wq2 = Wyp + ((size_t)(wid * 3 + 2) * 5 * 64 + lane) * 8;
  #pragma unroll
  for (int ks = 0; ks < 5; ++ks) {
    bf16x8 af  = *(const bf16x8*)(arow + ks * 32);
    bf16x8 w0f = *(const bf16x8*)(wq0 + ks * 512);
    bf16x8 w1f = *(const bf16x8*)(wq1 + ks * 512);
    bf16x8 w2f = *(const bf16x8*)(wq2 + ks * 512);
    acc0 = __builtin_amdgcn_mfma_f32_16x16x32_bf16(w0f, af, acc0, 0, 0, 0);
    acc1 = __builtin_amdgcn_mfma_f32_16x16x32_bf16(w1f, af, acc1, 0, 0, 0);
    acc2 = __builtin_amdgcn_mfma_f32_16x16x32_bf16(w2f, af, acc2, 0, 0, 0);
  }
  float a = attr[nbase + ch];
  float* yrow = y + (size_t)(nbase + ch) * 192 + quad * 4;
  { float4 st = {acc0[0]*a, acc0[1]*a, acc0[2]*a, acc0[3]*a};
    *(float4*)(yrow + (wid * 3 + 0) * 16) = st; }
  { float4 st = {acc1[0]*a, acc1[1]*a, acc1[2]*a, acc1[3]*a};
    *(float4*)(yrow + (wid * 3 + 1) * 16) = st; }
  { float4 st = {acc2[0]*a, acc2[1]*a, acc2[2]*a, acc2[3]*a};
    *(float4*)(yrow + (wid * 3 + 2) * 16) = st; }
}

// node_agg: round-0 proven loop (2-slot pipeline, 64 VGPR); accumulators
// stored directly to the per-node agg buffer (bf16, QDEG-scaled). No LDS.
__global__ __launch_bounds__(256) void node_agg(
    const float* __restrict__ y, const float* __restrict__ ed2,
    const unsigned short* __restrict__ wbuf,
    const int* __restrict__ order, const int* __restrict__ obeg,
    const int* __restrict__ ocnt, unsigned short* __restrict__ aggb) {
  int tid = threadIdx.x, wid = tid >> 6, lane = tid & 63, l31 = lane & 31;
  int gw = blockIdx.x * 4 + wid;
  // fixed per-lane byte offsets (loop-invariant)
  int voY  = 4 * lane;           // y scalar block
  int voX  = 256 + 16 * l31;     // y vector float4 {x0,x1,x2,0}
  int voAB = 4 * lane;           // wbuf AB
  int voC  = 256 + 2 * lane;     // wbuf C
  int voDG = 384 + 8 * l31;      // wbuf DEFG

#define E_LOAD(S, idx)                                                         \
  if ((idx) < cnt) {                                                           \
    const float4* ep = (const float4*)(ed2 + (size_t)(beg + (idx)) * 20);      \
    PE0##S = ep[0]; PE1##S = ep[1]; PE2##S = ep[2];                            \
  }
#define V_LOAD(S, idx)                                                         \
  if ((idx) < cnt) {                                                           \
    int srcn = __float_as_int(PE2##S.y);                                       \
    const char* yb = (const char*)y + (size_t)srcn * 768;                      \
    Y##S = *(const float*)(yb + voY);                                          \
    X##S = *(const f32x4*)(yb + voX);                                          \
    const char* wb = (const char*)wbuf + (size_t)(beg + (idx)) * 640;          \
    AB##S = *(const unsigned*)(wb + voAB);                                     \
    Cw##S = *(const unsigned short*)(wb + voC);                                \
    DG##S = *(const uint2*)(wb + voDG);                                        \
  }
#define COMPUTE(S)                                                             \
  {                                                                            \
    float e0 = PE0##S.x, ey = PE0##S.y, ez = PE0##S.z, ex = PE0##S.w;          \
    float q0 = PE1##S.x, q1 = PE1##S.y, q2 = PE1##S.z, q3 = PE1##S.w;          \
    float q4 = PE2##S.x;                                                       \
    float Yv = Y##S, x0 = X##S.x, x1 = X##S.y, x2 = X##S.z;                    \
    float vA = bf2f(AB##S), vB = bfhi(AB##S), vC = bf2f(Cw##S);                \
    float vD = bf2f(DG##S.x), vE = bfhi(DG##S.x);                              \
    float vF = bf2f(DG##S.y), vG = bfhi(DG##S.y);                              \
    aK0 += Yv * e0 * vA;                                                       \
    float tB = Yv * vB; aK2x += tB * ey; aK2y += tB * ez; aK2z += tB * ex;     \
    float tC = Yv * vC;                                                        \
    aK5a += tC * q0; aK5b += tC * q1; aK5c += tC * q2;                         \
    aK5d += tC * q3; aK5e += tC * q4;                                          \
    float t1 = x0 * ey + x1 * ez + x2 * ex; aK1 += (RS3 * vE) * t1;            \
    float s3 = e0 * vD; aK3x += x0 * s3; aK3y += x1 * s3; aK3z += x2 * s3;     \
    float s4 = SQ3_ * vG;                                                      \
    aK4x += s4 * (B_ * (x2 * q0 + x1 * q1 - x0 * q4) - A_ * x0 * q2);          \
    aK4y += s4 * (B_ * (x0 * q1 + x2 * q3) + 2.f * A_ * x1 * q2);              \
    aK4z += s4 * (B_ * (x0 * q0 + x1 * q3 + x2 * q4) - A_ * x2 * q2);          \
    float s6 = SQ5_ * vF;                                                      \
    aK6a += s6 * (-B_ * (x0 * ex + x2 * ey));                                  \
    aK6b += s6 * (-B_ * (x0 * ez + x1 * ey));                                  \
    aK6c += s6 * ( A_ * (x0 * ey + x2 * ex - 2.f * x1 * ez));                  \
    aK6d += s6 * (-B_ * (x1 * ex + x2 * ez));                                  \
    aK6e += s6 * ( B_ * (x0 * ey - x2 * ex));                                  \
  }

  int n = order[gw], beg = obeg[gw], cnt = ocnt[gw];

  float aK0 = 0.f, aK2x = 0.f, aK2y = 0.f, aK2z = 0.f;
  float aK5a = 0.f, aK5b = 0.f, aK5c = 0.f, aK5d = 0.f, aK5e = 0.f;
  float aK1 = 0.f, aK3x = 0.f, aK3y = 0.f, aK3z = 0.f;
  float aK4x = 0.f, aK4y = 0.f, aK4z = 0.f;
  float aK6a = 0.f, aK6b = 0.f, aK6c = 0.f, aK6d = 0.f, aK6e = 0.f;

  float4 PE0a, PE1a, PE2a, PE0b, PE1b, PE2b;
  float Ya, Yb; f32x4 Xa, Xb;
  unsigned ABa, ABb; unsigned short Cwa, Cwb;
  uint2 DGa, DGb;

  E_LOAD(a, 0)
  E_LOAD(b, 1)
  V_LOAD(a, 0)

  int i = 0;
  while (i < cnt) {
    V_LOAD(b, i + 1)
    COMPUTE(a)
    E_LOAD(a, i + 2)
    ++i; if (i >= cnt) break;
    V_LOAD(a, i + 1)
    COMPUTE(b)
    E_LOAD(b, i + 2)
    ++i;
  }

  // store accumulators (QDEG-scaled, bf16) to the node's agg row [960]
  unsigned short* ag = aggb + (size_t)n * 960;
  ag[lane]           = f2bf(aK0  * QDEG);
  ag[96 + 3 * lane]  = f2bf(aK2x * QDEG);
  ag[97 + 3 * lane]  = f2bf(aK2y * QDEG);
  ag[98 + 3 * lane]  = f2bf(aK2z * QDEG);
  ag[480 + 5 * lane] = f2bf(aK5a * QDEG);
  ag[481 + 5 * lane] = f2bf(aK5b * QDEG);
  ag[482 + 5 * lane] = f2bf(aK5c * QDEG);
  ag[483 + 5 * lane] = f2bf(aK5d * QDEG);
  ag[484 + 5 * lane] = f2bf(aK5e * QDEG);
  if (lane < 32) {
    ag[64 + lane]      = f2bf(aK1  * QDEG);
    ag[288 + 3 * lane] = f2bf(aK3x * QDEG);
    ag[289 + 3 * lane] = f2bf(aK3y * QDEG);
    ag[290 + 3 * lane] = f2bf(aK3z * QDEG);
    ag[384 + 3 * lane] = f2bf(aK4x * QDEG);
    ag[385 + 3 * lane] = f2bf(aK4y * QDEG);
    ag[386 + 3 * lane] = f2bf(aK4z * QDEG);
    ag[800 + 5 * lane] = f2bf(aK6a * QDEG);
    ag[801 + 5 * lane] = f2bf(aK6b * QDEG);
    ag[802 + 5 * lane] = f2bf(aK6c * QDEG);
    ag[803 + 5 * lane] = f2bf(aK6d * QDEG);
    ag[804 + 5 * lane] = f2bf(aK6e * QDEG);
  }
#undef E_LOAD
#undef V_LOAD
#undef COMPUTE
}

// k_out (MFMA): out[n,0:320] = attr[n] * (A[n,0:1120] @ W) where
// A = [aggb row (bf16) || bf16(xin row)], W = Wp (dense-packed, scales
// folded). 16 nodes/block, A staged in LDS, 4 waves x 5 N-tiles, 35 K-steps.
#define ASTR 1128
__global__ __launch_bounds__(256) void k_out(
    const unsigned short* __restrict__ aggb, const float* __restrict__ xin,
    const float* __restrict__ attr, const unsigned short* __restrict__ Wp,
    float* __restrict__ out) {
  __shared__ __align__(16) unsigned short Ash[16 * ASTR];
  int t = threadIdx.x;
  int nbase = blockIdx.x * 16;
  // stage aggb rows (960 bf16 = 480 u32 each)
  for (int idx = t; idx < 16 * 480; idx += 256) {
    int row = idx / 480, c = idx - row * 480;
    *(unsigned*)(Ash + row * ASTR + 2 * c) =
        *(const unsigned*)(aggb + (size_t)(nbase + row) * 960 + 2 * c);
  }
  // stage xin rows (160 f32 each) -> bf16 at A[960..1120)
  for (int idx = t; idx < 16 * 80; idx += 256) {
    int row = idx / 80, c = idx - row * 80;
    const float* xp = xin + (size_t)(nbase + row) * 160 + 2 * c;
    *(unsigned*)(Ash + row * ASTR + 960 + 2 * c) = pack2bf(xp[0], xp[1]);
  }
  __syncthreads();

  int wid = t >> 6, lane = t & 63;
  int ch = lane & 15, quad = lane >> 4;
  f32x4 acc0 = {0.f,0.f,0.f,0.f}, acc1 = {0.f,0.f,0.f,0.f};
  f32x4 acc2 = {0.f,0.f,0.f,0.f}, acc3 = {0.f,0.f,0.f,0.f};
  f32x4 acc4 = {0.f,0.f,0.f,0.f};
  const unsigned short* arow = Ash + ch * ASTR + quad * 8;
  const unsigned short* wq0 = Wp + ((size_t)(wid * 5 + 0) * 35 * 64 + lane) * 8;
  const unsigned short* wq1 = Wp + ((size_t)(wid * 5 + 1) * 35 * 64 + lane) * 8;
  const unsigned short* wq2 = Wp + ((size_t)(wid * 5 + 2) * 35 * 64 + lane) * 8;
  const unsigned short* wq3 = Wp + ((size_t)(wid * 5 + 3) * 35 * 64 + lane) * 8;
  const unsigned short* wq4 = Wp + ((size_t)(wid * 5 + 4) * 35 * 64 + lane) * 8;
  for (int ks = 0; ks < 35; ++ks) {
    bf16x8 af = *(const bf16x8*)(arow + ks * 32);
    bf16x8 w0f = *(const bf16x8*)(wq0 + ks * 512);
    bf16x8 w1f = *(const bf16x8*)(wq1 + ks * 512);
    bf16x8 w2f = *(const bf16x8*)(wq2 + ks * 512);
    bf16x8 w3f = *(const bf16x8*)(wq3 + ks * 512);
    bf16x8 w4f = *(const bf16x8*)(wq4 + ks * 512);
    acc0 = __builtin_amdgcn_mfma_f32_16x16x32_bf16(w0f, af, acc0, 0, 0, 0);
    acc1 = __builtin_amdgcn_mfma_f32_16x16x32_bf16(w1f, af, acc1, 0, 0, 0);
    acc2 = __builtin_amdgcn_mfma_f32_16x16x32_bf16(w2f, af, acc2, 0, 0, 0);
    acc3 = __builtin_amdgcn_mfma_f32_16x16x32_bf16(w3f, af, acc3, 0, 0, 0);
    acc4 = __builtin_amdgcn_mfma_f32_16x16x32_bf16(w4f, af, acc4, 0, 0, 0);
  }
  float a = attr[nbase + ch];
  float* orow = out + (size_t)(nbase + ch) * 320 + quad * 4;
  {
    float4 st = {acc0[0]*a, acc0[1]*a, acc0[2]*a, acc0[3]*a};
    *(float4*)(orow + (wid * 5 + 0) * 16) = st;
  }
  {
    float4 st = {acc1[0]*a, acc1[1]*a, acc1[2]*a, acc1[3]*a};
    *(float4*)(orow + (wid * 5 + 1) * 16) = st;
  }
  {
    float4 st = {acc2[0]*a, acc2[1]*a, acc2[2]*a, acc2[3]*a};
    *(float4*)(orow + (wid * 5 + 2) * 16) = st;
  }
  {
    float4 st = {acc3[0]*a, acc3[1]*a, acc3[2]*a, acc3[3]*a};
    *(float4*)(orow + (wid * 5 + 3) * 16) = st;
  }
  {
    float4 st = {acc4[0]*a, acc4[1]*a, acc4[2]*a, acc4[3]*a};
    *(float4*)(orow + (wid * 5 + 4) * 16) = st;
  }
}

extern "C" void kernel_launch(void* const* d_in, const int* in_sizes, int n_in,
                              void* d_out, int out_size, void* d_ws, size_t ws_size,
                              hipStream_t stream) {
  const float* node_input = (const float*)d_in[0];
  const float* node_attr  = (const float*)d_in[1];
  const int*   edge_src   = (const int*)d_in[2];
  const int*   edge_dst   = (const int*)d_in[3];
  const float* edge_attr  = (const float*)d_in[4];
  const float* ele        = (const float*)d_in[5];
  const float* sc_w0      = (const float*)d_in[6];
  const float* sc_w1      = (const float*)d_in[7];
  const float* l1_w0      = (const float*)d_in[8];
  const float* l1_w1      = (const float*)d_in[9];
  const float* fc_w0      = (const float*)d_in[10];
  const float* fc_w1      = (const float*)d_in[11];
  const float* l2_w0      = (const float*)d_in[12];
  const float* l2_w1      = (const float*)d_in[13];
  const float* l2_w2      = (const float*)d_in[14];
  float* out = (float*)d_out;

  char* base = (char*)d_ws;
  float* y              = (float*)(base);                       // 7.68 MB (stride 192)
  unsigned short* wbuf  = (unsigned short*)(base + 7680000);    // 102.4 MB packed
  float* ed2            = (float*)(base + 110080000);           // 12.8 MB (stride 20)
  int* counts           = (int*)(base + 122880000);
  int* offs             = (int*)(base + 122920000);
  int* cur              = (int*)(base + 122960000);
  int* order            = (int*)(base + 123000000);
  int* obeg             = (int*)(base + 123040000);
  int* ocnt             = (int*)(base + 123080000);
  int* dcur             = (int*)(base + 123120000);             // 1 KB
  unsigned short* fc1p  = (unsigned short*)(base + 123121024);  // 40 KB
  unsigned short* aggb  = (unsigned short*)(base + 123162624);  // 19.2 MB
  unsigned short* Wp    = (unsigned short*)(base + 142362624);  // 716.8 KB
  unsigned short* Wyp   = (unsigned short*)(base + 143079424);  // 61.4 KB

  hipLaunchKernelGGL(k_init, dim3(80), dim3(256), 0, stream, counts, fc_w1, fc1p);
  hipLaunchKernelGGL(k_wprep, dim3(1520), dim3(256), 0, stream,
                     sc_w0, sc_w1, l2_w0, l2_w1, l2_w2, l1_w0, l1_w1, Wp, Wyp);
  hipLaunchKernelGGL(k_hist, dim3((N_EDGES + 255) / 256), dim3(256), 0, stream,
                     edge_dst, counts);
  hipLaunchKernelGGL(k_scan, dim3(1), dim3(256), 0, stream, counts, offs, cur, dcur);
  hipLaunchKernelGGL(k_perm, dim3(N_EDGES / 256), dim3(256), 0, stream,
                     edge_dst, cur, counts, offs, dcur, order, obeg, ocnt,
                     ele, edge_attr, edge_src, ed2);
  hipLaunchKernelGGL(k_npre, dim3(625), dim3(256), 0, stream,
                     node_input, node_attr, Wyp, y);
  hipLaunchKernelGGL(k_mid, dim3(2500), dim3(256), 0, stream,
                     ed2, fc_w0, fc1p, wbuf);
  hipLaunchKernelGGL(node_agg, dim3(2500), dim3(256), 0, stream,
                     y, ed2, wbuf, order, obeg, ocnt, aggb);
  hipLaunchKernelGGL(k_out, dim3(625), dim3(256), 0, stream,
                     aggb, node_input, node_attr, Wp, out);
}

// Round 7
// 204.974 us; speedup vs baseline: 3.6414x; 1.0004x over previous
//
#include <hip/hip_runtime.h>
#include <cstddef>
#include <cstdint>

#define N_NODES 10000
#define N_EDGES 160000

// ---- constants ----
#define RS8    0.35355339059327373f   // 1/sqrt(8)
#define RS32   0.17677669529663687f   // 1/sqrt(32)
#define RS96   0.10206207261596575f   // 1/sqrt(96)
#define RS128  0.08838834764831845f   // 1/sqrt(128)
#define RS3    0.5773502691896258f    // 1/sqrt(3)
#define SQ3_   1.7320508075688772f
#define SQ5_   2.23606797749979f
#define A_     0.18257418583505536f   // 1/sqrt(30)
#define B_     0.31622776601683794f   // 1/sqrt(10)
#define SILU_C_ 1.6765208f
#define CS_    0.3826834323650898f    // sin(pi/8)
#define CX_    0.9238795325112867f    // cos(pi/8)
#define QDEG   0.25f                  // 1/sqrt(16)

typedef __attribute__((ext_vector_type(8))) short bf16x8;
typedef __attribute__((ext_vector_type(4))) float f32x4;

__device__ inline float bf2f(unsigned v) {
  union { unsigned u; float f; } c; c.u = v << 16; return c.f;
}
__device__ inline float bfhi(unsigned v) {   // float from HIGH 16 bits
  union { unsigned u; float f; } c; c.u = v & 0xffff0000u; return c.f;
}
__device__ inline unsigned short f2bf(float f) {
  union { float f; unsigned u; } c; c.f = f;
  unsigned r = c.u + 0x7fff + ((c.u >> 16) & 1);
  return (unsigned short)(r >> 16);
}
__device__ inline unsigned pack2bf(float a, float b) {
  return (unsigned)f2bf(a) | ((unsigned)f2bf(b) << 16);
}
__device__ inline float silu_c(float x) {
  return SILU_C_ * x / (1.f + __expf(-x));
}

// zero counts + build fc1p (fc1 64x320 -> bf16 MFMA B-fragment order) and
// fc0p (fc_w0 8x64 -> fragment order, K zero-padded 8->32, RS8 folded):
// fc0p[nt*512 + lane*8 + j] = RS8 * fc0[k=quad*8+j][oc=nt*16+ch], k<8 else 0.
__global__ void k_init(int* __restrict__ counts, const float* __restrict__ fc1,
                       unsigned short* __restrict__ fc1p,
                       const float* __restrict__ fc0,
                       unsigned short* __restrict__ fc0p) {
  int i = blockIdx.x * blockDim.x + threadIdx.x;
  if (i < N_NODES) counts[i] = 0;
  if (i < 20480) {
    int j = i & 7, q = (i >> 3) & 3, n = (i >> 5) & 15, kq = (i >> 9) & 1, t = i >> 10;
    int k = kq * 32 + q * 8 + j;
    fc1p[i] = f2bf(fc1[k * 320 + t * 16 + n]);
  } else if (i < 20480 + 2048) {
    int ii = i - 20480;
    int j = ii & 7;
    int lane = (ii >> 3) & 63;
    int ch = lane & 15, quad = lane >> 4;
    int nt = ii >> 9;                  // [0,4)
    int k = quad * 8 + j;
    float v = (k < 8) ? RS8 * fc0[k * 64 + nt * 16 + ch] : 0.f;
    fc0p[ii] = f2bf(v);
  }
}

__global__ void k_hist(const int* __restrict__ edst, int* __restrict__ counts) {
  int e = blockIdx.x * blockDim.x + threadIdx.x;
  if (e < N_EDGES) atomicAdd(&counts[edst[e]], 1);
}

// k_wprep: build (a) dense-packed bf16 epilogue weight Wp[1120][320] and
// (b) node_pre weight Wyp[160][192], both in the VERIFIED MFMA
// first-operand fragment order: linear index i = j + 8*lane + 512*(ks+KS*nt),
// lane = ch + 16*quad; value = W[k = ks*32 + quad*8 + j][oc = nt*16 + ch],
// block-sparse structure + scale factors folded in.
__global__ __launch_bounds__(256) void k_wprep(
    const float* __restrict__ sc_w0, const float* __restrict__ sc_w1,
    const float* __restrict__ w0, const float* __restrict__ w1,
    const float* __restrict__ w2, const float* __restrict__ l1_w0,
    const float* __restrict__ l1_w1, unsigned short* __restrict__ Wp,
    unsigned short* __restrict__ Wyp) {
  int i = blockIdx.x * 256 + threadIdx.x;
  if (i < 358400) {
    int j = i & 7;
    int lane = (i >> 3) & 63;
    int ch = lane & 15, quad = lane >> 4;
    int r = i >> 9;                    // [0,700)
    int nt = r / 35, ks = r - nt * 35;
    int k = ks * 32 + quad * 8 + j;
    int oc = nt * 16 + ch;
    float v = 0.f;
    if (k < 96) {                                   // m0 -> oc [0,64)
      if (oc < 64) v = (CX_ * RS96) * w0[k * 64 + oc];
    } else if (k < 480) {                           // m1 -> oc [64,160)
      int tt = k - 96, u = tt / 3, ii = tt - u * 3;
      if (oc >= 64 && oc < 160) {
        int d = oc - 64, vv = d / 3, jj = d - vv * 3;
        if (jj == ii) v = (CX_ * RS128) * w1[u * 32 + vv];
      }
    } else if (k < 960) {                           // m2 -> oc [160,320)
      int tt = k - 480, u = tt / 5, kk = tt - u * 5;
      if (oc >= 160) {
        int d = oc - 160, vv = d / 5, jj = d - vv * 5;
        if (jj == kk) v = RS96 * w2[u * 32 + vv];
      }
    } else if (k < 1024) {                          // x0 sc -> oc [0,64)
      int u = k - 960;
      if (oc < 64) v = (CS_ * 0.125f) * sc_w0[u * 64 + oc];
    } else {                                        // x1 sc -> oc [64,160)
      int tt = k - 1024, u = tt / 3, ii = tt - u * 3;
      if (oc >= 64 && oc < 160) {
        int d = oc - 64, vv = d / 3, jj = d - vv * 3;
        if (jj == ii) v = (CS_ * RS32) * sc_w1[u * 32 + vv];
      }
    }
    Wp[i] = f2bf(v);
  } else if (i < 358400 + 30720) {
    // Wyp: y[n, 0:192] = attr * (x[n,0:160] @ Wy). KS=5, NT=12.
    int ii2 = i - 358400;
    int j = ii2 & 7;
    int lane = (ii2 >> 3) & 63;
    int ch = lane & 15, quad = lane >> 4;
    int r = ii2 >> 9;                  // [0,60)
    int nt = r / 5, ks = r - nt * 5;
    int k = ks * 32 + quad * 8 + j;    // [0,160)
    int oc = nt * 16 + ch;             // [0,192)
    float v = 0.f;
    if (k < 64) {
      if (oc < 64) v = 0.125f * l1_w0[k * 64 + oc];
    } else {
      int tt = k - 64, u = tt / 3, ci = tt - u * 3;   // u<32, ci<3
      if (oc >= 64) {
        int d = oc - 64, vv = d >> 2, jj = d & 3;
        if (jj == ci) v = RS32 * l1_w1[u * 32 + vv];  // jj==3 never matches
      }
    }
    Wyp[ii2] = f2bf(v);
  }
}

// exclusive scan of counts -> offs/cur; degree histogram + descending-degree
// exclusive scan -> dcur (single block).
__global__ __launch_bounds__(256) void k_scan(const int* __restrict__ counts,
                                              int* __restrict__ offs,
                                              int* __restrict__ cur,
                                              int* __restrict__ dcur) {
  __shared__ int ps[256];
  __shared__ int dbin[256];
  int t = threadIdx.x;
  dbin[t] = 0;
  int base = t * 40;
  int sum = 0;
  for (int i = 0; i < 40; ++i) {
    int idx = base + i;
    if (idx < N_NODES) sum += counts[idx];
  }
  ps[t] = sum;
  __syncthreads();
  for (int off = 1; off < 256; off <<= 1) {
    int v = (t >= off) ? ps[t - off] : 0;
    __syncthreads();
    ps[t] += v;
    __syncthreads();
  }
  int run = (t == 0) ? 0 : ps[t - 1];
  for (int i = 0; i < 40; ++i) {
    int idx = base + i;
    if (idx < N_NODES) {
      int c = counts[idx];
      offs[idx] = run; cur[idx] = run;
      run += c;
      atomicAdd(&dbin[c < 255 ? c : 255], 1);
    }
  }
  __syncthreads();
  int rb = 255 - t;
  int v = dbin[rb];
  __syncthreads();
  ps[t] = v;
  __syncthreads();
  for (int off = 1; off < 256; off <<= 1) {
    int u = (t >= off) ? ps[t - off] : 0;
    __syncthreads();
    ps[t] += u;
    __syncthreads();
  }
  dcur[rb] = ps[t] - v;
}

// Permute kernel: per edge compute sorted position p and SCATTER-WRITE the
// permuted per-edge stream ed2 (stride 20 f): [0..8]=SH, [9]=src,
// [10,11]=pad, [12..19]=ele row. Inputs staged coalesced in LDS. Also the
// node scatter (descending-degree rank -> order/obeg/ocnt).
__global__ __launch_bounds__(256) void k_perm(
    const int* __restrict__ edst, int* __restrict__ cur,
    const int* __restrict__ counts, const int* __restrict__ offs,
    int* __restrict__ dcur, int* __restrict__ order,
    int* __restrict__ obeg, int* __restrict__ ocnt,
    const float* __restrict__ ele, const float* __restrict__ eattr,
    const int* __restrict__ esrc, float* __restrict__ ed2) {
  __shared__ __align__(16) float sh_ea[256 * 9];
  __shared__ __align__(16) float sh_el[256 * 8];
  int t = threadIdx.x;
  int eb = blockIdx.x * 256;
  int e = eb + t;
  for (int i = t; i < 2304; i += 256) sh_ea[i] = eattr[(size_t)eb * 9 + i];
  {
    const float4* src = (const float4*)(ele + (size_t)eb * 8);
    float4* dst = (float4*)sh_el;
    dst[t] = src[t]; dst[t + 256] = src[t + 256];
  }
  __syncthreads();
  int d = edst[e];
  int p = atomicAdd(&cur[d], 1);
  const float* ea = sh_ea + t * 9;
  const float* el = sh_el + t * 8;
  float4 r0 = {ea[0], ea[1], ea[2], ea[3]};
  float4 r1 = {ea[4], ea[5], ea[6], ea[7]};
  float4 r2 = {ea[8], __int_as_float(esrc[e]), 0.f, 0.f};
  float4 r3 = {el[0], el[1], el[2], el[3]};
  float4 r4 = {el[4], el[5], el[6], el[7]};
  float4* dst = (float4*)(ed2 + (size_t)p * 20);
  dst[0] = r0; dst[1] = r1; dst[2] = r2; dst[3] = r3; dst[4] = r4;
  if (e < N_NODES) {
    int c = counts[e];
    int b = c < 255 ? c : 255;
    int q = atomicAdd(&dcur[b], 1);
    order[q] = e; obeg[q] = offs[e]; ocnt[q] = c;
  }
}

__device__ inline f32x4 wtile(const unsigned short* __restrict__ fc1p,
                              bf16x8 a0, bf16x8 a1, int mrow, int quad, int t) {
  f32x4 acc = {0.f, 0.f, 0.f, 0.f};
  bf16x8 b0 = *(const bf16x8*)(fc1p + ((size_t)((t * 2 + 0) * 16 + mrow) * 4 + quad) * 8);
  bf16x8 b1 = *(const bf16x8*)(fc1p + ((size_t)((t * 2 + 1) * 16 + mrow) * 4 + quad) * 8);
  acc = __builtin_amdgcn_mfma_f32_16x16x32_bf16(b0, a0, acc, 0, 0, 0);
  acc = __builtin_amdgcn_mfma_f32_16x16x32_bf16(b1, a1, acc, 0, 0, 0);
  return acc;
}

struct WgemmShared {
  __align__(16) unsigned short elb[64 * 32];   // 4KB: ele bf16, K padded 8->32
  __align__(16) unsigned short h[64 * 72];     // 9KB, 72-stride pad
};

// STREAMING MFMA radial GEMM: 64 edges/block. h-phase is now MFMA:
// h[64e][64ch] = silu(ele @ fc0p) via 4 mfma/wave (K zero-padded to 32,
// RS8 folded into fc0p). D-layout (verified convention):
// lane l, reg r -> h[ch = nt*16 + quad*4 + r][edge = (l&15) + 16*wave].
// Pack-phase unchanged: writes packed wbuf (640 B/edge).
__device__ void w_gemm_body(WgemmShared& sh, int blk,
    const float* __restrict__ ed2, const unsigned short* __restrict__ fc0p,
    const unsigned short* __restrict__ fc1p, unsigned short* __restrict__ wout) {
  int t = threadIdx.x;
  int eb = blk * 64;
  {
    int e = t >> 2, q = t & 3;
    uint4 pk = {0u, 0u, 0u, 0u};
    if (q == 0) {
      const float4* ep = (const float4*)(ed2 + (size_t)(eb + e) * 20 + 12);
      float4 u = ep[0], v = ep[1];
      pk.x = pack2bf(u.x, u.y); pk.y = pack2bf(u.z, u.w);
      pk.z = pack2bf(v.x, v.y); pk.w = pack2bf(v.z, v.w);
    }
    *(uint4*)(sh.elb + e * 32 + q * 8) = pk;
  }
  __syncthreads();

  int wv = t >> 6, lane = t & 63;
  int ch16 = lane & 15, quad = lane >> 4;
  {
    bf16x8 af = *(const bf16x8*)(sh.elb + (wv * 16 + ch16) * 32 + quad * 8);
    bf16x8 b0 = *(const bf16x8*)(fc0p + 0 * 512 + lane * 8);
    bf16x8 b1 = *(const bf16x8*)(fc0p + 1 * 512 + lane * 8);
    bf16x8 b2 = *(const bf16x8*)(fc0p + 2 * 512 + lane * 8);
    bf16x8 b3 = *(const bf16x8*)(fc0p + 3 * 512 + lane * 8);
    f32x4 z = {0.f, 0.f, 0.f, 0.f};
    f32x4 h0 = __builtin_amdgcn_mfma_f32_16x16x32_bf16(b0, af, z, 0, 0, 0);
    f32x4 h1 = __builtin_amdgcn_mfma_f32_16x16x32_bf16(b1, af, z, 0, 0, 0);
    f32x4 h2 = __builtin_amdgcn_mfma_f32_16x16x32_bf16(b2, af, z, 0, 0, 0);
    f32x4 h3 = __builtin_amdgcn_mfma_f32_16x16x32_bf16(b3, af, z, 0, 0, 0);
    unsigned short* hb = sh.h + (wv * 16 + ch16) * 72 + quad * 4;
    uint2 s;
    s.x = pack2bf(silu_c(h0[0]), silu_c(h0[1]));
    s.y = pack2bf(silu_c(h0[2]), silu_c(h0[3]));
    *(uint2*)(hb + 0) = s;
    s.x = pack2bf(silu_c(h1[0]), silu_c(h1[1]));
    s.y = pack2bf(silu_c(h1[2]), silu_c(h1[3]));
    *(uint2*)(hb + 16) = s;
    s.x = pack2bf(silu_c(h2[0]), silu_c(h2[1]));
    s.y = pack2bf(silu_c(h2[2]), silu_c(h2[3]));
    *(uint2*)(hb + 32) = s;
    s.x = pack2bf(silu_c(h3[0]), silu_c(h3[1]));
    s.y = pack2bf(silu_c(h3[2]), silu_c(h3[3]));
    *(uint2*)(hb + 48) = s;
  }
  __syncthreads();

  int m0 = wv * 16;
  int mrow = lane & 15;
  bf16x8 a0 = *(const bf16x8*)(sh.h + (m0 + mrow) * 72 + quad * 8);
  bf16x8 a1 = *(const bf16x8*)(sh.h + (m0 + mrow) * 72 + 32 + quad * 8);
  char* wbase = (char*)wout + (size_t)(eb + m0 + mrow) * 640;
  const float K = 0.125f;
  #pragma unroll
  for (int tt = 0; tt < 4; ++tt) {
    f32x4 Av = wtile(fc1p, a0, a1, mrow, quad, tt);
    f32x4 Bv = wtile(fc1p, a0, a1, mrow, quad, tt + 4);
    uint4 st;
    st.x = pack2bf(Av[0] * K, Bv[0] * K);
    st.y = pack2bf(Av[1] * K, Bv[1] * K);
    st.z = pack2bf(Av[2] * K, Bv[2] * K);
    st.w = pack2bf(Av[3] * K, Bv[3] * K);
    *(uint4*)(wbase + 64 * tt + 16 * quad) = st;
  }
  #pragma unroll
  for (int tt = 8; tt < 12; ++tt) {
    f32x4 Cv = wtile(fc1p, a0, a1, mrow, quad, tt);
    uint2 st;
    st.x = pack2bf(Cv[0] * K, Cv[1] * K);
    st.y = pack2bf(Cv[2] * K, Cv[3] * K);
    *(uint2*)(wbase + 256 + 32 * (tt - 8) + 8 * quad) = st;
  }
  #pragma unroll
  for (int tt = 12; tt < 14; ++tt) {
    f32x4 Dv = wtile(fc1p, a0, a1, mrow, quad, tt);
    f32x4 Ev = wtile(fc1p, a0, a1, mrow, quad, tt + 2);
    f32x4 Fv = wtile(fc1p, a0, a1, mrow, quad, tt + 4);
    f32x4 Gv = wtile(fc1p, a0, a1, mrow, quad, tt + 6);
    char* db = wbase + 384 + 128 * (tt - 12) + 32 * quad;
    uint4 s0, s1;
    s0.x = pack2bf(Dv[0] * K, Ev[0] * K); s0.y = pack2bf(Fv[0] * K, Gv[0] * K);
    s0.z = pack2bf(Dv[1] * K, Ev[1] * K); s0.w = pack2bf(Fv[1] * K, Gv[1] * K);
    s1.x = pack2bf(Dv[2] * K, Ev[2] * K); s1.y = pack2bf(Fv[2] * K, Gv[2] * K);
    s1.z = pack2bf(Dv[3] * K, Ev[3] * K); s1.w = pack2bf(Fv[3] * K, Gv[3] * K);
    *(uint4*)(db) = s0;
    *(uint4*)(db + 16) = s1;
  }
}

// k_mid: w_gemm only
__global__ __launch_bounds__(256) void k_mid(
    const float* __restrict__ ed2, const unsigned short* __restrict__ fc0p,
    const unsigned short* __restrict__ fc1p, unsigned short* __restrict__ wout) {
  __shared__ WgemmShared sh;
  w_gemm_body(sh, blockIdx.x, ed2, fc0p, fc1p, wout);
}

// k_npre (MFMA): y[n, 0:192] = attr[n] * (bf16(xin[n,0:160]) @ Wyp).
#define YSTR 168
__global__ __launch_bounds__(256) void k_npre(
    const float* __restrict__ xin, const float* __restrict__ attr,
    const unsigned short* __restrict__ Wyp, float* __restrict__ y) {
  __shared__ __align__(16) unsigned short Ash[16 * YSTR];
  int t = threadIdx.x;
  int nbase = blockIdx.x * 16;
  for (int idx = t; idx < 16 * 80; idx += 256) {
    int row = idx / 80, c = idx - row * 80;
    const float* xp = xin + (size_t)(nbase + row) * 160 + 2 * c;
    *(unsigned*)(Ash + row * YSTR + 2 * c) = pack2bf(xp[0], xp[1]);
  }
  __syncthreads();
  int wid = t >> 6, lane = t & 63;
  int ch = lane & 15, quad = lane >> 4;
  const unsigned short* arow = Ash + ch * YSTR + quad * 8;
  f32x4 acc0 = {0.f,0.f,0.f,0.f}, acc1 = {0.f,0.f,0.f,0.f}, acc2 = {0.f,0.f,0.f,0.f};
  const unsigned short* wq0 = Wyp + ((size_t)(wid * 3 + 0) * 5 * 64 + lane) * 8;
  const unsigned short* wq1 = Wyp + ((size_t)(wid * 3 + 1) * 5 * 64 + lane) * 8;
  const unsigned short* wq2 = Wyp + ((size_t)(wid * 3 + 2) * 5 * 64 + lane) * 8;
  #pragma unroll
  for (int ks = 0; ks < 5; ++ks) {
    bf16x8 af  = *(const bf16x8*)(arow + ks * 32);
    bf16x8 w0f = *(const bf16x8*)(wq0 + ks * 512);
    bf16x8 w1f = *(const bf16x8*)(wq1 + ks * 512);
    bf16x8 w2f = *(const bf16x8*)(wq2 + ks * 512);
    acc0 = __builtin_amdgcn_mfma_f32_16x16x32_bf16(w0f, af, acc0, 0, 0, 0);
    acc1 = __builtin_amdgcn_mfma_f32_16x16x32_bf16(w1f, af, acc1, 0, 0, 0);
    acc2 = __builtin_amdgcn_mfma_f32_16x16x32_bf16(w2f, af, acc2, 0, 0, 0);
  }
  float a = attr[nbase + ch];
  float* yrow = y + (size_t)(nbase + ch) * 192 + quad * 4;
  { float4 st = {acc0[0]*a, acc0[1]*a, acc0[2]*a, acc0[3]*a};
    *(float4*)(yrow + (wid * 3 + 0) * 16) = st; }
  { float4 st = {acc1[0]*a, acc1[1]*a, acc1[2]*a, acc1[3]*a};
    *(float4*)(yrow + (wid * 3 + 1) * 16) = st; }
  { float4 st = {acc2[0]*a, acc2[1]*a, acc2[2]*a, acc2[3]*a};
    *(float4*)(yrow + (wid * 3 + 2) * 16) = st; }
}

// node_agg: round-0 proven loop (2-slot pipeline); accumulators stored
// directly to the per-node agg buffer (bf16, QDEG-scaled). No LDS.
__global__ __launch_bounds__(256) void node_agg(
    const float* __restrict__ y, const float* __restrict__ ed2,
    const unsigned short* __restrict__ wbuf,
    const int* __restrict__ order, const int* __restrict__ obeg,
    const int* __restrict__ ocnt, unsigned short* __restrict__ aggb) {
  int tid = threadIdx.x, wid = tid >> 6, lane = tid & 63, l31 = lane & 31;
  int gw = blockIdx.x * 4 + wid;
  // fixed per-lane byte offsets (loop-invariant)
  int voY  = 4 * lane;           // y scalar block
  int voX  = 256 + 16 * l31;     // y vector float4 {x0,x1,x2,0}
  int voAB = 4 * lane;           // wbuf AB
  int voC  = 256 + 2 * lane;     // wbuf C
  int voDG = 384 + 8 * l31;      // wbuf DEFG

#define E_LOAD(S, idx)                                                         \
  if ((idx) < cnt) {                                                           \
    const float4* ep = (const float4*)(ed2 + (size_t)(beg + (idx)) * 20);      \
    PE0##S = ep[0]; PE1##S = ep[1]; PE2##S = ep[2];                            \
  }
#define V_LOAD(S, idx)                                                         \
  if ((idx) < cnt) {                                                           \
    int srcn = __float_as_int(PE2##S.y);                                       \
    const char* yb = (const char*)y + (size_t)srcn * 768;                      \
    Y##S = *(const float*)(yb + voY);                                          \
    X##S = *(const f32x4*)(yb + voX);                                          \
    const char* wb = (const char*)wbuf + (size_t)(beg + (idx)) * 640;          \
    AB##S = *(const unsigned*)(wb + voAB);                                     \
    Cw##S = *(const unsigned short*)(wb + voC);                                \
    DG##S = *(const uint2*)(wb + voDG);                                        \
  }
#define COMPUTE(S)                                                             \
  {                                                                            \
    float e0 = PE0##S.x, ey = PE0##S.y, ez = PE0##S.z, ex = PE0##S.w;          \
    float q0 = PE1##S.x, q1 = PE1##S.y, q2 = PE1##S.z, q3 = PE1##S.w;          \
    float q4 = PE2##S.x;                                                       \
    float Yv = Y##S, x0 = X##S.x, x1 = X##S.y, x2 = X##S.z;                    \
    float vA = bf2f(AB##S), vB = bfhi(AB##S), vC = bf2f(Cw##S);                \
    float vD = bf2f(DG##S.x), vE = bfhi(DG##S.x);                              \
    float vF = bf2f(DG##S.y), vG = bfhi(DG##S.y);                              \
    aK0 += Yv * e0 * vA;                                                       \
    float tB = Yv * vB; aK2x += tB * ey; aK2y += tB * ez; aK2z += tB * ex;     \
    float tC = Yv * vC;                                                        \
    aK5a += tC * q0; aK5b += tC * q1; aK5c += tC * q2;                         \
    aK5d += tC * q3; aK5e += tC * q4;                                          \
    float t1 = x0 * ey + x1 * ez + x2 * ex; aK1 += (RS3 * vE) * t1;            \
    float s3 = e0 * vD; aK3x += x0 * s3; aK3y += x1 * s3; aK3z += x2 * s3;     \
    float s4 = SQ3_ * vG;                                                      \
    aK4x += s4 * (B_ * (x2 * q0 + x1 * q1 - x0 * q4) - A_ * x0 * q2);          \
    aK4y += s4 * (B_ * (x0 * q1 + x2 * q3) + 2.f * A_ * x1 * q2);              \
    aK4z += s4 * (B_ * (x0 * q0 + x1 * q3 + x2 * q4) - A_ * x2 * q2);          \
    float s6 = SQ5_ * vF;                                                      \
    aK6a += s6 * (-B_ * (x0 * ex + x2 * ey));                                  \
    aK6b += s6 * (-B_ * (x0 * ez + x1 * ey));                                  \
    aK6c += s6 * ( A_ * (x0 * ey + x2 * ex - 2.f * x1 * ez));                  \
    aK6d += s6 * (-B_ * (x1 * ex + x2 * ez));                                  \
    aK6e += s6 * ( B_ * (x0 * ey - x2 * ex));                                  \
  }

  int n = order[gw], beg = obeg[gw], cnt = ocnt[gw];

  float aK0 = 0.f, aK2x = 0.f, aK2y = 0.f, aK2z = 0.f;
  float aK5a = 0.f, aK5b = 0.f, aK5c = 0.f, aK5d = 0.f, aK5e = 0.f;
  float aK1 = 0.f, aK3x = 0.f, aK3y = 0.f, aK3z = 0.f;
  float aK4x = 0.f, aK4y = 0.f, aK4z = 0.f;
  float aK6a = 0.f, aK6b = 0.f, aK6c = 0.f, aK6d = 0.f, aK6e = 0.f;

  float4 PE0a, PE1a, PE2a, PE0b, PE1b, PE2b;
  float Ya, Yb; f32x4 Xa, Xb;
  unsigned ABa, ABb; unsigned short Cwa, Cwb;
  uint2 DGa, DGb;

  E_LOAD(a, 0)
  E_LOAD(b, 1)
  V_LOAD(a, 0)

  int i = 0;
  while (i < cnt) {
    V_LOAD(b, i + 1)
    COMPUTE(a)
    E_LOAD(a, i + 2)
    ++i; if (i >= cnt) break;
    V_LOAD(a, i + 1)
    COMPUTE(b)
    E_LOAD(b, i + 2)
    ++i;
  }

  // store accumulators (QDEG-scaled, bf16) to the node's agg row [960]
  unsigned short* ag = aggb + (size_t)n * 960;
  ag[lane]           = f2bf(aK0  * QDEG);
  ag[96 + 3 * lane]  = f2bf(aK2x * QDEG);
  ag[97 + 3 * lane]  = f2bf(aK2y * QDEG);
  ag[98 + 3 * lane]  = f2bf(aK2z * QDEG);
  ag[480 + 5 * lane] = f2bf(aK5a * QDEG);
  ag[481 + 5 * lane] = f2bf(aK5b * QDEG);
  ag[482 + 5 * lane] = f2bf(aK5c * QDEG);
  ag[483 + 5 * lane] = f2bf(aK5d * QDEG);
  ag[484 + 5 * lane] = f2bf(aK5e * QDEG);
  if (lane < 32) {
    ag[64 + lane]      = f2bf(aK1  * QDEG);
    ag[288 + 3 * lane] = f2bf(aK3x * QDEG);
    ag[289 + 3 * lane] = f2bf(aK3y * QDEG);
    ag[290 + 3 * lane] = f2bf(aK3z * QDEG);
    ag[384 + 3 * lane] = f2bf(aK4x * QDEG);
    ag[385 + 3 * lane] = f2bf(aK4y * QDEG);
    ag[386 + 3 * lane] = f2bf(aK4z * QDEG);
    ag[800 + 5 * lane] = f2bf(aK6a * QDEG);
    ag[801 + 5 * lane] = f2bf(aK6b * QDEG);
    ag[802 + 5 * lane] = f2bf(aK6c * QDEG);
    ag[803 + 5 * lane] = f2bf(aK6d * QDEG);
    ag[804 + 5 * lane] = f2bf(aK6e * QDEG);
  }
#undef E_LOAD
#undef V_LOAD
#undef COMPUTE
}

// k_out (MFMA): out[n,0:320] = attr[n] * (A[n,0:1120] @ W).
#define ASTR 1128
__global__ __launch_bounds__(256) void k_out(
    const unsigned short* __restrict__ aggb, const float* __restrict__ xin,
    const float* __restrict__ attr, const unsigned short* __restrict__ Wp,
    float* __restrict__ out) {
  __shared__ __align__(16) unsigned short Ash[16 * ASTR];
  int t = threadIdx.x;
  int nbase = blockIdx.x * 16;
  for (int idx = t; idx < 16 * 480; idx += 256) {
    int row = idx / 480, c = idx - row * 480;
    *(unsigned*)(Ash + row * ASTR + 2 * c) =
        *(const unsigned*)(aggb + (size_t)(nbase + row) * 960 + 2 * c);
  }
  for (int idx = t; idx < 16 * 80; idx += 256) {
    int row = idx / 80, c = idx - row * 80;
    const float* xp = xin + (size_t)(nbase + row) * 160 + 2 * c;
    *(unsigned*)(Ash + row * ASTR + 960 + 2 * c) = pack2bf(xp[0], xp[1]);
  }
  __syncthreads();

  int wid = t >> 6, lane = t & 63;
  int ch = lane & 15, quad = lane >> 4;
  f32x4 acc0 = {0.f,0.f,0.f,0.f}, acc1 = {0.f,0.f,0.f,0.f};
  f32x4 acc2 = {0.f,0.f,0.f,0.f}, acc3 = {0.f,0.f,0.f,0.f};
  f32x4 acc4 = {0.f,0.f,0.f,0.f};
  const unsigned short* arow = Ash + ch * ASTR + quad * 8;
  const unsigned short* wq0 = Wp + ((size_t)(wid * 5 + 0) * 35 * 64 + lane) * 8;
  const unsigned short* wq1 = Wp + ((size_t)(wid * 5 + 1) * 35 * 64 + lane) * 8;
  const unsigned short* wq2 = Wp + ((size_t)(wid * 5 + 2) * 35 * 64 + lane) * 8;
  const unsigned short* wq3 = Wp + ((size_t)(wid * 5 + 3) * 35 * 64 + lane) * 8;
  const unsigned short* wq4 = Wp + ((size_t)(wid * 5 + 4) * 35 * 64 + lane) * 8;
  for (int ks = 0; ks < 35; ++ks) {
    bf16x8 af = *(const bf16x8*)(arow + ks * 32);
    bf16x8 w0f = *(const bf16x8*)(wq0 + ks * 512);
    bf16x8 w1f = *(const bf16x8*)(wq1 + ks * 512);
    bf16x8 w2f = *(const bf16x8*)(wq2 + ks * 512);
    bf16x8 w3f = *(const bf16x8*)(wq3 + ks * 512);
    bf16x8 w4f = *(const bf16x8*)(wq4 + ks * 512);
    acc0 = __builtin_amdgcn_mfma_f32_16x16x32_bf16(w0f, af, acc0, 0, 0, 0);
    acc1 = __builtin_amdgcn_mfma_f32_16x16x32_bf16(w1f, af, acc1, 0, 0, 0);
    acc2 = __builtin_amdgcn_mfma_f32_16x16x32_bf16(w2f, af, acc2, 0, 0, 0);
    acc3 = __builtin_amdgcn_mfma_f32_16x16x32_bf16(w3f, af, acc3, 0, 0, 0);
    acc4 = __builtin_amdgcn_mfma_f32_16x16x32_bf16(w4f, af, acc4, 0, 0, 0);
  }
  float a = attr[nbase + ch];
  float* orow = out + (size_t)(nbase + ch) * 320 + quad * 4;
  {
    float4 st = {acc0[0]*a, acc0[1]*a, acc0[2]*a, acc0[3]*a};
    *(float4*)(orow + (wid * 5 + 0) * 16) = st;
  }
  {
    float4 st = {acc1[0]*a, acc1[1]*a, acc1[2]*a, acc1[3]*a};
    *(float4*)(orow + (wid * 5 + 1) * 16) = st;
  }
  {
    float4 st = {acc2[0]*a, acc2[1]*a, acc2[2]*a, acc2[3]*a};
    *(float4*)(orow + (wid * 5 + 2) * 16) = st;
  }
  {
    float4 st = {acc3[0]*a, acc3[1]*a, acc3[2]*a, acc3[3]*a};
    *(float4*)(orow + (wid * 5 + 3) * 16) = st;
  }
  {
    float4 st = {acc4[0]*a, acc4[1]*a, acc4[2]*a, acc4[3]*a};
    *(float4*)(orow + (wid * 5 + 4) * 16) = st;
  }
}

extern "C" void kernel_launch(void* const* d_in, const int* in_sizes, int n_in,
                              void* d_out, int out_size, void* d_ws, size_t ws_size,
                              hipStream_t stream) {
  const float* node_input = (const float*)d_in[0];
  const float* node_attr  = (const float*)d_in[1];
  const int*   edge_src   = (const int*)d_in[2];
  const int*   edge_dst   = (const int*)d_in[3];
  const float* edge_attr  = (const float*)d_in[4];
  const float* ele        = (const float*)d_in[5];
  const float* sc_w0      = (const float*)d_in[6];
  const float* sc_w1      = (const float*)d_in[7];
  const float* l1_w0      = (const float*)d_in[8];
  const float* l1_w1      = (const float*)d_in[9];
  const float* fc_w0      = (const float*)d_in[10];
  const float* fc_w1      = (const float*)d_in[11];
  const float* l2_w0      = (const float*)d_in[12];
  const float* l2_w1      = (const float*)d_in[13];
  const float* l2_w2      = (const float*)d_in[14];
  float* out = (float*)d_out;

  char* base = (char*)d_ws;
  float* y              = (float*)(base);                       // 7.68 MB (stride 192)
  unsigned short* wbuf  = (unsigned short*)(base + 7680000);    // 102.4 MB packed
  float* ed2            = (float*)(base + 110080000);           // 12.8 MB (stride 20)
  int* counts           = (int*)(base + 122880000);
  int* offs             = (int*)(base + 122920000);
  int* cur              = (int*)(base + 122960000);
  int* order            = (int*)(base + 123000000);
  int* obeg             = (int*)(base + 123040000);
  int* ocnt             = (int*)(base + 123080000);
  int* dcur             = (int*)(base + 123120000);             // 1 KB
  unsigned short* fc1p  = (unsigned short*)(base + 123121024);  // 40 KB
  unsigned short* aggb  = (unsigned short*)(base + 123162624);  // 19.2 MB
  unsigned short* Wp    = (unsigned short*)(base + 142362624);  // 716.8 KB
  unsigned short* Wyp   = (unsigned short*)(base + 143079424);  // 61.4 KB
  unsigned short* fc0p  = (unsigned short*)(base + 143140864);  // 4 KB

  hipLaunchKernelGGL(k_init, dim3(88), dim3(256), 0, stream, counts, fc_w1, fc1p,
                     fc_w0, fc0p);
  hipLaunchKernelGGL(k_wprep, dim3(1520), dim3(256), 0, stream,
                     sc_w0, sc_w1, l2_w0, l2_w1, l2_w2, l1_w0, l1_w1, Wp, Wyp);
  hipLaunchKernelGGL(k_hist, dim3((N_EDGES + 255) / 256), dim3(256), 0, stream,
                     edge_dst, counts);
  hipLaunchKernelGGL(k_scan, dim3(1), dim3(256), 0, stream, counts, offs, cur, dcur);
  hipLaunchKernelGGL(k_perm, dim3(N_EDGES / 256), dim3(256), 0, stream,
                     edge_dst, cur, counts, offs, dcur, order, obeg, ocnt,
                     ele, edge_attr, edge_src, ed2);
  hipLaunchKernelGGL(k_npre, dim3(625), dim3(256), 0, stream,
                     node_input, node_attr, Wyp, y);
  hipLaunchKernelGGL(k_mid, dim3(2500), dim3(256), 0, stream,
                     ed2, fc0p, fc1p, wbuf);
  hipLaunchKernelGGL(node_agg, dim3(2500), dim3(256), 0, stream,
                     y, ed2, wbuf, order, obeg, ocnt, aggb);
  hipLaunchKernelGGL(k_out, dim3(625), dim3(256), 0, stream,
                     aggb, node_input, node_attr, Wp, out);
}

// Round 8
// 197.752 us; speedup vs baseline: 3.7744x; 1.0365x over previous
//
#include <hip/hip_runtime.h>
#include <cstddef>
#include <cstdint>

#define N_NODES 10000
#define N_EDGES 160000

// ---- constants ----
#define RS8    0.35355339059327373f   // 1/sqrt(8)
#define RS32   0.17677669529663687f   // 1/sqrt(32)
#define RS96   0.10206207261596575f   // 1/sqrt(96)
#define RS128  0.08838834764831845f   // 1/sqrt(128)
#define RS3    0.5773502691896258f    // 1/sqrt(3)
#define SQ3_   1.7320508075688772f
#define SQ5_   2.23606797749979f
#define A_     0.18257418583505536f   // 1/sqrt(30)
#define B_     0.31622776601683794f   // 1/sqrt(10)
#define SILU_C_ 1.6765208f
#define CS_    0.3826834323650898f    // sin(pi/8)
#define CX_    0.9238795325112867f    // cos(pi/8)
#define QDEG   0.25f                  // 1/sqrt(16)

typedef __attribute__((ext_vector_type(8))) short bf16x8;
typedef __attribute__((ext_vector_type(4))) float f32x4;

__device__ inline float bf2f(unsigned v) {
  union { unsigned u; float f; } c; c.u = v << 16; return c.f;
}
__device__ inline float bfhi(unsigned v) {   // float from HIGH 16 bits
  union { unsigned u; float f; } c; c.u = v & 0xffff0000u; return c.f;
}
__device__ inline unsigned short f2bf(float f) {
  union { float f; unsigned u; } c; c.f = f;
  unsigned r = c.u + 0x7fff + ((c.u >> 16) & 1);
  return (unsigned short)(r >> 16);
}
__device__ inline unsigned pack2bf(float a, float b) {
  return (unsigned)f2bf(a) | ((unsigned)f2bf(b) << 16);
}
__device__ inline float silu_c(float x) {
  return SILU_C_ * x / (1.f + __expf(-x));
}

// k_prep: fused (counts pre-zeroed by hipMemsetAsync):
//  blocks [0,625)     : edge-dst histogram (atomics)
//  blocks [625,713)   : fc1p (fc1 64x320 -> MFMA B-frag order) + fc0p
//                       (fc_w0 8x64 -> frag order, K padded 8->32, RS8 folded)
//  blocks [713,2233)  : Wp[1120][320] + Wyp[160][192] in the VERIFIED MFMA
//                       first-operand fragment order (scales folded)
__global__ __launch_bounds__(256) void k_prep(
    const int* __restrict__ edst, int* __restrict__ counts,
    const float* __restrict__ fc1, unsigned short* __restrict__ fc1p,
    const float* __restrict__ fc0, unsigned short* __restrict__ fc0p,
    const float* __restrict__ sc_w0, const float* __restrict__ sc_w1,
    const float* __restrict__ w0, const float* __restrict__ w1,
    const float* __restrict__ w2, const float* __restrict__ l1_w0,
    const float* __restrict__ l1_w1, unsigned short* __restrict__ Wp,
    unsigned short* __restrict__ Wyp) {
  int b = blockIdx.x, t = threadIdx.x;
  if (b < 625) {
    int e = b * 256 + t;
    if (e < N_EDGES) atomicAdd(&counts[edst[e]], 1);
    return;
  }
  if (b < 713) {
    int i = (b - 625) * 256 + t;
    if (i < 20480) {
      int j = i & 7, q = (i >> 3) & 3, n = (i >> 5) & 15, kq = (i >> 9) & 1, tt = i >> 10;
      int k = kq * 32 + q * 8 + j;
      fc1p[i] = f2bf(fc1[k * 320 + tt * 16 + n]);
    } else if (i < 22528) {
      int ii = i - 20480;
      int j = ii & 7;
      int lane = (ii >> 3) & 63;
      int ch = lane & 15, quad = lane >> 4;
      int nt = ii >> 9;                  // [0,4)
      int k = quad * 8 + j;
      float v = (k < 8) ? RS8 * fc0[k * 64 + nt * 16 + ch] : 0.f;
      fc0p[ii] = f2bf(v);
    }
    return;
  }
  int i = (b - 713) * 256 + t;
  if (i < 358400) {
    int j = i & 7;
    int lane = (i >> 3) & 63;
    int ch = lane & 15, quad = lane >> 4;
    int r = i >> 9;                    // [0,700)
    int nt = r / 35, ks = r - nt * 35;
    int k = ks * 32 + quad * 8 + j;
    int oc = nt * 16 + ch;
    float v = 0.f;
    if (k < 96) {                                   // m0 -> oc [0,64)
      if (oc < 64) v = (CX_ * RS96) * w0[k * 64 + oc];
    } else if (k < 480) {                           // m1 -> oc [64,160)
      int tt = k - 96, u = tt / 3, ii = tt - u * 3;
      if (oc >= 64 && oc < 160) {
        int d = oc - 64, vv = d / 3, jj = d - vv * 3;
        if (jj == ii) v = (CX_ * RS128) * w1[u * 32 + vv];
      }
    } else if (k < 960) {                           // m2 -> oc [160,320)
      int tt = k - 480, u = tt / 5, kk = tt - u * 5;
      if (oc >= 160) {
        int d = oc - 160, vv = d / 5, jj = d - vv * 5;
        if (jj == kk) v = RS96 * w2[u * 32 + vv];
      }
    } else if (k < 1024) {                          // x0 sc -> oc [0,64)
      int u = k - 960;
      if (oc < 64) v = (CS_ * 0.125f) * sc_w0[u * 64 + oc];
    } else {                                        // x1 sc -> oc [64,160)
      int tt = k - 1024, u = tt / 3, ii = tt - u * 3;
      if (oc >= 64 && oc < 160) {
        int d = oc - 64, vv = d / 3, jj = d - vv * 3;
        if (jj == ii) v = (CS_ * RS32) * sc_w1[u * 32 + vv];
      }
    }
    Wp[i] = f2bf(v);
  } else if (i < 358400 + 30720) {
    // Wyp: y[n, 0:192] = attr * (x[n,0:160] @ Wy). KS=5, NT=12.
    int ii2 = i - 358400;
    int j = ii2 & 7;
    int lane = (ii2 >> 3) & 63;
    int ch = lane & 15, quad = lane >> 4;
    int r = ii2 >> 9;                  // [0,60)
    int nt = r / 5, ks = r - nt * 5;
    int k = ks * 32 + quad * 8 + j;    // [0,160)
    int oc = nt * 16 + ch;             // [0,192)
    float v = 0.f;
    if (k < 64) {
      if (oc < 64) v = 0.125f * l1_w0[k * 64 + oc];
    } else {
      int tt = k - 64, u = tt / 3, ci = tt - u * 3;   // u<32, ci<3
      if (oc >= 64) {
        int d = oc - 64, vv = d >> 2, jj = d & 3;
        if (jj == ci) v = RS32 * l1_w1[u * 32 + vv];  // jj==3 never matches
      }
    }
    Wyp[ii2] = f2bf(v);
  }
}

// exclusive scan of counts -> offs/cur; degree histogram + descending-degree
// exclusive scan -> dcur (single block).
__global__ __launch_bounds__(256) void k_scan(const int* __restrict__ counts,
                                              int* __restrict__ offs,
                                              int* __restrict__ cur,
                                              int* __restrict__ dcur) {
  __shared__ int ps[256];
  __shared__ int dbin[256];
  int t = threadIdx.x;
  dbin[t] = 0;
  int base = t * 40;
  int sum = 0;
  for (int i = 0; i < 40; ++i) {
    int idx = base + i;
    if (idx < N_NODES) sum += counts[idx];
  }
  ps[t] = sum;
  __syncthreads();
  for (int off = 1; off < 256; off <<= 1) {
    int v = (t >= off) ? ps[t - off] : 0;
    __syncthreads();
    ps[t] += v;
    __syncthreads();
  }
  int run = (t == 0) ? 0 : ps[t - 1];
  for (int i = 0; i < 40; ++i) {
    int idx = base + i;
    if (idx < N_NODES) {
      int c = counts[idx];
      offs[idx] = run; cur[idx] = run;
      run += c;
      atomicAdd(&dbin[c < 255 ? c : 255], 1);
    }
  }
  __syncthreads();
  int rb = 255 - t;
  int v = dbin[rb];
  __syncthreads();
  ps[t] = v;
  __syncthreads();
  for (int off = 1; off < 256; off <<= 1) {
    int u = (t >= off) ? ps[t - off] : 0;
    __syncthreads();
    ps[t] += u;
    __syncthreads();
  }
  dcur[rb] = ps[t] - v;
}

// Permute kernel (r1/r2-verified split form): per edge compute sorted
// position p and SCATTER-WRITE two permuted streams:
//   ed2a (stride 12 f): [0..8]=SH, [9]=src, [10,11]=pad   (node_agg input)
//   ed2b (stride  8 f): ele row                            (w_gemm input)
// Also the node scatter (descending-degree rank -> order/obeg/ocnt).
__global__ __launch_bounds__(256) void k_perm(
    const int* __restrict__ edst, int* __restrict__ cur,
    const int* __restrict__ counts, const int* __restrict__ offs,
    int* __restrict__ dcur, int* __restrict__ order,
    int* __restrict__ obeg, int* __restrict__ ocnt,
    const float* __restrict__ ele, const float* __restrict__ eattr,
    const int* __restrict__ esrc, float* __restrict__ ed2a,
    float* __restrict__ ed2b) {
  __shared__ __align__(16) float sh_ea[256 * 9];
  __shared__ __align__(16) float sh_el[256 * 8];
  int t = threadIdx.x;
  int eb = blockIdx.x * 256;
  int e = eb + t;
  for (int i = t; i < 2304; i += 256) sh_ea[i] = eattr[(size_t)eb * 9 + i];
  {
    const float4* src = (const float4*)(ele + (size_t)eb * 8);
    float4* dst = (float4*)sh_el;
    dst[t] = src[t]; dst[t + 256] = src[t + 256];
  }
  __syncthreads();
  int d = edst[e];
  int p = atomicAdd(&cur[d], 1);
  const float* ea = sh_ea + t * 9;
  const float* el = sh_el + t * 8;
  float4 r0 = {ea[0], ea[1], ea[2], ea[3]};
  float4 r1 = {ea[4], ea[5], ea[6], ea[7]};
  float4 r2 = {ea[8], __int_as_float(esrc[e]), 0.f, 0.f};
  float4* da = (float4*)(ed2a + (size_t)p * 12);
  da[0] = r0; da[1] = r1; da[2] = r2;
  float4 r3 = {el[0], el[1], el[2], el[3]};
  float4 r4 = {el[4], el[5], el[6], el[7]};
  float4* db = (float4*)(ed2b + (size_t)p * 8);
  db[0] = r3; db[1] = r4;
  if (e < N_NODES) {
    int c = counts[e];
    int b = c < 255 ? c : 255;
    int q = atomicAdd(&dcur[b], 1);
    order[q] = e; obeg[q] = offs[e]; ocnt[q] = c;
  }
}

__device__ inline f32x4 wtile(const unsigned short* __restrict__ fc1p,
                              bf16x8 a0, bf16x8 a1, int mrow, int quad, int t) {
  f32x4 acc = {0.f, 0.f, 0.f, 0.f};
  bf16x8 b0 = *(const bf16x8*)(fc1p + ((size_t)((t * 2 + 0) * 16 + mrow) * 4 + quad) * 8);
  bf16x8 b1 = *(const bf16x8*)(fc1p + ((size_t)((t * 2 + 1) * 16 + mrow) * 4 + quad) * 8);
  acc = __builtin_amdgcn_mfma_f32_16x16x32_bf16(b0, a0, acc, 0, 0, 0);
  acc = __builtin_amdgcn_mfma_f32_16x16x32_bf16(b1, a1, acc, 0, 0, 0);
  return acc;
}

struct WgemmShared {
  __align__(16) unsigned short elb[64 * 32];   // 4KB: ele bf16, K padded 8->32
  __align__(16) unsigned short h[64 * 72];     // 9KB, 72-stride pad
};

// STREAMING MFMA radial GEMM: 64 edges/block, reads ele from ed2b
// (sequential, stride 8 f). h-phase MFMA (verified r7); pack-phase writes
// packed wbuf (640 B/edge).
__device__ void w_gemm_body(WgemmShared& sh, int blk,
    const float* __restrict__ ed2b, const unsigned short* __restrict__ fc0p,
    const unsigned short* __restrict__ fc1p, unsigned short* __restrict__ wout) {
  int t = threadIdx.x;
  int eb = blk * 64;
  {
    int e = t >> 2, q = t & 3;
    uint4 pk = {0u, 0u, 0u, 0u};
    if (q == 0) {
      const float4* ep = (const float4*)(ed2b + (size_t)(eb + e) * 8);
      float4 u = ep[0], v = ep[1];
      pk.x = pack2bf(u.x, u.y); pk.y = pack2bf(u.z, u.w);
      pk.z = pack2bf(v.x, v.y); pk.w = pack2bf(v.z, v.w);
    }
    *(uint4*)(sh.elb + e * 32 + q * 8) = pk;
  }
  __syncthreads();

  int wv = t >> 6, lane = t & 63;
  int ch16 = lane & 15, quad = lane >> 4;
  {
    bf16x8 af = *(const bf16x8*)(sh.elb + (wv * 16 + ch16) * 32 + quad * 8);
    bf16x8 b0 = *(const bf16x8*)(fc0p + 0 * 512 + lane * 8);
    bf16x8 b1 = *(const bf16x8*)(fc0p + 1 * 512 + lane * 8);
    bf16x8 b2 = *(const bf16x8*)(fc0p + 2 * 512 + lane * 8);
    bf16x8 b3 = *(const bf16x8*)(fc0p + 3 * 512 + lane * 8);
    f32x4 z = {0.f, 0.f, 0.f, 0.f};
    f32x4 h0 = __builtin_amdgcn_mfma_f32_16x16x32_bf16(b0, af, z, 0, 0, 0);
    f32x4 h1 = __builtin_amdgcn_mfma_f32_16x16x32_bf16(b1, af, z, 0, 0, 0);
    f32x4 h2 = __builtin_amdgcn_mfma_f32_16x16x32_bf16(b2, af, z, 0, 0, 0);
    f32x4 h3 = __builtin_amdgcn_mfma_f32_16x16x32_bf16(b3, af, z, 0, 0, 0);
    unsigned short* hb = sh.h + (wv * 16 + ch16) * 72 + quad * 4;
    uint2 s;
    s.x = pack2bf(silu_c(h0[0]), silu_c(h0[1]));
    s.y = pack2bf(silu_c(h0[2]), silu_c(h0[3]));
    *(uint2*)(hb + 0) = s;
    s.x = pack2bf(silu_c(h1[0]), silu_c(h1[1]));
    s.y = pack2bf(silu_c(h1[2]), silu_c(h1[3]));
    *(uint2*)(hb + 16) = s;
    s.x = pack2bf(silu_c(h2[0]), silu_c(h2[1]));
    s.y = pack2bf(silu_c(h2[2]), silu_c(h2[3]));
    *(uint2*)(hb + 32) = s;
    s.x = pack2bf(silu_c(h3[0]), silu_c(h3[1]));
    s.y = pack2bf(silu_c(h3[2]), silu_c(h3[3]));
    *(uint2*)(hb + 48) = s;
  }
  __syncthreads();

  int m0 = wv * 16;
  int mrow = lane & 15;
  bf16x8 a0 = *(const bf16x8*)(sh.h + (m0 + mrow) * 72 + quad * 8);
  bf16x8 a1 = *(const bf16x8*)(sh.h + (m0 + mrow) * 72 + 32 + quad * 8);
  char* wbase = (char*)wout + (size_t)(eb + m0 + mrow) * 640;
  const float K = 0.125f;
  #pragma unroll
  for (int tt = 0; tt < 4; ++tt) {
    f32x4 Av = wtile(fc1p, a0, a1, mrow, quad, tt);
    f32x4 Bv = wtile(fc1p, a0, a1, mrow, quad, tt + 4);
    uint4 st;
    st.x = pack2bf(Av[0] * K, Bv[0] * K);
    st.y = pack2bf(Av[1] * K, Bv[1] * K);
    st.z = pack2bf(Av[2] * K, Bv[2] * K);
    st.w = pack2bf(Av[3] * K, Bv[3] * K);
    *(uint4*)(wbase + 64 * tt + 16 * quad) = st;
  }
  #pragma unroll
  for (int tt = 8; tt < 12; ++tt) {
    f32x4 Cv = wtile(fc1p, a0, a1, mrow, quad, tt);
    uint2 st;
    st.x = pack2bf(Cv[0] * K, Cv[1] * K);
    st.y = pack2bf(Cv[2] * K, Cv[3] * K);
    *(uint2*)(wbase + 256 + 32 * (tt - 8) + 8 * quad) = st;
  }
  #pragma unroll
  for (int tt = 12; tt < 14; ++tt) {
    f32x4 Dv = wtile(fc1p, a0, a1, mrow, quad, tt);
    f32x4 Ev = wtile(fc1p, a0, a1, mrow, quad, tt + 2);
    f32x4 Fv = wtile(fc1p, a0, a1, mrow, quad, tt + 4);
    f32x4 Gv = wtile(fc1p, a0, a1, mrow, quad, tt + 6);
    char* db = wbase + 384 + 128 * (tt - 12) + 32 * quad;
    uint4 s0, s1;
    s0.x = pack2bf(Dv[0] * K, Ev[0] * K); s0.y = pack2bf(Fv[0] * K, Gv[0] * K);
    s0.z = pack2bf(Dv[1] * K, Ev[1] * K); s0.w = pack2bf(Fv[1] * K, Gv[1] * K);
    s1.x = pack2bf(Dv[2] * K, Ev[2] * K); s1.y = pack2bf(Fv[2] * K, Gv[2] * K);
    s1.z = pack2bf(Dv[3] * K, Ev[3] * K); s1.w = pack2bf(Fv[3] * K, Gv[3] * K);
    *(uint4*)(db) = s0;
    *(uint4*)(db + 16) = s1;
  }
}

// k_npre body (MFMA): y[n, 0:192] = attr[n] * (bf16(xin[n,0:160]) @ Wyp).
#define YSTR 168
__device__ void npre_body(unsigned short* Ash, int blk,
    const float* __restrict__ xin, const float* __restrict__ attr,
    const unsigned short* __restrict__ Wyp, float* __restrict__ y) {
  int t = threadIdx.x;
  int nbase = blk * 16;
  for (int idx = t; idx < 16 * 80; idx += 256) {
    int row = idx / 80, c = idx - row * 80;
    const float* xp = xin + (size_t)(nbase + row) * 160 + 2 * c;
    *(unsigned*)(Ash + row * YSTR + 2 * c) = pack2bf(xp[0], xp[1]);
  }
  __syncthreads();
  int wid = t >> 6, lane = t & 63;
  int ch = lane & 15, quad = lane >> 4;
  const unsigned short* arow = Ash + ch * YSTR + quad * 8;
  f32x4 acc0 = {0.f,0.f,0.f,0.f}, acc1 = {0.f,0.f,0.f,0.f}, acc2 = {0.f,0.f,0.f,0.f};
  const unsigned short* wq0 = Wyp + ((size_t)(wid * 3 + 0) * 5 * 64 + lane) * 8;
  const unsigned short* wq1 = Wyp + ((size_t)(wid * 3 + 1) * 5 * 64 + lane) * 8;
  const unsigned short* wq2 = Wyp + ((size_t)(wid * 3 + 2) * 5 * 64 + lane) * 8;
  #pragma unroll
  for (int ks = 0; ks < 5; ++ks) {
    bf16x8 af  = *(const bf16x8*)(arow + ks * 32);
    bf16x8 w0f = *(const bf16x8*)(wq0 + ks * 512);
    bf16x8 w1f = *(const bf16x8*)(wq1 + ks * 512);
    bf16x8 w2f = *(const bf16x8*)(wq2 + ks * 512);
    acc0 = __builtin_amdgcn_mfma_f32_16x16x32_bf16(w0f, af, acc0, 0, 0, 0);
    acc1 = __builtin_amdgcn_mfma_f32_16x16x32_bf16(w1f, af, acc1, 0, 0, 0);
    acc2 = __builtin_amdgcn_mfma_f32_16x16x32_bf16(w2f, af, acc2, 0, 0, 0);
  }
  float a = attr[nbase + ch];
  float* yrow = y + (size_t)(nbase + ch) * 192 + quad * 4;
  { float4 st = {acc0[0]*a, acc0[1]*a, acc0[2]*a, acc0[3]*a};
    *(float4*)(yrow + (wid * 3 + 0) * 16) = st; }
  { float4 st = {acc1[0]*a, acc1[1]*a, acc1[2]*a, acc1[3]*a};
    *(float4*)(yrow + (wid * 3 + 1) * 16) = st; }
  { float4 st = {acc2[0]*a, acc2[1]*a, acc2[2]*a, acc2[3]*a};
    *(float4*)(yrow + (wid * 3 + 2) * 16) = st; }
}

// fused mid-stage: blocks [0,2500) = w_gemm, [2500,3125) = npre
__global__ __launch_bounds__(256) void k_midpre(
    const float* __restrict__ ed2b, const unsigned short* __restrict__ fc0p,
    const unsigned short* __restrict__ fc1p, unsigned short* __restrict__ wout,
    const float* __restrict__ xin, const float* __restrict__ attr,
    const unsigned short* __restrict__ Wyp, float* __restrict__ y) {
  __shared__ union ShU {
    WgemmShared w;
    unsigned short ash[16 * YSTR];
  } sh;
  if (blockIdx.x < 2500) {
    w_gemm_body(sh.w, blockIdx.x, ed2b, fc0p, fc1p, wout);
  } else {
    npre_body(sh.ash, blockIdx.x - 2500, xin, attr, Wyp, y);
  }
}

// node_agg: round-0 proven loop (2-slot pipeline) — BYTE-IDENTICAL body;
// only E_LOAD's stride changed (ed2a, 48 B rows). Accumulators stored
// directly to the per-node agg buffer (bf16, QDEG-scaled). No LDS.
__global__ __launch_bounds__(256) void node_agg(
    const float* __restrict__ y, const float* __restrict__ ed2a,
    const unsigned short* __restrict__ wbuf,
    const int* __restrict__ order, const int* __restrict__ obeg,
    const int* __restrict__ ocnt, unsigned short* __restrict__ aggb) {
  int tid = threadIdx.x, wid = tid >> 6, lane = tid & 63, l31 = lane & 31;
  int gw = blockIdx.x * 4 + wid;
  // fixed per-lane byte offsets (loop-invariant)
  int voY  = 4 * lane;           // y scalar block
  int voX  = 256 + 16 * l31;     // y vector float4 {x0,x1,x2,0}
  int voAB = 4 * lane;           // wbuf AB
  int voC  = 256 + 2 * lane;     // wbuf C
  int voDG = 384 + 8 * l31;      // wbuf DEFG

#define E_LOAD(S, idx)                                                         \
  if ((idx) < cnt) {                                                           \
    const float4* ep = (const float4*)(ed2a + (size_t)(beg + (idx)) * 12);     \
    PE0##S = ep[0]; PE1##S = ep[1]; PE2##S = ep[2];                            \
  }
#define V_LOAD(S, idx)                                                         \
  if ((idx) < cnt) {                                                           \
    int srcn = __float_as_int(PE2##S.y);                                       \
    const char* yb = (const char*)y + (size_t)srcn * 768;                      \
    Y##S = *(const float*)(yb + voY);                                          \
    X##S = *(const f32x4*)(yb + voX);                                          \
    const char* wb = (const char*)wbuf + (size_t)(beg + (idx)) * 640;          \
    AB##S = *(const unsigned*)(wb + voAB);                                     \
    Cw##S = *(const unsigned short*)(wb + voC);                                \
    DG##S = *(const uint2*)(wb + voDG);                                        \
  }
#define COMPUTE(S)                                                             \
  {                                                                            \
    float e0 = PE0##S.x, ey = PE0##S.y, ez = PE0##S.z, ex = PE0##S.w;          \
    float q0 = PE1##S.x, q1 = PE1##S.y, q2 = PE1##S.z, q3 = PE1##S.w;          \
    float q4 = PE2##S.x;                                                       \
    float Yv = Y##S, x0 = X##S.x, x1 = X##S.y, x2 = X##S.z;                    \
    float vA = bf2f(AB##S), vB = bfhi(AB##S), vC = bf2f(Cw##S);                \
    float vD = bf2f(DG##S.x), vE = bfhi(DG##S.x);                              \
    float vF = bf2f(DG##S.y), vG = bfhi(DG##S.y);                              \
    aK0 += Yv * e0 * vA;                                                       \
    float tB = Yv * vB; aK2x += tB * ey; aK2y += tB * ez; aK2z += tB * ex;     \
    float tC = Yv * vC;                                                        \
    aK5a += tC * q0; aK5b += tC * q1; aK5c += tC * q2;                         \
    aK5d += tC * q3; aK5e += tC * q4;                                          \
    float t1 = x0 * ey + x1 * ez + x2 * ex; aK1 += (RS3 * vE) * t1;            \
    float s3 = e0 * vD; aK3x += x0 * s3; aK3y += x1 * s3; aK3z += x2 * s3;     \
    float s4 = SQ3_ * vG;                                                      \
    aK4x += s4 * (B_ * (x2 * q0 + x1 * q1 - x0 * q4) - A_ * x0 * q2);          \
    aK4y += s4 * (B_ * (x0 * q1 + x2 * q3) + 2.f * A_ * x1 * q2);              \
    aK4z += s4 * (B_ * (x0 * q0 + x1 * q3 + x2 * q4) - A_ * x2 * q2);          \
    float s6 = SQ5_ * vF;                                                      \
    aK6a += s6 * (-B_ * (x0 * ex + x2 * ey));                                  \
    aK6b += s6 * (-B_ * (x0 * ez + x1 * ey));                                  \
    aK6c += s6 * ( A_ * (x0 * ey + x2 * ex - 2.f * x1 * ez));                  \
    aK6d += s6 * (-B_ * (x1 * ex + x2 * ez));                                  \
    aK6e += s6 * ( B_ * (x0 * ey - x2 * ex));                                  \
  }

  int n = order[gw], beg = obeg[gw], cnt = ocnt[gw];

  float aK0 = 0.f, aK2x = 0.f, aK2y = 0.f, aK2z = 0.f;
  float aK5a = 0.f, aK5b = 0.f, aK5c = 0.f, aK5d = 0.f, aK5e = 0.f;
  float aK1 = 0.f, aK3x = 0.f, aK3y = 0.f, aK3z = 0.f;
  float aK4x = 0.f, aK4y = 0.f, aK4z = 0.f;
  float aK6a = 0.f, aK6b = 0.f, aK6c = 0.f, aK6d = 0.f, aK6e = 0.f;

  float4 PE0a, PE1a, PE2a, PE0b, PE1b, PE2b;
  float Ya, Yb; f32x4 Xa, Xb;
  unsigned ABa, ABb; unsigned short Cwa, Cwb;
  uint2 DGa, DGb;

  E_LOAD(a, 0)
  E_LOAD(b, 1)
  V_LOAD(a, 0)

  int i = 0;
  while (i < cnt) {
    V_LOAD(b, i + 1)
    COMPUTE(a)
    E_LOAD(a, i + 2)
    ++i; if (i >= cnt) break;
    V_LOAD(a, i + 1)
    COMPUTE(b)
    E_LOAD(b, i + 2)
    ++i;
  }

  // store accumulators (QDEG-scaled, bf16) to the node's agg row [960]
  unsigned short* ag = aggb + (size_t)n * 960;
  ag[lane]           = f2bf(aK0  * QDEG);
  ag[96 + 3 * lane]  = f2bf(aK2x * QDEG);
  ag[97 + 3 * lane]  = f2bf(aK2y * QDEG);
  ag[98 + 3 * lane]  = f2bf(aK2z * QDEG);
  ag[480 + 5 * lane] = f2bf(aK5a * QDEG);
  ag[481 + 5 * lane] = f2bf(aK5b * QDEG);
  ag[482 + 5 * lane] = f2bf(aK5c * QDEG);
  ag[483 + 5 * lane] = f2bf(aK5d * QDEG);
  ag[484 + 5 * lane] = f2bf(aK5e * QDEG);
  if (lane < 32) {
    ag[64 + lane]      = f2bf(aK1  * QDEG);
    ag[288 + 3 * lane] = f2bf(aK3x * QDEG);
    ag[289 + 3 * lane] = f2bf(aK3y * QDEG);
    ag[290 + 3 * lane] = f2bf(aK3z * QDEG);
    ag[384 + 3 * lane] = f2bf(aK4x * QDEG);
    ag[385 + 3 * lane] = f2bf(aK4y * QDEG);
    ag[386 + 3 * lane] = f2bf(aK4z * QDEG);
    ag[800 + 5 * lane] = f2bf(aK6a * QDEG);
    ag[801 + 5 * lane] = f2bf(aK6b * QDEG);
    ag[802 + 5 * lane] = f2bf(aK6c * QDEG);
    ag[803 + 5 * lane] = f2bf(aK6d * QDEG);
    ag[804 + 5 * lane] = f2bf(aK6e * QDEG);
  }
#undef E_LOAD
#undef V_LOAD
#undef COMPUTE
}

// k_out (MFMA): out[n,0:320] = attr[n] * (A[n,0:1120] @ W).
#define ASTR 1128
__global__ __launch_bounds__(256) void k_out(
    const unsigned short* __restrict__ aggb, const float* __restrict__ xin,
    const float* __restrict__ attr, const unsigned short* __restrict__ Wp,
    float* __restrict__ out) {
  __shared__ __align__(16) unsigned short Ash[16 * ASTR];
  int t = threadIdx.x;
  int nbase = blockIdx.x * 16;
  for (int idx = t; idx < 16 * 480; idx += 256) {
    int row = idx / 480, c = idx - row * 480;
    *(unsigned*)(Ash + row * ASTR + 2 * c) =
        *(const unsigned*)(aggb + (size_t)(nbase + row) * 960 + 2 * c);
  }
  for (int idx = t; idx < 16 * 80; idx += 256) {
    int row = idx / 80, c = idx - row * 80;
    const float* xp = xin + (size_t)(nbase + row) * 160 + 2 * c;
    *(unsigned*)(Ash + row * ASTR + 960 + 2 * c) = pack2bf(xp[0], xp[1]);
  }
  __syncthreads();

  int wid = t >> 6, lane = t & 63;
  int ch = lane & 15, quad = lane >> 4;
  f32x4 acc0 = {0.f,0.f,0.f,0.f}, acc1 = {0.f,0.f,0.f,0.f};
  f32x4 acc2 = {0.f,0.f,0.f,0.f}, acc3 = {0.f,0.f,0.f,0.f};
  f32x4 acc4 = {0.f,0.f,0.f,0.f};
  const unsigned short* arow = Ash + ch * ASTR + quad * 8;
  const unsigned short* wq0 = Wp + ((size_t)(wid * 5 + 0) * 35 * 64 + lane) * 8;
  const unsigned short* wq1 = Wp + ((size_t)(wid * 5 + 1) * 35 * 64 + lane) * 8;
  const unsigned short* wq2 = Wp + ((size_t)(wid * 5 + 2) * 35 * 64 + lane) * 8;
  const unsigned short* wq3 = Wp + ((size_t)(wid * 5 + 3) * 35 * 64 + lane) * 8;
  const unsigned short* wq4 = Wp + ((size_t)(wid * 5 + 4) * 35 * 64 + lane) * 8;
  for (int ks = 0; ks < 35; ++ks) {
    bf16x8 af = *(const bf16x8*)(arow + ks * 32);
    bf16x8 w0f = *(const bf16x8*)(wq0 + ks * 512);
    bf16x8 w1f = *(const bf16x8*)(wq1 + ks * 512);
    bf16x8 w2f = *(const bf16x8*)(wq2 + ks * 512);
    bf16x8 w3f = *(const bf16x8*)(wq3 + ks * 512);
    bf16x8 w4f = *(const bf16x8*)(wq4 + ks * 512);
    acc0 = __builtin_amdgcn_mfma_f32_16x16x32_bf16(w0f, af, acc0, 0, 0, 0);
    acc1 = __builtin_amdgcn_mfma_f32_16x16x32_bf16(w1f, af, acc1, 0, 0, 0);
    acc2 = __builtin_amdgcn_mfma_f32_16x16x32_bf16(w2f, af, acc2, 0, 0, 0);
    acc3 = __builtin_amdgcn_mfma_f32_16x16x32_bf16(w3f, af, acc3, 0, 0, 0);
    acc4 = __builtin_amdgcn_mfma_f32_16x16x32_bf16(w4f, af, acc4, 0, 0, 0);
  }
  float a = attr[nbase + ch];
  float* orow = out + (size_t)(nbase + ch) * 320 + quad * 4;
  {
    float4 st = {acc0[0]*a, acc0[1]*a, acc0[2]*a, acc0[3]*a};
    *(float4*)(orow + (wid * 5 + 0) * 16) = st;
  }
  {
    float4 st = {acc1[0]*a, acc1[1]*a, acc1[2]*a, acc1[3]*a};
    *(float4*)(orow + (wid * 5 + 1) * 16) = st;
  }
  {
    float4 st = {acc2[0]*a, acc2[1]*a, acc2[2]*a, acc2[3]*a};
    *(float4*)(orow + (wid * 5 + 2) * 16) = st;
  }
  {
    float4 st = {acc3[0]*a, acc3[1]*a, acc3[2]*a, acc3[3]*a};
    *(float4*)(orow + (wid * 5 + 3) * 16) = st;
  }
  {
    float4 st = {acc4[0]*a, acc4[1]*a, acc4[2]*a, acc4[3]*a};
    *(float4*)(orow + (wid * 5 + 4) * 16) = st;
  }
}

extern "C" void kernel_launch(void* const* d_in, const int* in_sizes, int n_in,
                              void* d_out, int out_size, void* d_ws, size_t ws_size,
                              hipStream_t stream) {
  const float* node_input = (const float*)d_in[0];
  const float* node_attr  = (const float*)d_in[1];
  const int*   edge_src   = (const int*)d_in[2];
  const int*   edge_dst   = (const int*)d_in[3];
  const float* edge_attr  = (const float*)d_in[4];
  const float* ele        = (const float*)d_in[5];
  const float* sc_w0      = (const float*)d_in[6];
  const float* sc_w1      = (const float*)d_in[7];
  const float* l1_w0      = (const float*)d_in[8];
  const float* l1_w1      = (const float*)d_in[9];
  const float* fc_w0      = (const float*)d_in[10];
  const float* fc_w1      = (const float*)d_in[11];
  const float* l2_w0      = (const float*)d_in[12];
  const float* l2_w1      = (const float*)d_in[13];
  const float* l2_w2      = (const float*)d_in[14];
  float* out = (float*)d_out;

  char* base = (char*)d_ws;
  float* y              = (float*)(base);                       // 7.68 MB (stride 192)
  unsigned short* wbuf  = (unsigned short*)(base + 7680000);    // 102.4 MB packed
  float* ed2a           = (float*)(base + 110080000);           // 7.68 MB (stride 12)
  float* ed2b           = (float*)(base + 117760000);           // 5.12 MB (stride 8)
  int* counts           = (int*)(base + 122880000);
  int* offs             = (int*)(base + 122920000);
  int* cur              = (int*)(base + 122960000);
  int* order            = (int*)(base + 123000000);
  int* obeg             = (int*)(base + 123040000);
  int* ocnt             = (int*)(base + 123080000);
  int* dcur             = (int*)(base + 123120000);             // 1 KB
  unsigned short* fc1p  = (unsigned short*)(base + 123121024);  // 40 KB
  unsigned short* aggb  = (unsigned short*)(base + 123162624);  // 19.2 MB
  unsigned short* Wp    = (unsigned short*)(base + 142362624);  // 716.8 KB
  unsigned short* Wyp   = (unsigned short*)(base + 143079424);  // 61.4 KB
  unsigned short* fc0p  = (unsigned short*)(base + 143140864);  // 4 KB

  hipMemsetAsync(counts, 0, N_NODES * sizeof(int), stream);
  hipLaunchKernelGGL(k_prep, dim3(2233), dim3(256), 0, stream,
                     edge_dst, counts, fc_w1, fc1p, fc_w0, fc0p,
                     sc_w0, sc_w1, l2_w0, l2_w1, l2_w2, l1_w0, l1_w1, Wp, Wyp);
  hipLaunchKernelGGL(k_scan, dim3(1), dim3(256), 0, stream, counts, offs, cur, dcur);
  hipLaunchKernelGGL(k_perm, dim3(N_EDGES / 256), dim3(256), 0, stream,
                     edge_dst, cur, counts, offs, dcur, order, obeg, ocnt,
                     ele, edge_attr, edge_src, ed2a, ed2b);
  hipLaunchKernelGGL(k_midpre, dim3(3125), dim3(256), 0, stream,
                     ed2b, fc0p, fc1p, wbuf, node_input, node_attr, Wyp, y);
  hipLaunchKernelGGL(node_agg, dim3(2500), dim3(256), 0, stream,
                     y, ed2a, wbuf, order, obeg, ocnt, aggb);
  hipLaunchKernelGGL(k_out, dim3(625), dim3(256), 0, stream,
                     aggb, node_input, node_attr, Wp, out);
}